// Round 14
// baseline (473.762 us; speedup 1.0000x reference)
//
#include <hip/hip_runtime.h>

// ---------------------------------------------------------------------------
// Transformer block (pre-LN attn + FFN), B=16 T=512 D=1024 H=16 HD=64, f32 io.
// bf16 MFMA GEMMs; q/k path uses bf16 hi/lo split (K'=3K GEMM) so the
// UNSCALED K.Q^T scores stay ~f32-accurate.
// GEMM v3-256 (verified r7/r13): 2 superphases/K-tile, counted vmcnt never 0,
// ring-4 regions, XOR swizzle (0 conflicts), XCD swizzle, setprio. Schedule
// variants all refuted (4-phase=114, reg-prefetch=111, m201-port=114,
// 128^2-TLP=+35; v3=107us = m97-class rate). Composites reverted (r10).
// NEW (r14): LDS-staged coalesced epilogues for RELU/SPLIT/RES (r13 analysis:
// ~18us/block fixed cost dominated by scalar u16 stores). Stage C-tile in
// dead LDS, store 512B-contiguous rows as u16x8/f32x4. Window-XOR
// ((row>>2)&3)<<5 (bf16) / <<6 (f32): 4 l4-groups -> disjoint bank windows
// (<=2-way free); store-phase reads full rows (conflict-free). RES also
// coalesces the residual read. QKFRAG/VFRAG keep scalar (16B-chunk granular).
// Attention v3 (r13): paired t-groups (g,31-g), 9 iters/wave, grid (4,256).
// Workspace (~167 MiB, liveness-aliased), x2 lives in d_out.
// ---------------------------------------------------------------------------

#define DEV __device__ __forceinline__

typedef unsigned short u16;
typedef __attribute__((ext_vector_type(8))) __bf16 bf16x8;
typedef __attribute__((ext_vector_type(4))) float f32x4;
typedef __attribute__((ext_vector_type(8))) unsigned short u16x8;

typedef __attribute__((address_space(1))) void as1_void;
typedef __attribute__((address_space(3))) void as3_void;

DEV u16 f2b(float f) {                       // f32 -> bf16 RNE (finite inputs)
  unsigned u = __float_as_uint(f);
  u = (u + 0x7fffu + ((u >> 16) & 1u)) >> 16;
  return (u16)u;
}
DEV float b2f(u16 h) { return __uint_as_float(((unsigned)h) << 16); }

DEV f32x4 mfma16(bf16x8 a, bf16x8 b, f32x4 c) {
  return __builtin_amdgcn_mfma_f32_16x16x32_bf16(a, b, c, 0, 0, 0);
}

// async global->LDS, 16B per lane, dest = uniform base + lane*16
DEV void gload16(const void* g, void* l) {
  __builtin_amdgcn_global_load_lds((as1_void*)(unsigned long long)g,
                                   (as3_void*)(unsigned long long)l,
                                   16u, 0, 0u);
}

#define EPI_BF16 0
#define EPI_RELU 1
#define EPI_RES 2
#define EPI_SPLIT 3
#define EPI_QKFRAG 4
#define EPI_VFRAG 5

// ---------------------------------------------------------------------------
// GEMM v3: C[M,N] = A[M,K]*Bt[N,K]^T + bias. BMxBN tile, BK=64.
// kdup  (A): ktA = (kt>=kdup)? kt-kdup : kt  -> A' = [hi, hi, lo]
// kdupB (B): ktB analogous (dual [hi|lo] serving [hi,lo,hi]).
// Superphase per iteration u (buf cur=u&1):
//   kh0: read A(cur,0)+B(cur,0); stage (u+1).kh1 -> (cur^1,1);
//        MFMA; lgkm0; vmcnt(NWAIT); barrier
//   kh1: read A(cur,1)+B(cur,1); stage (u+2).kh0 -> (cur,0);
//        MFMA; lgkm0; vmcnt(NWAIT); barrier
// NWAIT = 2 stage-groups = 2*(LA+LB). Prologue = 3 groups then vmcnt(NWAIT).
// Tail stages clamp kt; targets are dead regions (counts stay uniform).
// ---------------------------------------------------------------------------
template <int BM, int BN, int EPI>
__global__ __launch_bounds__((BM == 256) ? 512 : 256, 2) void gemm256(
    const u16* __restrict__ A, int lda, int kdup, const u16* __restrict__ Bt,
    const float* __restrict__ bias, const float* __restrict__ res,
    void* __restrict__ Cout, void* __restrict__ Cout2, int ldc, int N, int K,
    int ldb, int kdupB) {
  constexpr int THREADS = (BM == 256) ? 512 : 256;
  constexpr int NWAVE = THREADS / 64;
  constexpr int NWN = (BN == 256) ? 4 : 2;   // n-waves (64 cols each)
  constexpr int NWM = NWAVE / NWN;           // m-waves
  constexpr int MPW = BM / NWM;              // per-wave m rows
  constexpr int MF = MPW / 16;               // m-frags per wave
  constexpr int LA = BM * 4 / THREADS;       // A gloads/thread/stage (=2)
  constexpr int LB = BN * 4 / THREADS;       // B gloads/thread/stage (1 or 2)
  constexpr int NWAIT = 2 * (LA + LB);       // counted vmcnt
  constexpr int ASZ = BM * 64;               // bytes per (buf,ks) A region
  constexpr int BSZ = BN * 64;
  constexpr int ATOT = 4 * ASZ;
  __shared__ __align__(1024) char lds[4 * ASZ + 4 * BSZ];

  // XCD-contiguous block swizzle (gridDim.x % 8 == 0 by construction)
  const int nwg = (int)gridDim.x;
  const int cpx = nwg >> 3;
  int w = (int)blockIdx.x;
  w = (w & 7) * cpx + (w >> 3);
  const int nbn = N / BN;
  const int bn = w % nbn, bm = w / nbn;

  const int tid = threadIdx.x;
  const int wave = tid >> 6, lane = tid & 63;
  const int l15 = lane & 15, l4 = lane >> 4;
  const int wm = wave / NWN;
  const int wn = wave % NWN;
  const int nk = K >> 6;

  // staging source: dest row-in-16-group = lane>>2, dest chunk = lane&3;
  // source holds chunk (lane&3) ^ ((row>>1)&3)  [same involution as reads]
  const int srow = lane >> 2;
  const int schunk = ((lane & 3) ^ ((srow >> 1) & 3)) << 4;
  const char* Ab = (const char*)A;
  const char* Bb = (const char*)Bt;
  const int arowA = wave * (BM / NWAVE) + srow;
  const int arowB = wave * (BN / NWAVE) + srow;

  auto stageA = [&](int buf, int kh, int kt) {
    const int ktA = (kdup && kt >= kdup) ? kt - kdup : kt;
    const char* s = Ab + (size_t)(bm * BM + arowA) * (size_t)(lda * 2) +
                    ktA * 128 + kh * 64 + schunk;
    char* d = lds + (((buf << 1) | kh) * ASZ) + wave * (LA * 1024);
    gload16(s, d);
    gload16(s + (size_t)16 * (size_t)(lda * 2), d + 1024);
  };
  auto stageB = [&](int buf, int kh, int kt) {
    const int ktB = (kdupB && kt >= kdupB) ? kt - kdupB : kt;
    const char* s = Bb + (size_t)(bn * BN + arowB) * (size_t)(ldb * 2) +
                    ktB * 128 + kh * 64 + schunk;
    char* d = lds + ATOT + (((buf << 1) | kh) * BSZ) + wave * (LB * 1024);
    gload16(s, d);
    if (LB == 2) gload16(s + (size_t)16 * (size_t)(ldb * 2), d + 1024);
  };

  const f32x4 fz = {0.f, 0.f, 0.f, 0.f};
  f32x4 acc[MF][4];
#pragma unroll
  for (int i = 0; i < MF; ++i)
#pragma unroll
    for (int j = 0; j < 4; ++j) acc[i][j] = fz;

  // prologue: tile0 full + tile1 kh0, in steady-state issue order
  stageA(0, 0, 0);
  stageB(0, 0, 0);
  stageA(0, 1, 0);
  stageB(0, 1, 0);
  {
    const int k1 = (1 < nk) ? 1 : nk - 1;
    stageA(1, 0, k1);
    stageB(1, 0, k1);
  }
  asm volatile("s_waitcnt vmcnt(%0)" ::"i"(NWAIT) : "memory");
  __builtin_amdgcn_s_barrier();

  for (int u = 0; u < nk; ++u) {
    const int cur = u & 1;
    const int kp1 = (u + 1 < nk) ? u + 1 : nk - 1;
    const int kp2 = (u + 2 < nk) ? u + 2 : nk - 1;
#pragma unroll
    for (int kh = 0; kh < 2; ++kh) {
      const char* Ar = lds + (((cur << 1) | kh) * ASZ);
      const char* Br = lds + ATOT + (((cur << 1) | kh) * BSZ);
      bf16x8 bfr[4], af[MF];
#pragma unroll
      for (int ni = 0; ni < 4; ++ni) {
        const int n = wn * 64 + ni * 16 + l15;
        bfr[ni] = *(const bf16x8*)(Br + n * 64 + ((l4 ^ ((n >> 1) & 3)) << 4));
      }
#pragma unroll
      for (int mi = 0; mi < MF; ++mi) {
        const int m = wm * MPW + mi * 16 + l15;
        af[mi] = *(const bf16x8*)(Ar + m * 64 + ((l4 ^ ((m >> 1) & 3)) << 4));
      }
      if (kh == 0) {
        stageA(cur ^ 1, 1, kp1);
        stageB(cur ^ 1, 1, kp1);
      } else {
        stageA(cur, 0, kp2);
        stageB(cur, 0, kp2);
      }
      __builtin_amdgcn_s_setprio(1);
#pragma unroll
      for (int mi = 0; mi < MF; ++mi)
#pragma unroll
        for (int ni = 0; ni < 4; ++ni)
          acc[mi][ni] = mfma16(af[mi], bfr[ni], acc[mi][ni]);
      __builtin_amdgcn_s_setprio(0);
      // WAR guard: this kh's region is re-staged next superphase.
      asm volatile("s_waitcnt lgkmcnt(0)" ::: "memory");
      // visibility: next superphase's region complete for all waves.
      asm volatile("s_waitcnt vmcnt(%0)" ::"i"(NWAIT) : "memory");
      __builtin_amdgcn_s_barrier();
    }
  }
  asm volatile("s_waitcnt vmcnt(0)" ::: "memory");

  // ---- epilogue ----
  if constexpr (EPI == EPI_BF16 || EPI == EPI_QKFRAG || EPI == EPI_VFRAG) {
    // scalar epilogue (frag layouts already 16B-chunk granular)
#pragma unroll
    for (int mf = 0; mf < MF; ++mf) {
#pragma unroll
      for (int ni = 0; ni < 4; ++ni) {
        const int gn = bn * BN + wn * 64 + ni * 16 + l15;
        const float bia = bias[gn];
#pragma unroll
        for (int r = 0; r < 4; ++r) {
          const int gm = bm * BM + wm * MPW + mf * 16 + l4 * 4 + r;
          float v = acc[mf][ni][r] + bia;
          if (EPI == EPI_BF16) {
            ((u16*)Cout)[(size_t)gm * ldc + gn] = f2b(v);
          } else if (EPI == EPI_QKFRAG) {
            // gm=(b,s); gn<1024: q -> Cout frags; gn>=1024: k -> Cout2.
            const int b = gm >> 9, s = gm & 511;
            const int gs = s >> 4, sr = s & 15;
            const int n = gn & 1023;
            const int h = n >> 6, e = n & 63;
            u16* base = (u16*)((gn >> 10) ? Cout2 : Cout);
            const size_t blk = ((size_t)(b * 16 + h) * 32 + gs) * 4;
            const int idx = ((e >> 3) & 3) * 128 + sr * 8 + (e & 7);
            const u16 hi = f2b(v);
            base[(blk + (e >> 5)) * 512 + idx] = hi;
            base[(blk + 2 + (e >> 5)) * 512 + idx] = f2b(v - b2f(hi));
          } else {  // EPI_VFRAG
            const int b = gm >> 9, s = gm & 511;
            const int h = gn >> 6, e = gn & 63;
            const size_t blk =
                ((size_t)(b * 16 + h) * 16 + (s >> 5)) * 4 + (e >> 4);
            ((u16*)Cout)[blk * 512 + ((s >> 3) & 3) * 128 + (e & 15) * 8 +
                         (s & 7)] = f2b(v);
          }
        }
      }
    }
  } else if constexpr (EPI == EPI_RELU) {
    // staged bf16 tile (BM x BN x 2B <= LDS), coalesced u16x8 stores
    constexpr int ROWB = BN * 2;
    constexpr int CPR = ROWB / 16;
    constexpr int RPI = THREADS / CPR;
    __builtin_amdgcn_s_barrier();
#pragma unroll
    for (int mf = 0; mf < MF; ++mf)
#pragma unroll
      for (int ni = 0; ni < 4; ++ni) {
        const int col = wn * 64 + ni * 16 + l15;
        const float bia = bias[bn * BN + col];
#pragma unroll
        for (int r = 0; r < 4; ++r) {
          const int row = wm * MPW + mf * 16 + l4 * 4 + r;
          float v = acc[mf][ni][r] + bia;
          v = v > 0.f ? v : 0.f;
          *(u16*)(lds + row * ROWB +
                  ((col * 2) ^ (((row >> 2) & 3) << 5))) = f2b(v);
        }
      }
    __builtin_amdgcn_s_barrier();
#pragma unroll
    for (int it = 0; it < BM / RPI; ++it) {
      const int row = it * RPI + tid / CPR;
      const int ch = tid % CPR;
      const u16x8 v = *(const u16x8*)(lds + row * ROWB +
                                      ((ch << 4) ^ (((row >> 2) & 3) << 5)));
      *(u16x8*)((u16*)Cout + (size_t)(bm * BM + row) * ldc + bn * BN +
                ch * 8) = v;
    }
  } else if constexpr (EPI == EPI_SPLIT) {
    // staged bf16, two passes: hi plane then lo plane (+N cols)
    constexpr int ROWB = BN * 2;
    constexpr int CPR = ROWB / 16;
    constexpr int RPI = THREADS / CPR;
#pragma unroll
    for (int pass = 0; pass < 2; ++pass) {
      __builtin_amdgcn_s_barrier();
#pragma unroll
      for (int mf = 0; mf < MF; ++mf)
#pragma unroll
        for (int ni = 0; ni < 4; ++ni) {
          const int col = wn * 64 + ni * 16 + l15;
          const float bia = bias[bn * BN + col];
#pragma unroll
          for (int r = 0; r < 4; ++r) {
            const int row = wm * MPW + mf * 16 + l4 * 4 + r;
            const float v = acc[mf][ni][r] + bia;
            const u16 hi = f2b(v);
            const u16 val = pass ? f2b(v - b2f(hi)) : hi;
            *(u16*)(lds + row * ROWB +
                    ((col * 2) ^ (((row >> 2) & 3) << 5))) = val;
          }
        }
      __builtin_amdgcn_s_barrier();
#pragma unroll
      for (int it = 0; it < BM / RPI; ++it) {
        const int row = it * RPI + tid / CPR;
        const int ch = tid % CPR;
        const u16x8 v = *(const u16x8*)(lds + row * ROWB +
                                        ((ch << 4) ^ (((row >> 2) & 3) << 5)));
        *(u16x8*)((u16*)Cout + (size_t)(bm * BM + row) * ldc + pass * N +
                  bn * BN + ch * 8) = v;
      }
    }
  } else {  // EPI_RES: staged f32, two mf-half passes; coalesced res read
    constexpr int ROWB = BN * 4;
    constexpr int CPR = ROWB / 16;
    constexpr int RPI = THREADS / CPR;
    constexpr int HR = BM / 2;
#pragma unroll
    for (int p = 0; p < 2; ++p) {
      __builtin_amdgcn_s_barrier();
#pragma unroll
      for (int mi = 0; mi < MF / 2; ++mi) {
        const int mf = p * (MF / 2) + mi;
#pragma unroll
        for (int ni = 0; ni < 4; ++ni) {
          const int col = wn * 64 + ni * 16 + l15;
          const float bia = bias[bn * BN + col];
#pragma unroll
          for (int r = 0; r < 4; ++r) {
            const int lrow = wm * (MPW / 2) + mi * 16 + l4 * 4 + r;  // 0..127
            *(float*)(lds + lrow * ROWB +
                      ((col * 4) ^ (((lrow >> 2) & 3) << 6))) =
                acc[mf][ni][r] + bia;
          }
        }
      }
      __builtin_amdgcn_s_barrier();
#pragma unroll
      for (int it = 0; it < HR / RPI; ++it) {
        const int lrow = it * RPI + tid / CPR;
        const int ch = tid % CPR;
        f32x4 v = *(const f32x4*)(lds + lrow * ROWB +
                                  ((ch << 4) ^ (((lrow >> 2) & 3) << 6)));
        const int grow =
            bm * BM + (lrow >> 5) * MPW + p * (MPW / 2) + (lrow & 31);
        const size_t goff = (size_t)grow * ldc + bn * BN + ch * 4;
        const f32x4 rv = *(const f32x4*)(res + goff);
        *(f32x4*)((float*)Cout + goff) = v + rv;
      }
    }
  }
}

// ---------------------------------------------------------------------------
// LayerNorm row kernel. SPLIT: out row = [hi(1024) | lo(1024)] (stride 2048).
// ---------------------------------------------------------------------------
template <bool SPLIT>
__global__ __launch_bounds__(256) void lnorm(const float* __restrict__ x,
                                             const float* __restrict__ g,
                                             const float* __restrict__ bt,
                                             u16* __restrict__ out) {
  const int row = blockIdx.x, tid = threadIdx.x;
  const int wave = tid >> 6, lane = tid & 63;
  const float4 v = *(const float4*)(x + (size_t)row * 1024 + tid * 4);
  float xv[4] = {v.x, v.y, v.z, v.w};
  float s = xv[0] + xv[1] + xv[2] + xv[3];
  float s2 = xv[0] * xv[0] + xv[1] * xv[1] + xv[2] * xv[2] + xv[3] * xv[3];
  for (int off = 32; off; off >>= 1) {
    s += __shfl_down(s, off);
    s2 += __shfl_down(s2, off);
  }
  __shared__ float red[8];
  if (lane == 0) {
    red[wave] = s;
    red[4 + wave] = s2;
  }
  __syncthreads();
  const float ts = red[0] + red[1] + red[2] + red[3];
  const float ts2 = red[4] + red[5] + red[6] + red[7];
  const float mean = ts * (1.f / 1024.f);
  const float var = ts2 * (1.f / 1024.f) - mean * mean;
  const float rstd = rsqrtf(var + 1e-5f);
#pragma unroll
  for (int j = 0; j < 4; ++j) {
    const int col = tid * 4 + j;
    const float y = (xv[j] - mean) * rstd * g[col] + bt[col];
    const u16 hi = f2b(y);
    if (SPLIT) {
      out[(size_t)row * 2048 + col] = hi;
      out[(size_t)row * 2048 + 1024 + col] = f2b(y - b2f(hi));
    } else {
      out[(size_t)row * 1024 + col] = hi;
    }
  }
}

// ---------------------------------------------------------------------------
// Weight transpose f32[K][cols] -> bf16 out[n][k] (row stride ors).
// MODE 0: plain hi. MODE 2: triple [hi @0 | lo @Koff | hi @2*Koff].
// grid: (cols/64, K/64, batch)
// ---------------------------------------------------------------------------
template <int MODE>
__global__ __launch_bounds__(256) void wtrans(const float* __restrict__ in,
                                              int kstride, long ibs,
                                              u16* __restrict__ out, int ors,
                                              long obs, int Koff) {
  in += (size_t)blockIdx.z * ibs;
  out += (size_t)blockIdx.z * obs;
  const int n0 = blockIdx.x * 64, k0 = blockIdx.y * 64;
  const int tid = threadIdx.x;
  __shared__ float tt[64][65];
  const int r = tid >> 4, c4 = (tid & 15) * 4;
#pragma unroll
  for (int p = 0; p < 4; ++p) {
    const int rr = r + p * 16;
    const float4 vv =
        *(const float4*)(in + (size_t)(k0 + rr) * kstride + n0 + c4);
    tt[rr][c4] = vv.x;
    tt[rr][c4 + 1] = vv.y;
    tt[rr][c4 + 2] = vv.z;
    tt[rr][c4 + 3] = vv.w;
  }
  __syncthreads();
  const int nl = tid >> 2, kc = (tid & 3) * 16;
  u16 hi[16], lo[16];
#pragma unroll
  for (int j = 0; j < 16; ++j) {
    const float w2 = tt[kc + j][nl];
    hi[j] = f2b(w2);
    if (MODE == 2) lo[j] = f2b(w2 - b2f(hi[j]));
  }
  u16* orow = out + (size_t)(n0 + nl) * ors + k0 + kc;
  u16x8 a, b;
#pragma unroll
  for (int j = 0; j < 8; ++j) {
    a[j] = hi[j];
    b[j] = hi[8 + j];
  }
  *(u16x8*)(orow) = a;
  *(u16x8*)(orow + 8) = b;
  if (MODE == 2) {
    *(u16x8*)(orow + 2 * Koff) = a;
    *(u16x8*)(orow + 2 * Koff + 8) = b;
    u16x8 c, d;
#pragma unroll
    for (int j = 0; j < 8; ++j) {
      c[j] = lo[j];
      d[j] = lo[8 + j];
    }
    *(u16x8*)(orow + Koff) = c;
    *(u16x8*)(orow + Koff + 8) = d;
  }
}

__global__ void biascat(const float* __restrict__ bq,
                        const float* __restrict__ bk, float* __restrict__ o) {
  const int i = blockIdx.x * 256 + threadIdx.x;  // 2048 total
  o[i] = (i < 1024) ? bq[i] : bk[i - 1024];
}

__global__ void fillconst(float* __restrict__ p, float v, int n) {
  const int i = blockIdx.x * 256 + threadIdx.x;
  if (i < n) p[i] = v;
}

// ---------------------------------------------------------------------------
// Flash attention v3: paired t-groups (g, 31-g) per wave, 9 iters each.
// grid (4, B*H). Per-group body identical to verified round-3 kernel.
// ---------------------------------------------------------------------------
__global__ __launch_bounds__(256) void attn_fwd(const u16* __restrict__ qf,
                                                const u16* __restrict__ kf,
                                                const u16* __restrict__ vf,
                                                u16* __restrict__ o) {
  const int bh = blockIdx.y;
  const int b = bh >> 4, h = bh & 15;
  const int tid = threadIdx.x, wave = tid >> 6, lane = tid & 63;
  const int l15 = lane & 15, l4 = lane >> 4;
  const int g0 = (int)blockIdx.x * 4 + wave;  // 0..15
  __shared__ u16 Pl[4][1024];  // per-wave 16x64 bf16 P, 128B rows, swizzled

  const f32x4 fz = {0.f, 0.f, 0.f, 0.f};
  const u16* qfb = qf + (size_t)bh * 32 * 2048 + lane * 8;
  const u16* vfb = vf + (size_t)bh * 16 * 2048 + lane * 8;

  for (int grp = 0; grp < 2; ++grp) {
    const int gt = grp ? (31 - g0) : g0;  // pair (g, 31-g): 9 iters total
    const int tw = gt * 16;
    const u16* kfb = kf + ((size_t)(bh * 32 + gt) * 4) * 512 + lane * 8;
    const bf16x8 kh0 = *(const bf16x8*)(kfb);
    const bf16x8 kh1 = *(const bf16x8*)(kfb + 512);
    const bf16x8 kl0 = *(const bf16x8*)(kfb + 1024);
    const bf16x8 kl1 = *(const bf16x8*)(kfb + 1536);

    f32x4 oacc[4] = {fz, fz, fz, fz};
    float mrow[4] = {-1e30f, -1e30f, -1e30f, -1e30f};
    float lrow[4] = {0.f, 0.f, 0.f, 0.f};
    const int niter = (tw + 79) >> 6;

    for (int it = 0; it < niter; ++it) {
      const int s0 = it * 64;
      bf16x8 qh[4][2], ql[4][2];
#pragma unroll
      for (int scb = 0; scb < 4; ++scb) {
        const u16* qp = qfb + (size_t)((s0 >> 4) + scb) * 2048;
        qh[scb][0] = *(const bf16x8*)(qp);
        qh[scb][1] = *(const bf16x8*)(qp + 512);
        ql[scb][0] = *(const bf16x8*)(qp + 1024);
        ql[scb][1] = *(const bf16x8*)(qp + 1536);
      }
      bf16x8 vv[2][4];
#pragma unroll
      for (int h2 = 0; h2 < 2; ++h2) {
        const u16* vp = vfb + (size_t)((s0 >> 5) + h2) * 2048;
#pragma unroll
        for (int eF = 0; eF < 4; ++eF)
          vv[h2][eF] = *(const bf16x8*)(vp + eF * 512);
      }
      f32x4 sf[4];
#pragma unroll
      for (int scb = 0; scb < 4; ++scb) {
        f32x4 z = fz;
        z = mfma16(kh0, qh[scb][0], z);
        z = mfma16(kh1, qh[scb][1], z);
        z = mfma16(kh0, ql[scb][0], z);
        z = mfma16(kh1, ql[scb][1], z);
        z = mfma16(kl0, qh[scb][0], z);
        z = mfma16(kl1, qh[scb][1], z);
        sf[scb] = z;
      }
      if (s0 + 63 > tw) {
#pragma unroll
        for (int scb = 0; scb < 4; ++scb)
#pragma unroll
          for (int r = 0; r < 4; ++r) {
            const int s = s0 + scb * 16 + l15, t = tw + l4 * 4 + r;
            if (s > t) sf[scb][r] = -1e30f;
          }
      }
      float scl[4];
#pragma unroll
      for (int r = 0; r < 4; ++r) {
        float v = fmaxf(fmaxf(sf[0][r], sf[1][r]), fmaxf(sf[2][r], sf[3][r]));
        v = fmaxf(v, __shfl_xor(v, 1));
        v = fmaxf(v, __shfl_xor(v, 2));
        v = fmaxf(v, __shfl_xor(v, 4));
        v = fmaxf(v, __shfl_xor(v, 8));
        const float mn = fmaxf(mrow[r], v);
        scl[r] = __expf(mrow[r] - mn);
        mrow[r] = mn;
      }
      float ps[4] = {0.f, 0.f, 0.f, 0.f};
#pragma unroll
      for (int scb = 0; scb < 4; ++scb)
#pragma unroll
        for (int r = 0; r < 4; ++r) {
          const float p = __expf(sf[scb][r] - mrow[r]);
          sf[scb][r] = p;
          ps[r] += p;
        }
#pragma unroll
      for (int r = 0; r < 4; ++r) {
        float v = ps[r];
        v += __shfl_xor(v, 1);
        v += __shfl_xor(v, 2);
        v += __shfl_xor(v, 4);
        v += __shfl_xor(v, 8);
        lrow[r] = lrow[r] * scl[r] + v;
        oacc[0][r] *= scl[r];
        oacc[1][r] *= scl[r];
        oacc[2][r] *= scl[r];
        oacc[3][r] *= scl[r];
      }
#pragma unroll
      for (int scb = 0; scb < 4; ++scb)
#pragma unroll
        for (int r = 0; r < 4; ++r) {
          const int trow = l4 * 4 + r, scol = scb * 16 + l15;
          const int byte = trow * 128 + ((scol * 2) ^ ((trow & 7) << 4));
          *(u16*)((char*)&Pl[wave][0] + byte) = f2b(sf[scb][r]);
        }
#pragma unroll
      for (int h2 = 0; h2 < 2; ++h2) {
        const bf16x8 pf = *(const bf16x8*)((const char*)&Pl[wave][0] +
                                           l15 * 128 +
                                           (((h2 * 4 + l4) ^ (l15 & 7)) << 4));
#pragma unroll
        for (int eF = 0; eF < 4; ++eF)
          oacc[eF] = mfma16(pf, vv[h2][eF], oacc[eF]);
      }
    }
#pragma unroll
    for (int eF = 0; eF < 4; ++eF)
#pragma unroll
      for (int r = 0; r < 4; ++r) {
        const int t = tw + l4 * 4 + r;
        const float val = oacc[eF][r] / lrow[r];
        o[(size_t)(b * 512 + t) * 1024 + h * 64 + eF * 16 + l15] = f2b(val);
      }
  }
}

// ---------------------------------------------------------------------------
extern "C" void kernel_launch(void* const* d_in, const int* in_sizes, int n_in,
                              void* d_out, int out_size, void* d_ws,
                              size_t ws_size, hipStream_t stream) {
  const float* x = (const float*)d_in[0];
  const float* ga = (const float*)d_in[1];
  const float* ba = (const float*)d_in[2];
  const float* Win = (const float*)d_in[3];
  const float* bin = (const float*)d_in[4];
  const float* Wk = (const float*)d_in[5];
  const float* bk = (const float*)d_in[6];
  const float* Wq = (const float*)d_in[7];
  const float* bq = (const float*)d_in[8];
  const float* Wv = (const float*)d_in[9];
  const float* bv = (const float*)d_in[10];
  const float* Wout = (const float*)d_in[11];
  const float* bout = (const float*)d_in[12];
  const float* gf = (const float*)d_in[13];
  const float* bf_ = (const float*)d_in[14];
  const float* W1 = (const float*)d_in[15];
  const float* b1 = (const float*)d_in[16];
  const float* W2 = (const float*)d_in[17];
  const float* b2 = (const float*)d_in[18];
  float* out = (float*)d_out;

  char* ws = (char*)d_ws;
  size_t off = 0;
  auto alloc = [&](size_t bytes) {
    char* p = ws + off;
    off += (bytes + 255) & ~(size_t)255;
    return p;
  };
  u16* WinT = (u16*)alloc((size_t)1024 * 3072 * 2);  // [n][hi|lo|hi]
  u16* WqkT = (u16*)alloc((size_t)2048 * 3072 * 2);  // rows 0..1023 q, rest k
  u16* WvT = (u16*)alloc((size_t)1024 * 1024 * 2);
  u16* WoutT = (u16*)alloc((size_t)1024 * 1024 * 2);
  u16* W1T = (u16*)alloc((size_t)4096 * 1024 * 2);
  u16* W2T = (u16*)alloc((size_t)1024 * 4096 * 2);
  float* bqk = (float*)alloc(2048 * 4);
  char* R1 = alloc((size_t)8192 * 2048 * 2);  // ln1 -> vf
  char* R2 = alloc((size_t)8192 * 2048 * 2);  // hb  -> ob, ln2
  char* QK = alloc((size_t)2 * 256 * 32 * 4 * 1024);  // qf+kf (64MB) -> ffn1
  const size_t need = off;                            // ~167 MiB

  if (need > ws_size) {  // diagnostic sentinel: ws too small -> absmax ~12345
    fillconst<<<(out_size + 255) / 256, 256, 0, stream>>>(out, 12345.0f,
                                                          out_size);
    return;
  }

  u16* ln1 = (u16*)R1;                              // 32 MiB
  u16* vfb = (u16*)R1;                              // 16 MiB, after ln1 dead
  u16* hb = (u16*)R2;                               // 32 MiB
  u16* ob = (u16*)R2;                               // after hb dead
  u16* ln2 = (u16*)(R2 + (size_t)8192 * 1024 * 2);  // second 16 MiB
  u16* qfb = (u16*)QK;                              // 32 MiB
  u16* kfb = (u16*)(QK + (size_t)256 * 32 * 4 * 1024);  // 32 MiB
  u16* ffn1 = (u16*)QK;                             // after attn, qf/kf dead
  float* x2 = out;                                  // d_out doubles as x2

  // ---- weight prep (bf16 [+split] transposes) ----
  wtrans<2><<<dim3(16, 16, 1), 256, 0, stream>>>(Win, 1024, 0, WinT, 3072, 0,
                                                 1024);
  wtrans<2><<<dim3(1, 16, 16), 256, 0, stream>>>(Wq, 64, 65536, WqkT, 3072,
                                                 (long)64 * 3072, 1024);
  wtrans<2><<<dim3(1, 16, 16), 256, 0, stream>>>(
      Wk, 64, 65536, WqkT + (size_t)1024 * 3072, 3072, (long)64 * 3072, 1024);
  wtrans<0><<<dim3(1, 16, 16), 256, 0, stream>>>(Wv, 64, 65536, WvT, 1024,
                                                 (long)64 * 1024, 0);
  wtrans<0><<<dim3(16, 16, 1), 256, 0, stream>>>(Wout, 1024, 0, WoutT, 1024, 0,
                                                 0);
  wtrans<0><<<dim3(64, 16, 1), 256, 0, stream>>>(W1, 4096, 0, W1T, 1024, 0, 0);
  wtrans<0><<<dim3(16, 64, 1), 256, 0, stream>>>(W2, 1024, 0, W2T, 4096, 0, 0);
  biascat<<<8, 256, 0, stream>>>(bq, bk, bqk);

  // ---- pipeline (all GEMMs: verified r7 config, BM=256) ----
  lnorm<true><<<8192, 256, 0, stream>>>(x, ga, ba, ln1);
  // h = ln1 @ Win + bin  (split-K 3072, split output)
  gemm256<256, 128, EPI_SPLIT><<<256, 512, 0, stream>>>(
      ln1, 2048, 16, WinT, bin, nullptr, hb, nullptr, 2048, 1024, 3072, 3072,
      0);
  // [q|k] = h @ [Wq|Wk]  (split-K, fragment-layout split output)
  gemm256<256, 256, EPI_QKFRAG><<<256, 512, 0, stream>>>(
      hb, 2048, 16, WqkT, bqk, nullptr, qfb, kfb, 0, 2048, 3072, 3072, 0);
  // v = h_hi @ Wv + bv  (fragment layout, overwrites ln1 region: dead)
  gemm256<256, 128, EPI_VFRAG><<<256, 512, 0, stream>>>(
      hb, 2048, 0, WvT, bv, nullptr, vfb, nullptr, 0, 1024, 1024, 1024, 0);
  attn_fwd<<<dim3(4, 256), 256, 0, stream>>>(qfb, kfb, vfb, ob);
  // x2 = o @ Wout + bout + x   (x2 == d_out)
  gemm256<256, 128, EPI_RES><<<256, 512, 0, stream>>>(
      ob, 1024, 0, WoutT, bout, x, x2, nullptr, 1024, 1024, 1024, 1024, 0);
  lnorm<false><<<8192, 256, 0, stream>>>(x2, gf, bf_, ln2);
  // ffn1 = relu(ln2 @ W1 + b1)   (overwrites qf/kf region: dead)
  gemm256<256, 256, EPI_RELU><<<512, 512, 0, stream>>>(
      ln2, 1024, 0, W1T, b1, nullptr, ffn1, nullptr, 4096, 4096, 1024, 1024,
      0);
  // out = ffn1 @ W2 + b2 + x2   (res == Cout == d_out, element-wise safe)
  gemm256<256, 128, EPI_RES><<<256, 512, 0, stream>>>(
      ffn1, 4096, 0, W2T, b2, x2, out, nullptr, 1024, 1024, 4096, 4096, 0);
}

// Round 15
// 439.880 us; speedup vs baseline: 1.0770x; 1.0770x over previous
//
#include <hip/hip_runtime.h>

// ---------------------------------------------------------------------------
// Transformer block (pre-LN attn + FFN), B=16 T=512 D=1024 H=16 HD=64, f32 io.
// bf16 MFMA GEMMs. Precision plan (r15): q/k path now 2-TERM split
// q = h@bf16(W) = hi@Whi + lo@Whi (K'=2048; A=[hi|lo] kdup=0, B=Whi
// re-read via kdupB=16). Dropped term h@W_lo ~ 0.0023 rms -> score err
// ~0.026 rms; calibrated vs measured ULP-floor absmax (2^-5) and v's
// harmless 1-term error. Win GEMM stays 3-term (single-variable change).
// GEMM v3-256 (verified r7/r13, 963 TF on qk): 2 superphases/K-tile,
// counted vmcnt never 0, ring-4 regions, XOR swizzle (0 conflicts),
// XCD swizzle, setprio. Scalar epilogues (r14 staged variant was neutral
// -> reverted to r13's verified form). Schedule variants all refuted
// (4-phase=114, reg-prefetch=111, m201-port=114, 128^2-TLP=+35; v3=107).
// Attention v3 (r13): paired t-groups (g,31-g), 9 iters/wave, grid (4,256).
// Workspace (~151 MiB, liveness-aliased), x2 lives in d_out.
// ---------------------------------------------------------------------------

#define DEV __device__ __forceinline__

typedef unsigned short u16;
typedef __attribute__((ext_vector_type(8))) __bf16 bf16x8;
typedef __attribute__((ext_vector_type(4))) float f32x4;
typedef __attribute__((ext_vector_type(8))) unsigned short u16x8;

typedef __attribute__((address_space(1))) void as1_void;
typedef __attribute__((address_space(3))) void as3_void;

DEV u16 f2b(float f) {                       // f32 -> bf16 RNE (finite inputs)
  unsigned u = __float_as_uint(f);
  u = (u + 0x7fffu + ((u >> 16) & 1u)) >> 16;
  return (u16)u;
}
DEV float b2f(u16 h) { return __uint_as_float(((unsigned)h) << 16); }

DEV f32x4 mfma16(bf16x8 a, bf16x8 b, f32x4 c) {
  return __builtin_amdgcn_mfma_f32_16x16x32_bf16(a, b, c, 0, 0, 0);
}

// async global->LDS, 16B per lane, dest = uniform base + lane*16
DEV void gload16(const void* g, void* l) {
  __builtin_amdgcn_global_load_lds((as1_void*)(unsigned long long)g,
                                   (as3_void*)(unsigned long long)l,
                                   16u, 0, 0u);
}

#define EPI_BF16 0
#define EPI_RELU 1
#define EPI_RES 2
#define EPI_SPLIT 3
#define EPI_QKFRAG 4
#define EPI_VFRAG 5

// ---------------------------------------------------------------------------
// GEMM v3: C[M,N] = A[M,K]*Bt[N,K]^T + bias. BMxBN tile, BK=64.
// kdup  (A): ktA = (kt>=kdup)? kt-kdup : kt  -> A' = [hi, hi, lo]
// kdupB (B): ktB analogous (re-reads B blocks; used for 2-term qk: B=Whi
//            stored once, served for both the hi and lo halves of A).
// Superphase per iteration u (buf cur=u&1):
//   kh0: read A(cur,0)+B(cur,0); stage (u+1).kh1 -> (cur^1,1);
//        MFMA; lgkm0; vmcnt(NWAIT); barrier
//   kh1: read A(cur,1)+B(cur,1); stage (u+2).kh0 -> (cur,0);
//        MFMA; lgkm0; vmcnt(NWAIT); barrier
// NWAIT = 2 stage-groups = 2*(LA+LB). Prologue = 3 groups then vmcnt(NWAIT).
// Tail stages clamp kt; targets are dead regions (counts stay uniform).
// ---------------------------------------------------------------------------
template <int BM, int BN, int EPI>
__global__ __launch_bounds__((BM == 256) ? 512 : 256, 2) void gemm256(
    const u16* __restrict__ A, int lda, int kdup, const u16* __restrict__ Bt,
    const float* __restrict__ bias, const float* __restrict__ res,
    void* __restrict__ Cout, void* __restrict__ Cout2, int ldc, int N, int K,
    int ldb, int kdupB) {
  constexpr int THREADS = (BM == 256) ? 512 : 256;
  constexpr int NWAVE = THREADS / 64;
  constexpr int NWN = (BN == 256) ? 4 : 2;   // n-waves (64 cols each)
  constexpr int NWM = NWAVE / NWN;           // m-waves
  constexpr int MPW = BM / NWM;              // per-wave m rows
  constexpr int MF = MPW / 16;               // m-frags per wave
  constexpr int LA = BM * 4 / THREADS;       // A gloads/thread/stage (=2)
  constexpr int LB = BN * 4 / THREADS;       // B gloads/thread/stage (1 or 2)
  constexpr int NWAIT = 2 * (LA + LB);       // counted vmcnt
  constexpr int ASZ = BM * 64;               // bytes per (buf,ks) A region
  constexpr int BSZ = BN * 64;
  constexpr int ATOT = 4 * ASZ;
  __shared__ __align__(1024) char lds[4 * ASZ + 4 * BSZ];

  // XCD-contiguous block swizzle (gridDim.x % 8 == 0 by construction)
  const int nwg = (int)gridDim.x;
  const int cpx = nwg >> 3;
  int w = (int)blockIdx.x;
  w = (w & 7) * cpx + (w >> 3);
  const int nbn = N / BN;
  const int bn = w % nbn, bm = w / nbn;

  const int tid = threadIdx.x;
  const int wave = tid >> 6, lane = tid & 63;
  const int l15 = lane & 15, l4 = lane >> 4;
  const int wm = wave / NWN;
  const int wn = wave % NWN;
  const int nk = K >> 6;

  // staging source: dest row-in-16-group = lane>>2, dest chunk = lane&3;
  // source holds chunk (lane&3) ^ ((row>>1)&3)  [same involution as reads]
  const int srow = lane >> 2;
  const int schunk = ((lane & 3) ^ ((srow >> 1) & 3)) << 4;
  const char* Ab = (const char*)A;
  const char* Bb = (const char*)Bt;
  const int arowA = wave * (BM / NWAVE) + srow;
  const int arowB = wave * (BN / NWAVE) + srow;

  auto stageA = [&](int buf, int kh, int kt) {
    const int ktA = (kdup && kt >= kdup) ? kt - kdup : kt;
    const char* s = Ab + (size_t)(bm * BM + arowA) * (size_t)(lda * 2) +
                    ktA * 128 + kh * 64 + schunk;
    char* d = lds + (((buf << 1) | kh) * ASZ) + wave * (LA * 1024);
    gload16(s, d);
    gload16(s + (size_t)16 * (size_t)(lda * 2), d + 1024);
  };
  auto stageB = [&](int buf, int kh, int kt) {
    const int ktB = (kdupB && kt >= kdupB) ? kt - kdupB : kt;
    const char* s = Bb + (size_t)(bn * BN + arowB) * (size_t)(ldb * 2) +
                    ktB * 128 + kh * 64 + schunk;
    char* d = lds + ATOT + (((buf << 1) | kh) * BSZ) + wave * (LB * 1024);
    gload16(s, d);
    if (LB == 2) gload16(s + (size_t)16 * (size_t)(ldb * 2), d + 1024);
  };

  const f32x4 fz = {0.f, 0.f, 0.f, 0.f};
  f32x4 acc[MF][4];
#pragma unroll
  for (int i = 0; i < MF; ++i)
#pragma unroll
    for (int j = 0; j < 4; ++j) acc[i][j] = fz;

  // prologue: tile0 full + tile1 kh0, in steady-state issue order
  stageA(0, 0, 0);
  stageB(0, 0, 0);
  stageA(0, 1, 0);
  stageB(0, 1, 0);
  {
    const int k1 = (1 < nk) ? 1 : nk - 1;
    stageA(1, 0, k1);
    stageB(1, 0, k1);
  }
  asm volatile("s_waitcnt vmcnt(%0)" ::"i"(NWAIT) : "memory");
  __builtin_amdgcn_s_barrier();

  for (int u = 0; u < nk; ++u) {
    const int cur = u & 1;
    const int kp1 = (u + 1 < nk) ? u + 1 : nk - 1;
    const int kp2 = (u + 2 < nk) ? u + 2 : nk - 1;
#pragma unroll
    for (int kh = 0; kh < 2; ++kh) {
      const char* Ar = lds + (((cur << 1) | kh) * ASZ);
      const char* Br = lds + ATOT + (((cur << 1) | kh) * BSZ);
      bf16x8 bfr[4], af[MF];
#pragma unroll
      for (int ni = 0; ni < 4; ++ni) {
        const int n = wn * 64 + ni * 16 + l15;
        bfr[ni] = *(const bf16x8*)(Br + n * 64 + ((l4 ^ ((n >> 1) & 3)) << 4));
      }
#pragma unroll
      for (int mi = 0; mi < MF; ++mi) {
        const int m = wm * MPW + mi * 16 + l15;
        af[mi] = *(const bf16x8*)(Ar + m * 64 + ((l4 ^ ((m >> 1) & 3)) << 4));
      }
      if (kh == 0) {
        stageA(cur ^ 1, 1, kp1);
        stageB(cur ^ 1, 1, kp1);
      } else {
        stageA(cur, 0, kp2);
        stageB(cur, 0, kp2);
      }
      __builtin_amdgcn_s_setprio(1);
#pragma unroll
      for (int mi = 0; mi < MF; ++mi)
#pragma unroll
        for (int ni = 0; ni < 4; ++ni)
          acc[mi][ni] = mfma16(af[mi], bfr[ni], acc[mi][ni]);
      __builtin_amdgcn_s_setprio(0);
      // WAR guard: this kh's region is re-staged next superphase.
      asm volatile("s_waitcnt lgkmcnt(0)" ::: "memory");
      // visibility: next superphase's region complete for all waves.
      asm volatile("s_waitcnt vmcnt(%0)" ::"i"(NWAIT) : "memory");
      __builtin_amdgcn_s_barrier();
    }
  }
  asm volatile("s_waitcnt vmcnt(0)" ::: "memory");

  // ---- epilogue (scalar form; r13-verified) ----
#pragma unroll
  for (int mf = 0; mf < MF; ++mf) {
#pragma unroll
    for (int ni = 0; ni < 4; ++ni) {
      const int gn = bn * BN + wn * 64 + ni * 16 + l15;
      const float bia = bias[gn];
#pragma unroll
      for (int r = 0; r < 4; ++r) {
        const int gm = bm * BM + wm * MPW + mf * 16 + l4 * 4 + r;
        float v = acc[mf][ni][r] + bia;
        if (EPI == EPI_BF16) {
          ((u16*)Cout)[(size_t)gm * ldc + gn] = f2b(v);
        } else if (EPI == EPI_RELU) {
          ((u16*)Cout)[(size_t)gm * ldc + gn] = f2b(v > 0.f ? v : 0.f);
        } else if (EPI == EPI_RES) {
          ((float*)Cout)[(size_t)gm * ldc + gn] =
              v + res[(size_t)gm * ldc + gn];
        } else if (EPI == EPI_SPLIT) {  // [hi | lo] planes within row
          u16 hi = f2b(v);
          ((u16*)Cout)[(size_t)gm * ldc + gn] = hi;
          ((u16*)Cout)[(size_t)gm * ldc + N + gn] = f2b(v - b2f(hi));
        } else if (EPI == EPI_QKFRAG) {
          // gm=(b,s); gn<1024: q -> Cout frags; gn>=1024: k -> Cout2.
          const int b = gm >> 9, s = gm & 511;
          const int gs = s >> 4, sr = s & 15;
          const int n = gn & 1023;
          const int h = n >> 6, e = n & 63;
          u16* base = (u16*)((gn >> 10) ? Cout2 : Cout);
          const size_t blk = ((size_t)(b * 16 + h) * 32 + gs) * 4;
          const int idx = ((e >> 3) & 3) * 128 + sr * 8 + (e & 7);
          const u16 hi = f2b(v);
          base[(blk + (e >> 5)) * 512 + idx] = hi;
          base[(blk + 2 + (e >> 5)) * 512 + idx] = f2b(v - b2f(hi));
        } else {  // EPI_VFRAG: B-operand frag for PV
          const int b = gm >> 9, s = gm & 511;
          const int h = gn >> 6, e = gn & 63;
          const size_t blk =
              ((size_t)(b * 16 + h) * 16 + (s >> 5)) * 4 + (e >> 4);
          ((u16*)Cout)[blk * 512 + ((s >> 3) & 3) * 128 + (e & 15) * 8 +
                       (s & 7)] = f2b(v);
        }
      }
    }
  }
}

// ---------------------------------------------------------------------------
// LayerNorm row kernel. SPLIT: out row = [hi(1024) | lo(1024)] (stride 2048).
// ---------------------------------------------------------------------------
template <bool SPLIT>
__global__ __launch_bounds__(256) void lnorm(const float* __restrict__ x,
                                             const float* __restrict__ g,
                                             const float* __restrict__ bt,
                                             u16* __restrict__ out) {
  const int row = blockIdx.x, tid = threadIdx.x;
  const int wave = tid >> 6, lane = tid & 63;
  const float4 v = *(const float4*)(x + (size_t)row * 1024 + tid * 4);
  float xv[4] = {v.x, v.y, v.z, v.w};
  float s = xv[0] + xv[1] + xv[2] + xv[3];
  float s2 = xv[0] * xv[0] + xv[1] * xv[1] + xv[2] * xv[2] + xv[3] * xv[3];
  for (int off = 32; off; off >>= 1) {
    s += __shfl_down(s, off);
    s2 += __shfl_down(s2, off);
  }
  __shared__ float red[8];
  if (lane == 0) {
    red[wave] = s;
    red[4 + wave] = s2;
  }
  __syncthreads();
  const float ts = red[0] + red[1] + red[2] + red[3];
  const float ts2 = red[4] + red[5] + red[6] + red[7];
  const float mean = ts * (1.f / 1024.f);
  const float var = ts2 * (1.f / 1024.f) - mean * mean;
  const float rstd = rsqrtf(var + 1e-5f);
#pragma unroll
  for (int j = 0; j < 4; ++j) {
    const int col = tid * 4 + j;
    const float y = (xv[j] - mean) * rstd * g[col] + bt[col];
    const u16 hi = f2b(y);
    if (SPLIT) {
      out[(size_t)row * 2048 + col] = hi;
      out[(size_t)row * 2048 + 1024 + col] = f2b(y - b2f(hi));
    } else {
      out[(size_t)row * 1024 + col] = hi;
    }
  }
}

// ---------------------------------------------------------------------------
// Weight transpose f32[K][cols] -> bf16 out[n][k] (row stride ors).
// MODE 0: plain hi. MODE 2: triple [hi @0 | lo @Koff | hi @2*Koff].
// grid: (cols/64, K/64, batch)
// ---------------------------------------------------------------------------
template <int MODE>
__global__ __launch_bounds__(256) void wtrans(const float* __restrict__ in,
                                              int kstride, long ibs,
                                              u16* __restrict__ out, int ors,
                                              long obs, int Koff) {
  in += (size_t)blockIdx.z * ibs;
  out += (size_t)blockIdx.z * obs;
  const int n0 = blockIdx.x * 64, k0 = blockIdx.y * 64;
  const int tid = threadIdx.x;
  __shared__ float tt[64][65];
  const int r = tid >> 4, c4 = (tid & 15) * 4;
#pragma unroll
  for (int p = 0; p < 4; ++p) {
    const int rr = r + p * 16;
    const float4 vv =
        *(const float4*)(in + (size_t)(k0 + rr) * kstride + n0 + c4);
    tt[rr][c4] = vv.x;
    tt[rr][c4 + 1] = vv.y;
    tt[rr][c4 + 2] = vv.z;
    tt[rr][c4 + 3] = vv.w;
  }
  __syncthreads();
  const int nl = tid >> 2, kc = (tid & 3) * 16;
  u16 hi[16], lo[16];
#pragma unroll
  for (int j = 0; j < 16; ++j) {
    const float w2 = tt[kc + j][nl];
    hi[j] = f2b(w2);
    if (MODE == 2) lo[j] = f2b(w2 - b2f(hi[j]));
  }
  u16* orow = out + (size_t)(n0 + nl) * ors + k0 + kc;
  u16x8 a, b;
#pragma unroll
  for (int j = 0; j < 8; ++j) {
    a[j] = hi[j];
    b[j] = hi[8 + j];
  }
  *(u16x8*)(orow) = a;
  *(u16x8*)(orow + 8) = b;
  if (MODE == 2) {
    *(u16x8*)(orow + 2 * Koff) = a;
    *(u16x8*)(orow + 2 * Koff + 8) = b;
    u16x8 c, d;
#pragma unroll
    for (int j = 0; j < 8; ++j) {
      c[j] = lo[j];
      d[j] = lo[8 + j];
    }
    *(u16x8*)(orow + Koff) = c;
    *(u16x8*)(orow + Koff + 8) = d;
  }
}

__global__ void biascat(const float* __restrict__ bq,
                        const float* __restrict__ bk, float* __restrict__ o) {
  const int i = blockIdx.x * 256 + threadIdx.x;  // 2048 total
  o[i] = (i < 1024) ? bq[i] : bk[i - 1024];
}

__global__ void fillconst(float* __restrict__ p, float v, int n) {
  const int i = blockIdx.x * 256 + threadIdx.x;
  if (i < n) p[i] = v;
}

// ---------------------------------------------------------------------------
// Flash attention v3: paired t-groups (g, 31-g) per wave, 9 iters each.
// grid (4, B*H). Per-group body identical to verified round-3 kernel.
// ---------------------------------------------------------------------------
__global__ __launch_bounds__(256) void attn_fwd(const u16* __restrict__ qf,
                                                const u16* __restrict__ kf,
                                                const u16* __restrict__ vf,
                                                u16* __restrict__ o) {
  const int bh = blockIdx.y;
  const int b = bh >> 4, h = bh & 15;
  const int tid = threadIdx.x, wave = tid >> 6, lane = tid & 63;
  const int l15 = lane & 15, l4 = lane >> 4;
  const int g0 = (int)blockIdx.x * 4 + wave;  // 0..15
  __shared__ u16 Pl[4][1024];  // per-wave 16x64 bf16 P, 128B rows, swizzled

  const f32x4 fz = {0.f, 0.f, 0.f, 0.f};
  const u16* qfb = qf + (size_t)bh * 32 * 2048 + lane * 8;
  const u16* vfb = vf + (size_t)bh * 16 * 2048 + lane * 8;

  for (int grp = 0; grp < 2; ++grp) {
    const int gt = grp ? (31 - g0) : g0;  // pair (g, 31-g): 9 iters total
    const int tw = gt * 16;
    const u16* kfb = kf + ((size_t)(bh * 32 + gt) * 4) * 512 + lane * 8;
    const bf16x8 kh0 = *(const bf16x8*)(kfb);
    const bf16x8 kh1 = *(const bf16x8*)(kfb + 512);
    const bf16x8 kl0 = *(const bf16x8*)(kfb + 1024);
    const bf16x8 kl1 = *(const bf16x8*)(kfb + 1536);

    f32x4 oacc[4] = {fz, fz, fz, fz};
    float mrow[4] = {-1e30f, -1e30f, -1e30f, -1e30f};
    float lrow[4] = {0.f, 0.f, 0.f, 0.f};
    const int niter = (tw + 79) >> 6;

    for (int it = 0; it < niter; ++it) {
      const int s0 = it * 64;
      bf16x8 qh[4][2], ql[4][2];
#pragma unroll
      for (int scb = 0; scb < 4; ++scb) {
        const u16* qp = qfb + (size_t)((s0 >> 4) + scb) * 2048;
        qh[scb][0] = *(const bf16x8*)(qp);
        qh[scb][1] = *(const bf16x8*)(qp + 512);
        ql[scb][0] = *(const bf16x8*)(qp + 1024);
        ql[scb][1] = *(const bf16x8*)(qp + 1536);
      }
      bf16x8 vv[2][4];
#pragma unroll
      for (int h2 = 0; h2 < 2; ++h2) {
        const u16* vp = vfb + (size_t)((s0 >> 5) + h2) * 2048;
#pragma unroll
        for (int eF = 0; eF < 4; ++eF)
          vv[h2][eF] = *(const bf16x8*)(vp + eF * 512);
      }
      f32x4 sf[4];
#pragma unroll
      for (int scb = 0; scb < 4; ++scb) {
        f32x4 z = fz;
        z = mfma16(kh0, qh[scb][0], z);
        z = mfma16(kh1, qh[scb][1], z);
        z = mfma16(kh0, ql[scb][0], z);
        z = mfma16(kh1, ql[scb][1], z);
        z = mfma16(kl0, qh[scb][0], z);
        z = mfma16(kl1, qh[scb][1], z);
        sf[scb] = z;
      }
      if (s0 + 63 > tw) {
#pragma unroll
        for (int scb = 0; scb < 4; ++scb)
#pragma unroll
          for (int r = 0; r < 4; ++r) {
            const int s = s0 + scb * 16 + l15, t = tw + l4 * 4 + r;
            if (s > t) sf[scb][r] = -1e30f;
          }
      }
      float scl[4];
#pragma unroll
      for (int r = 0; r < 4; ++r) {
        float v = fmaxf(fmaxf(sf[0][r], sf[1][r]), fmaxf(sf[2][r], sf[3][r]));
        v = fmaxf(v, __shfl_xor(v, 1));
        v = fmaxf(v, __shfl_xor(v, 2));
        v = fmaxf(v, __shfl_xor(v, 4));
        v = fmaxf(v, __shfl_xor(v, 8));
        const float mn = fmaxf(mrow[r], v);
        scl[r] = __expf(mrow[r] - mn);
        mrow[r] = mn;
      }
      float ps[4] = {0.f, 0.f, 0.f, 0.f};
#pragma unroll
      for (int scb = 0; scb < 4; ++scb)
#pragma unroll
        for (int r = 0; r < 4; ++r) {
          const float p = __expf(sf[scb][r] - mrow[r]);
          sf[scb][r] = p;
          ps[r] += p;
        }
#pragma unroll
      for (int r = 0; r < 4; ++r) {
        float v = ps[r];
        v += __shfl_xor(v, 1);
        v += __shfl_xor(v, 2);
        v += __shfl_xor(v, 4);
        v += __shfl_xor(v, 8);
        lrow[r] = lrow[r] * scl[r] + v;
        oacc[0][r] *= scl[r];
        oacc[1][r] *= scl[r];
        oacc[2][r] *= scl[r];
        oacc[3][r] *= scl[r];
      }
#pragma unroll
      for (int scb = 0; scb < 4; ++scb)
#pragma unroll
        for (int r = 0; r < 4; ++r) {
          const int trow = l4 * 4 + r, scol = scb * 16 + l15;
          const int byte = trow * 128 + ((scol * 2) ^ ((trow & 7) << 4));
          *(u16*)((char*)&Pl[wave][0] + byte) = f2b(sf[scb][r]);
        }
#pragma unroll
      for (int h2 = 0; h2 < 2; ++h2) {
        const bf16x8 pf = *(const bf16x8*)((const char*)&Pl[wave][0] +
                                           l15 * 128 +
                                           (((h2 * 4 + l4) ^ (l15 & 7)) << 4));
#pragma unroll
        for (int eF = 0; eF < 4; ++eF)
          oacc[eF] = mfma16(pf, vv[h2][eF], oacc[eF]);
      }
    }
#pragma unroll
    for (int eF = 0; eF < 4; ++eF)
#pragma unroll
      for (int r = 0; r < 4; ++r) {
        const int t = tw + l4 * 4 + r;
        const float val = oacc[eF][r] / lrow[r];
        o[(size_t)(b * 512 + t) * 1024 + h * 64 + eF * 16 + l15] = f2b(val);
      }
  }
}

// ---------------------------------------------------------------------------
extern "C" void kernel_launch(void* const* d_in, const int* in_sizes, int n_in,
                              void* d_out, int out_size, void* d_ws,
                              size_t ws_size, hipStream_t stream) {
  const float* x = (const float*)d_in[0];
  const float* ga = (const float*)d_in[1];
  const float* ba = (const float*)d_in[2];
  const float* Win = (const float*)d_in[3];
  const float* bin = (const float*)d_in[4];
  const float* Wk = (const float*)d_in[5];
  const float* bk = (const float*)d_in[6];
  const float* Wq = (const float*)d_in[7];
  const float* bq = (const float*)d_in[8];
  const float* Wv = (const float*)d_in[9];
  const float* bv = (const float*)d_in[10];
  const float* Wout = (const float*)d_in[11];
  const float* bout = (const float*)d_in[12];
  const float* gf = (const float*)d_in[13];
  const float* bf_ = (const float*)d_in[14];
  const float* W1 = (const float*)d_in[15];
  const float* b1 = (const float*)d_in[16];
  const float* W2 = (const float*)d_in[17];
  const float* b2 = (const float*)d_in[18];
  float* out = (float*)d_out;

  char* ws = (char*)d_ws;
  size_t off = 0;
  auto alloc = [&](size_t bytes) {
    char* p = ws + off;
    off += (bytes + 255) & ~(size_t)255;
    return p;
  };
  u16* WinT = (u16*)alloc((size_t)1024 * 3072 * 2);  // [n][hi|lo|hi] 3-term
  u16* WqkT = (u16*)alloc((size_t)2048 * 1024 * 2);  // [n][Whi] (2-term qk)
  u16* WvT = (u16*)alloc((size_t)1024 * 1024 * 2);
  u16* WoutT = (u16*)alloc((size_t)1024 * 1024 * 2);
  u16* W1T = (u16*)alloc((size_t)4096 * 1024 * 2);
  u16* W2T = (u16*)alloc((size_t)1024 * 4096 * 2);
  float* bqk = (float*)alloc(2048 * 4);
  char* R1 = alloc((size_t)8192 * 2048 * 2);  // ln1 -> vf
  char* R2 = alloc((size_t)8192 * 2048 * 2);  // hb  -> ob, ln2
  char* QK = alloc((size_t)2 * 256 * 32 * 4 * 1024);  // qf+kf (64MB) -> ffn1
  const size_t need = off;                            // ~151 MiB

  if (need > ws_size) {  // diagnostic sentinel: ws too small -> absmax ~12345
    fillconst<<<(out_size + 255) / 256, 256, 0, stream>>>(out, 12345.0f,
                                                          out_size);
    return;
  }

  u16* ln1 = (u16*)R1;                              // 32 MiB
  u16* vfb = (u16*)R1;                              // 16 MiB, after ln1 dead
  u16* hb = (u16*)R2;                               // 32 MiB
  u16* ob = (u16*)R2;                               // after hb dead
  u16* ln2 = (u16*)(R2 + (size_t)8192 * 1024 * 2);  // second 16 MiB
  u16* qfb = (u16*)QK;                              // 32 MiB
  u16* kfb = (u16*)(QK + (size_t)256 * 32 * 4 * 1024);  // 32 MiB
  u16* ffn1 = (u16*)QK;                             // after attn, qf/kf dead
  float* x2 = out;                                  // d_out doubles as x2

  // ---- weight prep (bf16 [+split] transposes) ----
  wtrans<2><<<dim3(16, 16, 1), 256, 0, stream>>>(Win, 1024, 0, WinT, 3072, 0,
                                                 1024);
  wtrans<0><<<dim3(1, 16, 16), 256, 0, stream>>>(Wq, 64, 65536, WqkT, 1024,
                                                 (long)64 * 1024, 0);
  wtrans<0><<<dim3(1, 16, 16), 256, 0, stream>>>(
      Wk, 64, 65536, WqkT + (size_t)1024 * 1024, 1024, (long)64 * 1024, 0);
  wtrans<0><<<dim3(1, 16, 16), 256, 0, stream>>>(Wv, 64, 65536, WvT, 1024,
                                                 (long)64 * 1024, 0);
  wtrans<0><<<dim3(16, 16, 1), 256, 0, stream>>>(Wout, 1024, 0, WoutT, 1024, 0,
                                                 0);
  wtrans<0><<<dim3(64, 16, 1), 256, 0, stream>>>(W1, 4096, 0, W1T, 1024, 0, 0);
  wtrans<0><<<dim3(16, 64, 1), 256, 0, stream>>>(W2, 1024, 0, W2T, 4096, 0, 0);
  biascat<<<8, 256, 0, stream>>>(bq, bk, bqk);

  // ---- pipeline (all GEMMs: verified r7 config, BM=256) ----
  lnorm<true><<<8192, 256, 0, stream>>>(x, ga, ba, ln1);
  // h = ln1 @ Win + bin  (3-term split-K 3072, split output)
  gemm256<256, 128, EPI_SPLIT><<<256, 512, 0, stream>>>(
      ln1, 2048, 16, WinT, bin, nullptr, hb, nullptr, 2048, 1024, 3072, 3072,
      0);
  // [q|k] = h @ [Wq|Wk]_hi  (2-TERM: A=[hi|lo] straight K=2048, kdup=0;
  //  B=Whi re-read via kdupB=16 -> (hi+lo)@Whi = h@bf16(W))
  gemm256<256, 256, EPI_QKFRAG><<<256, 512, 0, stream>>>(
      hb, 2048, 0, WqkT, bqk, nullptr, qfb, kfb, 0, 2048, 2048, 1024, 16);
  // v = h_hi @ Wv + bv  (fragment layout, overwrites ln1 region: dead)
  gemm256<256, 128, EPI_VFRAG><<<256, 512, 0, stream>>>(
      hb, 2048, 0, WvT, bv, nullptr, vfb, nullptr, 0, 1024, 1024, 1024, 0);
  attn_fwd<<<dim3(4, 256), 256, 0, stream>>>(qfb, kfb, vfb, ob);
  // x2 = o @ Wout + bout + x   (x2 == d_out)
  gemm256<256, 128, EPI_RES><<<256, 512, 0, stream>>>(
      ob, 1024, 0, WoutT, bout, x, x2, nullptr, 1024, 1024, 1024, 1024, 0);
  lnorm<false><<<8192, 256, 0, stream>>>(x2, gf, bf_, ln2);
  // ffn1 = relu(ln2 @ W1 + b1)   (overwrites qf/kf region: dead)
  gemm256<256, 256, EPI_RELU><<<512, 512, 0, stream>>>(
      ln2, 1024, 0, W1T, b1, nullptr, ffn1, nullptr, 4096, 4096, 1024, 1024,
      0);
  // out = ffn1 @ W2 + b2 + x2   (res == Cout == d_out, element-wise safe)
  gemm256<256, 128, EPI_RES><<<256, 512, 0, stream>>>(
      ffn1, 4096, 0, W2T, b2, x2, out, nullptr, 1024, 1024, 4096, 4096, 0);
}

// Round 16
// 421.764 us; speedup vs baseline: 1.1233x; 1.0430x over previous
//
#include <hip/hip_runtime.h>

// ---------------------------------------------------------------------------
// Transformer block (pre-LN attn + FFN), B=16 T=512 D=1024 H=16 HD=64, f32 io.
// bf16 MFMA GEMMs. Precision plan (r15/r16): q/k path 2-TERM split
// q = h@bf16(W) = hi@Whi + lo@Whi (K'=2048, kdupB re-read) — verified r15:
// absmax 0.0625 (2.5x margin). r16: Win GEMM also 2-term,
// h = ln1@bf16(Win) = (ln1_hi+ln1_lo)@Win_hi (K'=2048, kdupB=16); dropped
// term ln1@Win_lo ~0.002 rms -> +14% score err in quadrature (calibrated).
// GEMM v3-256 (verified r7/r13, 963 TF): 2 superphases/K-tile, counted
// vmcnt never 0, ring-4 regions, XOR swizzle (0 conflicts), XCD swizzle,
// setprio, scalar epilogues. Schedule variants all refuted
// (4-phase=114, reg-prefetch=111, m201-port=114, 128^2-TLP=+35; v3=107->80).
// Attention v3 (r13): paired t-groups (g,31-g), 9 iters/wave, grid (4,256).
// Workspace (~147 MiB, liveness-aliased), x2 lives in d_out.
// ---------------------------------------------------------------------------

#define DEV __device__ __forceinline__

typedef unsigned short u16;
typedef __attribute__((ext_vector_type(8))) __bf16 bf16x8;
typedef __attribute__((ext_vector_type(4))) float f32x4;
typedef __attribute__((ext_vector_type(8))) unsigned short u16x8;

typedef __attribute__((address_space(1))) void as1_void;
typedef __attribute__((address_space(3))) void as3_void;

DEV u16 f2b(float f) {                       // f32 -> bf16 RNE (finite inputs)
  unsigned u = __float_as_uint(f);
  u = (u + 0x7fffu + ((u >> 16) & 1u)) >> 16;
  return (u16)u;
}
DEV float b2f(u16 h) { return __uint_as_float(((unsigned)h) << 16); }

DEV f32x4 mfma16(bf16x8 a, bf16x8 b, f32x4 c) {
  return __builtin_amdgcn_mfma_f32_16x16x32_bf16(a, b, c, 0, 0, 0);
}

// async global->LDS, 16B per lane, dest = uniform base + lane*16
DEV void gload16(const void* g, void* l) {
  __builtin_amdgcn_global_load_lds((as1_void*)(unsigned long long)g,
                                   (as3_void*)(unsigned long long)l,
                                   16u, 0, 0u);
}

#define EPI_BF16 0
#define EPI_RELU 1
#define EPI_RES 2
#define EPI_SPLIT 3
#define EPI_QKFRAG 4
#define EPI_VFRAG 5

// ---------------------------------------------------------------------------
// GEMM v3: C[M,N] = A[M,K]*Bt[N,K]^T + bias. BMxBN tile, BK=64.
// kdup  (A): ktA = (kt>=kdup)? kt-kdup : kt  -> A' = [hi, hi, lo]
// kdupB (B): ktB analogous (re-reads B blocks; 2-term paths: B=Whi stored
//            once, served for both the hi and lo halves of A).
// Superphase per iteration u (buf cur=u&1):
//   kh0: read A(cur,0)+B(cur,0); stage (u+1).kh1 -> (cur^1,1);
//        MFMA; lgkm0; vmcnt(NWAIT); barrier
//   kh1: read A(cur,1)+B(cur,1); stage (u+2).kh0 -> (cur,0);
//        MFMA; lgkm0; vmcnt(NWAIT); barrier
// NWAIT = 2 stage-groups = 2*(LA+LB). Prologue = 3 groups then vmcnt(NWAIT).
// Tail stages clamp kt; targets are dead regions (counts stay uniform).
// ---------------------------------------------------------------------------
template <int BM, int BN, int EPI>
__global__ __launch_bounds__((BM == 256) ? 512 : 256, 2) void gemm256(
    const u16* __restrict__ A, int lda, int kdup, const u16* __restrict__ Bt,
    const float* __restrict__ bias, const float* __restrict__ res,
    void* __restrict__ Cout, void* __restrict__ Cout2, int ldc, int N, int K,
    int ldb, int kdupB) {
  constexpr int THREADS = (BM == 256) ? 512 : 256;
  constexpr int NWAVE = THREADS / 64;
  constexpr int NWN = (BN == 256) ? 4 : 2;   // n-waves (64 cols each)
  constexpr int NWM = NWAVE / NWN;           // m-waves
  constexpr int MPW = BM / NWM;              // per-wave m rows
  constexpr int MF = MPW / 16;               // m-frags per wave
  constexpr int LA = BM * 4 / THREADS;       // A gloads/thread/stage (=2)
  constexpr int LB = BN * 4 / THREADS;       // B gloads/thread/stage (1 or 2)
  constexpr int NWAIT = 2 * (LA + LB);       // counted vmcnt
  constexpr int ASZ = BM * 64;               // bytes per (buf,ks) A region
  constexpr int BSZ = BN * 64;
  constexpr int ATOT = 4 * ASZ;
  __shared__ __align__(1024) char lds[4 * ASZ + 4 * BSZ];

  // XCD-contiguous block swizzle (gridDim.x % 8 == 0 by construction)
  const int nwg = (int)gridDim.x;
  const int cpx = nwg >> 3;
  int w = (int)blockIdx.x;
  w = (w & 7) * cpx + (w >> 3);
  const int nbn = N / BN;
  const int bn = w % nbn, bm = w / nbn;

  const int tid = threadIdx.x;
  const int wave = tid >> 6, lane = tid & 63;
  const int l15 = lane & 15, l4 = lane >> 4;
  const int wm = wave / NWN;
  const int wn = wave % NWN;
  const int nk = K >> 6;

  // staging source: dest row-in-16-group = lane>>2, dest chunk = lane&3;
  // source holds chunk (lane&3) ^ ((row>>1)&3)  [same involution as reads]
  const int srow = lane >> 2;
  const int schunk = ((lane & 3) ^ ((srow >> 1) & 3)) << 4;
  const char* Ab = (const char*)A;
  const char* Bb = (const char*)Bt;
  const int arowA = wave * (BM / NWAVE) + srow;
  const int arowB = wave * (BN / NWAVE) + srow;

  auto stageA = [&](int buf, int kh, int kt) {
    const int ktA = (kdup && kt >= kdup) ? kt - kdup : kt;
    const char* s = Ab + (size_t)(bm * BM + arowA) * (size_t)(lda * 2) +
                    ktA * 128 + kh * 64 + schunk;
    char* d = lds + (((buf << 1) | kh) * ASZ) + wave * (LA * 1024);
    gload16(s, d);
    gload16(s + (size_t)16 * (size_t)(lda * 2), d + 1024);
  };
  auto stageB = [&](int buf, int kh, int kt) {
    const int ktB = (kdupB && kt >= kdupB) ? kt - kdupB : kt;
    const char* s = Bb + (size_t)(bn * BN + arowB) * (size_t)(ldb * 2) +
                    ktB * 128 + kh * 64 + schunk;
    char* d = lds + ATOT + (((buf << 1) | kh) * BSZ) + wave * (LB * 1024);
    gload16(s, d);
    if (LB == 2) gload16(s + (size_t)16 * (size_t)(ldb * 2), d + 1024);
  };

  const f32x4 fz = {0.f, 0.f, 0.f, 0.f};
  f32x4 acc[MF][4];
#pragma unroll
  for (int i = 0; i < MF; ++i)
#pragma unroll
    for (int j = 0; j < 4; ++j) acc[i][j] = fz;

  // prologue: tile0 full + tile1 kh0, in steady-state issue order
  stageA(0, 0, 0);
  stageB(0, 0, 0);
  stageA(0, 1, 0);
  stageB(0, 1, 0);
  {
    const int k1 = (1 < nk) ? 1 : nk - 1;
    stageA(1, 0, k1);
    stageB(1, 0, k1);
  }
  asm volatile("s_waitcnt vmcnt(%0)" ::"i"(NWAIT) : "memory");
  __builtin_amdgcn_s_barrier();

  for (int u = 0; u < nk; ++u) {
    const int cur = u & 1;
    const int kp1 = (u + 1 < nk) ? u + 1 : nk - 1;
    const int kp2 = (u + 2 < nk) ? u + 2 : nk - 1;
#pragma unroll
    for (int kh = 0; kh < 2; ++kh) {
      const char* Ar = lds + (((cur << 1) | kh) * ASZ);
      const char* Br = lds + ATOT + (((cur << 1) | kh) * BSZ);
      bf16x8 bfr[4], af[MF];
#pragma unroll
      for (int ni = 0; ni < 4; ++ni) {
        const int n = wn * 64 + ni * 16 + l15;
        bfr[ni] = *(const bf16x8*)(Br + n * 64 + ((l4 ^ ((n >> 1) & 3)) << 4));
      }
#pragma unroll
      for (int mi = 0; mi < MF; ++mi) {
        const int m = wm * MPW + mi * 16 + l15;
        af[mi] = *(const bf16x8*)(Ar + m * 64 + ((l4 ^ ((m >> 1) & 3)) << 4));
      }
      if (kh == 0) {
        stageA(cur ^ 1, 1, kp1);
        stageB(cur ^ 1, 1, kp1);
      } else {
        stageA(cur, 0, kp2);
        stageB(cur, 0, kp2);
      }
      __builtin_amdgcn_s_setprio(1);
#pragma unroll
      for (int mi = 0; mi < MF; ++mi)
#pragma unroll
        for (int ni = 0; ni < 4; ++ni)
          acc[mi][ni] = mfma16(af[mi], bfr[ni], acc[mi][ni]);
      __builtin_amdgcn_s_setprio(0);
      // WAR guard: this kh's region is re-staged next superphase.
      asm volatile("s_waitcnt lgkmcnt(0)" ::: "memory");
      // visibility: next superphase's region complete for all waves.
      asm volatile("s_waitcnt vmcnt(%0)" ::"i"(NWAIT) : "memory");
      __builtin_amdgcn_s_barrier();
    }
  }
  asm volatile("s_waitcnt vmcnt(0)" ::: "memory");

  // ---- epilogue (scalar form; r13-verified) ----
#pragma unroll
  for (int mf = 0; mf < MF; ++mf) {
#pragma unroll
    for (int ni = 0; ni < 4; ++ni) {
      const int gn = bn * BN + wn * 64 + ni * 16 + l15;
      const float bia = bias[gn];
#pragma unroll
      for (int r = 0; r < 4; ++r) {
        const int gm = bm * BM + wm * MPW + mf * 16 + l4 * 4 + r;
        float v = acc[mf][ni][r] + bia;
        if (EPI == EPI_BF16) {
          ((u16*)Cout)[(size_t)gm * ldc + gn] = f2b(v);
        } else if (EPI == EPI_RELU) {
          ((u16*)Cout)[(size_t)gm * ldc + gn] = f2b(v > 0.f ? v : 0.f);
        } else if (EPI == EPI_RES) {
          ((float*)Cout)[(size_t)gm * ldc + gn] =
              v + res[(size_t)gm * ldc + gn];
        } else if (EPI == EPI_SPLIT) {  // [hi | lo] planes within row
          u16 hi = f2b(v);
          ((u16*)Cout)[(size_t)gm * ldc + gn] = hi;
          ((u16*)Cout)[(size_t)gm * ldc + N + gn] = f2b(v - b2f(hi));
        } else if (EPI == EPI_QKFRAG) {
          // gm=(b,s); gn<1024: q -> Cout frags; gn>=1024: k -> Cout2.
          const int b = gm >> 9, s = gm & 511;
          const int gs = s >> 4, sr = s & 15;
          const int n = gn & 1023;
          const int h = n >> 6, e = n & 63;
          u16* base = (u16*)((gn >> 10) ? Cout2 : Cout);
          const size_t blk = ((size_t)(b * 16 + h) * 32 + gs) * 4;
          const int idx = ((e >> 3) & 3) * 128 + sr * 8 + (e & 7);
          const u16 hi = f2b(v);
          base[(blk + (e >> 5)) * 512 + idx] = hi;
          base[(blk + 2 + (e >> 5)) * 512 + idx] = f2b(v - b2f(hi));
        } else {  // EPI_VFRAG: B-operand frag for PV
          const int b = gm >> 9, s = gm & 511;
          const int h = gn >> 6, e = gn & 63;
          const size_t blk =
              ((size_t)(b * 16 + h) * 16 + (s >> 5)) * 4 + (e >> 4);
          ((u16*)Cout)[blk * 512 + ((s >> 3) & 3) * 128 + (e & 15) * 8 +
                       (s & 7)] = f2b(v);
        }
      }
    }
  }
}

// ---------------------------------------------------------------------------
// LayerNorm row kernel. SPLIT: out row = [hi(1024) | lo(1024)] (stride 2048).
// ---------------------------------------------------------------------------
template <bool SPLIT>
__global__ __launch_bounds__(256) void lnorm(const float* __restrict__ x,
                                             const float* __restrict__ g,
                                             const float* __restrict__ bt,
                                             u16* __restrict__ out) {
  const int row = blockIdx.x, tid = threadIdx.x;
  const int wave = tid >> 6, lane = tid & 63;
  const float4 v = *(const float4*)(x + (size_t)row * 1024 + tid * 4);
  float xv[4] = {v.x, v.y, v.z, v.w};
  float s = xv[0] + xv[1] + xv[2] + xv[3];
  float s2 = xv[0] * xv[0] + xv[1] * xv[1] + xv[2] * xv[2] + xv[3] * xv[3];
  for (int off = 32; off; off >>= 1) {
    s += __shfl_down(s, off);
    s2 += __shfl_down(s2, off);
  }
  __shared__ float red[8];
  if (lane == 0) {
    red[wave] = s;
    red[4 + wave] = s2;
  }
  __syncthreads();
  const float ts = red[0] + red[1] + red[2] + red[3];
  const float ts2 = red[4] + red[5] + red[6] + red[7];
  const float mean = ts * (1.f / 1024.f);
  const float var = ts2 * (1.f / 1024.f) - mean * mean;
  const float rstd = rsqrtf(var + 1e-5f);
#pragma unroll
  for (int j = 0; j < 4; ++j) {
    const int col = tid * 4 + j;
    const float y = (xv[j] - mean) * rstd * g[col] + bt[col];
    const u16 hi = f2b(y);
    if (SPLIT) {
      out[(size_t)row * 2048 + col] = hi;
      out[(size_t)row * 2048 + 1024 + col] = f2b(y - b2f(hi));
    } else {
      out[(size_t)row * 1024 + col] = hi;
    }
  }
}

// ---------------------------------------------------------------------------
// Weight transpose f32[K][cols] -> bf16 out[n][k] (row stride ors).
// MODE 0: plain hi. MODE 2: triple [hi @0 | lo @Koff | hi @2*Koff].
// grid: (cols/64, K/64, batch)
// ---------------------------------------------------------------------------
template <int MODE>
__global__ __launch_bounds__(256) void wtrans(const float* __restrict__ in,
                                              int kstride, long ibs,
                                              u16* __restrict__ out, int ors,
                                              long obs, int Koff) {
  in += (size_t)blockIdx.z * ibs;
  out += (size_t)blockIdx.z * obs;
  const int n0 = blockIdx.x * 64, k0 = blockIdx.y * 64;
  const int tid = threadIdx.x;
  __shared__ float tt[64][65];
  const int r = tid >> 4, c4 = (tid & 15) * 4;
#pragma unroll
  for (int p = 0; p < 4; ++p) {
    const int rr = r + p * 16;
    const float4 vv =
        *(const float4*)(in + (size_t)(k0 + rr) * kstride + n0 + c4);
    tt[rr][c4] = vv.x;
    tt[rr][c4 + 1] = vv.y;
    tt[rr][c4 + 2] = vv.z;
    tt[rr][c4 + 3] = vv.w;
  }
  __syncthreads();
  const int nl = tid >> 2, kc = (tid & 3) * 16;
  u16 hi[16], lo[16];
#pragma unroll
  for (int j = 0; j < 16; ++j) {
    const float w2 = tt[kc + j][nl];
    hi[j] = f2b(w2);
    if (MODE == 2) lo[j] = f2b(w2 - b2f(hi[j]));
  }
  u16* orow = out + (size_t)(n0 + nl) * ors + k0 + kc;
  u16x8 a, b;
#pragma unroll
  for (int j = 0; j < 8; ++j) {
    a[j] = hi[j];
    b[j] = hi[8 + j];
  }
  *(u16x8*)(orow) = a;
  *(u16x8*)(orow + 8) = b;
  if (MODE == 2) {
    *(u16x8*)(orow + 2 * Koff) = a;
    *(u16x8*)(orow + 2 * Koff + 8) = b;
    u16x8 c, d;
#pragma unroll
    for (int j = 0; j < 8; ++j) {
      c[j] = lo[j];
      d[j] = lo[8 + j];
    }
    *(u16x8*)(orow + Koff) = c;
    *(u16x8*)(orow + Koff + 8) = d;
  }
}

__global__ void biascat(const float* __restrict__ bq,
                        const float* __restrict__ bk, float* __restrict__ o) {
  const int i = blockIdx.x * 256 + threadIdx.x;  // 2048 total
  o[i] = (i < 1024) ? bq[i] : bk[i - 1024];
}

__global__ void fillconst(float* __restrict__ p, float v, int n) {
  const int i = blockIdx.x * 256 + threadIdx.x;
  if (i < n) p[i] = v;
}

// ---------------------------------------------------------------------------
// Flash attention v3: paired t-groups (g, 31-g) per wave, 9 iters each.
// grid (4, B*H). Per-group body identical to verified round-3 kernel.
// ---------------------------------------------------------------------------
__global__ __launch_bounds__(256) void attn_fwd(const u16* __restrict__ qf,
                                                const u16* __restrict__ kf,
                                                const u16* __restrict__ vf,
                                                u16* __restrict__ o) {
  const int bh = blockIdx.y;
  const int b = bh >> 4, h = bh & 15;
  const int tid = threadIdx.x, wave = tid >> 6, lane = tid & 63;
  const int l15 = lane & 15, l4 = lane >> 4;
  const int g0 = (int)blockIdx.x * 4 + wave;  // 0..15
  __shared__ u16 Pl[4][1024];  // per-wave 16x64 bf16 P, 128B rows, swizzled

  const f32x4 fz = {0.f, 0.f, 0.f, 0.f};
  const u16* qfb = qf + (size_t)bh * 32 * 2048 + lane * 8;
  const u16* vfb = vf + (size_t)bh * 16 * 2048 + lane * 8;

  for (int grp = 0; grp < 2; ++grp) {
    const int gt = grp ? (31 - g0) : g0;  // pair (g, 31-g): 9 iters total
    const int tw = gt * 16;
    const u16* kfb = kf + ((size_t)(bh * 32 + gt) * 4) * 512 + lane * 8;
    const bf16x8 kh0 = *(const bf16x8*)(kfb);
    const bf16x8 kh1 = *(const bf16x8*)(kfb + 512);
    const bf16x8 kl0 = *(const bf16x8*)(kfb + 1024);
    const bf16x8 kl1 = *(const bf16x8*)(kfb + 1536);

    f32x4 oacc[4] = {fz, fz, fz, fz};
    float mrow[4] = {-1e30f, -1e30f, -1e30f, -1e30f};
    float lrow[4] = {0.f, 0.f, 0.f, 0.f};
    const int niter = (tw + 79) >> 6;

    for (int it = 0; it < niter; ++it) {
      const int s0 = it * 64;
      bf16x8 qh[4][2], ql[4][2];
#pragma unroll
      for (int scb = 0; scb < 4; ++scb) {
        const u16* qp = qfb + (size_t)((s0 >> 4) + scb) * 2048;
        qh[scb][0] = *(const bf16x8*)(qp);
        qh[scb][1] = *(const bf16x8*)(qp + 512);
        ql[scb][0] = *(const bf16x8*)(qp + 1024);
        ql[scb][1] = *(const bf16x8*)(qp + 1536);
      }
      bf16x8 vv[2][4];
#pragma unroll
      for (int h2 = 0; h2 < 2; ++h2) {
        const u16* vp = vfb + (size_t)((s0 >> 5) + h2) * 2048;
#pragma unroll
        for (int eF = 0; eF < 4; ++eF)
          vv[h2][eF] = *(const bf16x8*)(vp + eF * 512);
      }
      f32x4 sf[4];
#pragma unroll
      for (int scb = 0; scb < 4; ++scb) {
        f32x4 z = fz;
        z = mfma16(kh0, qh[scb][0], z);
        z = mfma16(kh1, qh[scb][1], z);
        z = mfma16(kh0, ql[scb][0], z);
        z = mfma16(kh1, ql[scb][1], z);
        z = mfma16(kl0, qh[scb][0], z);
        z = mfma16(kl1, qh[scb][1], z);
        sf[scb] = z;
      }
      if (s0 + 63 > tw) {
#pragma unroll
        for (int scb = 0; scb < 4; ++scb)
#pragma unroll
          for (int r = 0; r < 4; ++r) {
            const int s = s0 + scb * 16 + l15, t = tw + l4 * 4 + r;
            if (s > t) sf[scb][r] = -1e30f;
          }
      }
      float scl[4];
#pragma unroll
      for (int r = 0; r < 4; ++r) {
        float v = fmaxf(fmaxf(sf[0][r], sf[1][r]), fmaxf(sf[2][r], sf[3][r]));
        v = fmaxf(v, __shfl_xor(v, 1));
        v = fmaxf(v, __shfl_xor(v, 2));
        v = fmaxf(v, __shfl_xor(v, 4));
        v = fmaxf(v, __shfl_xor(v, 8));
        const float mn = fmaxf(mrow[r], v);
        scl[r] = __expf(mrow[r] - mn);
        mrow[r] = mn;
      }
      float ps[4] = {0.f, 0.f, 0.f, 0.f};
#pragma unroll
      for (int scb = 0; scb < 4; ++scb)
#pragma unroll
        for (int r = 0; r < 4; ++r) {
          const float p = __expf(sf[scb][r] - mrow[r]);
          sf[scb][r] = p;
          ps[r] += p;
        }
#pragma unroll
      for (int r = 0; r < 4; ++r) {
        float v = ps[r];
        v += __shfl_xor(v, 1);
        v += __shfl_xor(v, 2);
        v += __shfl_xor(v, 4);
        v += __shfl_xor(v, 8);
        lrow[r] = lrow[r] * scl[r] + v;
        oacc[0][r] *= scl[r];
        oacc[1][r] *= scl[r];
        oacc[2][r] *= scl[r];
        oacc[3][r] *= scl[r];
      }
#pragma unroll
      for (int scb = 0; scb < 4; ++scb)
#pragma unroll
        for (int r = 0; r < 4; ++r) {
          const int trow = l4 * 4 + r, scol = scb * 16 + l15;
          const int byte = trow * 128 + ((scol * 2) ^ ((trow & 7) << 4));
          *(u16*)((char*)&Pl[wave][0] + byte) = f2b(sf[scb][r]);
        }
#pragma unroll
      for (int h2 = 0; h2 < 2; ++h2) {
        const bf16x8 pf = *(const bf16x8*)((const char*)&Pl[wave][0] +
                                           l15 * 128 +
                                           (((h2 * 4 + l4) ^ (l15 & 7)) << 4));
#pragma unroll
        for (int eF = 0; eF < 4; ++eF)
          oacc[eF] = mfma16(pf, vv[h2][eF], oacc[eF]);
      }
    }
#pragma unroll
    for (int eF = 0; eF < 4; ++eF)
#pragma unroll
      for (int r = 0; r < 4; ++r) {
        const int t = tw + l4 * 4 + r;
        const float val = oacc[eF][r] / lrow[r];
        o[(size_t)(b * 512 + t) * 1024 + h * 64 + eF * 16 + l15] = f2b(val);
      }
  }
}

// ---------------------------------------------------------------------------
extern "C" void kernel_launch(void* const* d_in, const int* in_sizes, int n_in,
                              void* d_out, int out_size, void* d_ws,
                              size_t ws_size, hipStream_t stream) {
  const float* x = (const float*)d_in[0];
  const float* ga = (const float*)d_in[1];
  const float* ba = (const float*)d_in[2];
  const float* Win = (const float*)d_in[3];
  const float* bin = (const float*)d_in[4];
  const float* Wk = (const float*)d_in[5];
  const float* bk = (const float*)d_in[6];
  const float* Wq = (const float*)d_in[7];
  const float* bq = (const float*)d_in[8];
  const float* Wv = (const float*)d_in[9];
  const float* bv = (const float*)d_in[10];
  const float* Wout = (const float*)d_in[11];
  const float* bout = (const float*)d_in[12];
  const float* gf = (const float*)d_in[13];
  const float* bf_ = (const float*)d_in[14];
  const float* W1 = (const float*)d_in[15];
  const float* b1 = (const float*)d_in[16];
  const float* W2 = (const float*)d_in[17];
  const float* b2 = (const float*)d_in[18];
  float* out = (float*)d_out;

  char* ws = (char*)d_ws;
  size_t off = 0;
  auto alloc = [&](size_t bytes) {
    char* p = ws + off;
    off += (bytes + 255) & ~(size_t)255;
    return p;
  };
  u16* WinT = (u16*)alloc((size_t)1024 * 1024 * 2);  // [n][Whi] (2-term)
  u16* WqkT = (u16*)alloc((size_t)2048 * 1024 * 2);  // [n][Whi] (2-term qk)
  u16* WvT = (u16*)alloc((size_t)1024 * 1024 * 2);
  u16* WoutT = (u16*)alloc((size_t)1024 * 1024 * 2);
  u16* W1T = (u16*)alloc((size_t)4096 * 1024 * 2);
  u16* W2T = (u16*)alloc((size_t)1024 * 4096 * 2);
  float* bqk = (float*)alloc(2048 * 4);
  char* R1 = alloc((size_t)8192 * 2048 * 2);  // ln1 -> vf
  char* R2 = alloc((size_t)8192 * 2048 * 2);  // hb  -> ob, ln2
  char* QK = alloc((size_t)2 * 256 * 32 * 4 * 1024);  // qf+kf (64MB) -> ffn1
  const size_t need = off;                            // ~147 MiB

  if (need > ws_size) {  // diagnostic sentinel: ws too small -> absmax ~12345
    fillconst<<<(out_size + 255) / 256, 256, 0, stream>>>(out, 12345.0f,
                                                          out_size);
    return;
  }

  u16* ln1 = (u16*)R1;                              // 32 MiB
  u16* vfb = (u16*)R1;                              // 16 MiB, after ln1 dead
  u16* hb = (u16*)R2;                               // 32 MiB
  u16* ob = (u16*)R2;                               // after hb dead
  u16* ln2 = (u16*)(R2 + (size_t)8192 * 1024 * 2);  // second 16 MiB
  u16* qfb = (u16*)QK;                              // 32 MiB
  u16* kfb = (u16*)(QK + (size_t)256 * 32 * 4 * 1024);  // 32 MiB
  u16* ffn1 = (u16*)QK;                             // after attn, qf/kf dead
  float* x2 = out;                                  // d_out doubles as x2

  // ---- weight prep (bf16 transposes; hi planes only) ----
  wtrans<0><<<dim3(16, 16, 1), 256, 0, stream>>>(Win, 1024, 0, WinT, 1024, 0,
                                                 0);
  wtrans<0><<<dim3(1, 16, 16), 256, 0, stream>>>(Wq, 64, 65536, WqkT, 1024,
                                                 (long)64 * 1024, 0);
  wtrans<0><<<dim3(1, 16, 16), 256, 0, stream>>>(
      Wk, 64, 65536, WqkT + (size_t)1024 * 1024, 1024, (long)64 * 1024, 0);
  wtrans<0><<<dim3(1, 16, 16), 256, 0, stream>>>(Wv, 64, 65536, WvT, 1024,
                                                 (long)64 * 1024, 0);
  wtrans<0><<<dim3(16, 16, 1), 256, 0, stream>>>(Wout, 1024, 0, WoutT, 1024, 0,
                                                 0);
  wtrans<0><<<dim3(64, 16, 1), 256, 0, stream>>>(W1, 4096, 0, W1T, 1024, 0, 0);
  wtrans<0><<<dim3(16, 64, 1), 256, 0, stream>>>(W2, 1024, 0, W2T, 4096, 0, 0);
  biascat<<<8, 256, 0, stream>>>(bq, bk, bqk);

  // ---- pipeline (all GEMMs: verified r7 config, BM=256) ----
  lnorm<true><<<8192, 256, 0, stream>>>(x, ga, ba, ln1);
  // h = ln1 @ bf16(Win) + bin  (2-TERM: A=[hi|lo] K=2048 kdup=0;
  //  B=Win_hi re-read via kdupB=16; split output for qk's A)
  gemm256<256, 128, EPI_SPLIT><<<256, 512, 0, stream>>>(
      ln1, 2048, 0, WinT, bin, nullptr, hb, nullptr, 2048, 1024, 2048, 1024,
      16);
  // [q|k] = h @ [Wq|Wk]_hi  (2-TERM: A=[hi|lo] K=2048 kdup=0;
  //  B=Whi re-read via kdupB=16 -> (hi+lo)@Whi = h@bf16(W))
  gemm256<256, 256, EPI_QKFRAG><<<256, 512, 0, stream>>>(
      hb, 2048, 0, WqkT, bqk, nullptr, qfb, kfb, 0, 2048, 2048, 1024, 16);
  // v = h_hi @ Wv + bv  (fragment layout, overwrites ln1 region: dead)
  gemm256<256, 128, EPI_VFRAG><<<256, 512, 0, stream>>>(
      hb, 2048, 0, WvT, bv, nullptr, vfb, nullptr, 0, 1024, 1024, 1024, 0);
  attn_fwd<<<dim3(4, 256), 256, 0, stream>>>(qfb, kfb, vfb, ob);
  // x2 = o @ Wout + bout + x   (x2 == d_out)
  gemm256<256, 128, EPI_RES><<<256, 512, 0, stream>>>(
      ob, 1024, 0, WoutT, bout, x, x2, nullptr, 1024, 1024, 1024, 1024, 0);
  lnorm<false><<<8192, 256, 0, stream>>>(x2, gf, bf_, ln2);
  // ffn1 = relu(ln2 @ W1 + b1)   (overwrites qf/kf region: dead)
  gemm256<256, 256, EPI_RELU><<<512, 512, 0, stream>>>(
      ln2, 1024, 0, W1T, b1, nullptr, ffn1, nullptr, 4096, 4096, 1024, 1024,
      0);
  // out = ffn1 @ W2 + b2 + x2   (res == Cout == d_out, element-wise safe)
  gemm256<256, 128, EPI_RES><<<256, 512, 0, stream>>>(
      ffn1, 4096, 0, W2T, b2, x2, out, nullptr, 1024, 1024, 4096, 4096, 0);
}

// Round 17
// 390.799 us; speedup vs baseline: 1.2123x; 1.0792x over previous
//
#include <hip/hip_runtime.h>

// ---------------------------------------------------------------------------
// Transformer block (pre-LN attn + FFN), B=16 T=512 D=1024 H=16 HD=64, f32 io.
// bf16 MFMA GEMMs. Precision ladder (calibrated r15/r16/r17):
//   r15: qk 2-term (drop W_lo term)      absmax 0.031 -> 0.0625
//   r16: Win 2-term (drop Win_lo term)   absmax -> 0.0645
//   r17: h collapsed to plain bf16; qk/v consume bf16(h) (K'=1024).
//        Added err: h_residual@W ~0.0023 rms -> dS ~0.026 -> absmax ~0.09.
// q/k OUTPUTS remain hi/lo-split in fragment layout (scores are unscaled;
// their representation precision is preserved). ln1 stays split so
// h = (exact ln1)@bf16(Win).
// GEMM v3-256 (verified r7/r13, 963 TF): 2 superphases/K-tile, counted
// vmcnt never 0, ring-4 regions, XOR swizzle (0 conflicts), XCD swizzle,
// setprio, scalar epilogues. Schedule variants all refuted
// (4-phase=114, reg-prefetch=111, m201-port=114, 128^2-TLP=+35).
// Attention v3 (r13): paired t-groups (g,31-g), 9 iters/wave, grid (4,256).
// Workspace (~131 MiB, liveness-aliased), x2 lives in d_out.
// ---------------------------------------------------------------------------

#define DEV __device__ __forceinline__

typedef unsigned short u16;
typedef __attribute__((ext_vector_type(8))) __bf16 bf16x8;
typedef __attribute__((ext_vector_type(4))) float f32x4;
typedef __attribute__((ext_vector_type(8))) unsigned short u16x8;

typedef __attribute__((address_space(1))) void as1_void;
typedef __attribute__((address_space(3))) void as3_void;

DEV u16 f2b(float f) {                       // f32 -> bf16 RNE (finite inputs)
  unsigned u = __float_as_uint(f);
  u = (u + 0x7fffu + ((u >> 16) & 1u)) >> 16;
  return (u16)u;
}
DEV float b2f(u16 h) { return __uint_as_float(((unsigned)h) << 16); }

DEV f32x4 mfma16(bf16x8 a, bf16x8 b, f32x4 c) {
  return __builtin_amdgcn_mfma_f32_16x16x32_bf16(a, b, c, 0, 0, 0);
}

// async global->LDS, 16B per lane, dest = uniform base + lane*16
DEV void gload16(const void* g, void* l) {
  __builtin_amdgcn_global_load_lds((as1_void*)(unsigned long long)g,
                                   (as3_void*)(unsigned long long)l,
                                   16u, 0, 0u);
}

#define EPI_BF16 0
#define EPI_RELU 1
#define EPI_RES 2
#define EPI_SPLIT 3
#define EPI_QKFRAG 4
#define EPI_VFRAG 5

// ---------------------------------------------------------------------------
// GEMM v3: C[M,N] = A[M,K]*Bt[N,K]^T + bias. BMxBN tile, BK=64.
// kdup  (A): ktA = (kt>=kdup)? kt-kdup : kt  -> A' = [hi, hi, lo]
// kdupB (B): ktB analogous (re-reads B blocks for 2-term paths).
// Superphase per iteration u (buf cur=u&1):
//   kh0: read A(cur,0)+B(cur,0); stage (u+1).kh1 -> (cur^1,1);
//        MFMA; lgkm0; vmcnt(NWAIT); barrier
//   kh1: read A(cur,1)+B(cur,1); stage (u+2).kh0 -> (cur,0);
//        MFMA; lgkm0; vmcnt(NWAIT); barrier
// NWAIT = 2 stage-groups = 2*(LA+LB). Prologue = 3 groups then vmcnt(NWAIT).
// Tail stages clamp kt; targets are dead regions (counts stay uniform).
// ---------------------------------------------------------------------------
template <int BM, int BN, int EPI>
__global__ __launch_bounds__((BM == 256) ? 512 : 256, 2) void gemm256(
    const u16* __restrict__ A, int lda, int kdup, const u16* __restrict__ Bt,
    const float* __restrict__ bias, const float* __restrict__ res,
    void* __restrict__ Cout, void* __restrict__ Cout2, int ldc, int N, int K,
    int ldb, int kdupB) {
  constexpr int THREADS = (BM == 256) ? 512 : 256;
  constexpr int NWAVE = THREADS / 64;
  constexpr int NWN = (BN == 256) ? 4 : 2;   // n-waves (64 cols each)
  constexpr int NWM = NWAVE / NWN;           // m-waves
  constexpr int MPW = BM / NWM;              // per-wave m rows
  constexpr int MF = MPW / 16;               // m-frags per wave
  constexpr int LA = BM * 4 / THREADS;       // A gloads/thread/stage (=2)
  constexpr int LB = BN * 4 / THREADS;       // B gloads/thread/stage (1 or 2)
  constexpr int NWAIT = 2 * (LA + LB);       // counted vmcnt
  constexpr int ASZ = BM * 64;               // bytes per (buf,ks) A region
  constexpr int BSZ = BN * 64;
  constexpr int ATOT = 4 * ASZ;
  __shared__ __align__(1024) char lds[4 * ASZ + 4 * BSZ];

  // XCD-contiguous block swizzle (gridDim.x % 8 == 0 by construction)
  const int nwg = (int)gridDim.x;
  const int cpx = nwg >> 3;
  int w = (int)blockIdx.x;
  w = (w & 7) * cpx + (w >> 3);
  const int nbn = N / BN;
  const int bn = w % nbn, bm = w / nbn;

  const int tid = threadIdx.x;
  const int wave = tid >> 6, lane = tid & 63;
  const int l15 = lane & 15, l4 = lane >> 4;
  const int wm = wave / NWN;
  const int wn = wave % NWN;
  const int nk = K >> 6;

  // staging source: dest row-in-16-group = lane>>2, dest chunk = lane&3;
  // source holds chunk (lane&3) ^ ((row>>1)&3)  [same involution as reads]
  const int srow = lane >> 2;
  const int schunk = ((lane & 3) ^ ((srow >> 1) & 3)) << 4;
  const char* Ab = (const char*)A;
  const char* Bb = (const char*)Bt;
  const int arowA = wave * (BM / NWAVE) + srow;
  const int arowB = wave * (BN / NWAVE) + srow;

  auto stageA = [&](int buf, int kh, int kt) {
    const int ktA = (kdup && kt >= kdup) ? kt - kdup : kt;
    const char* s = Ab + (size_t)(bm * BM + arowA) * (size_t)(lda * 2) +
                    ktA * 128 + kh * 64 + schunk;
    char* d = lds + (((buf << 1) | kh) * ASZ) + wave * (LA * 1024);
    gload16(s, d);
    gload16(s + (size_t)16 * (size_t)(lda * 2), d + 1024);
  };
  auto stageB = [&](int buf, int kh, int kt) {
    const int ktB = (kdupB && kt >= kdupB) ? kt - kdupB : kt;
    const char* s = Bb + (size_t)(bn * BN + arowB) * (size_t)(ldb * 2) +
                    ktB * 128 + kh * 64 + schunk;
    char* d = lds + ATOT + (((buf << 1) | kh) * BSZ) + wave * (LB * 1024);
    gload16(s, d);
    if (LB == 2) gload16(s + (size_t)16 * (size_t)(ldb * 2), d + 1024);
  };

  const f32x4 fz = {0.f, 0.f, 0.f, 0.f};
  f32x4 acc[MF][4];
#pragma unroll
  for (int i = 0; i < MF; ++i)
#pragma unroll
    for (int j = 0; j < 4; ++j) acc[i][j] = fz;

  // prologue: tile0 full + tile1 kh0, in steady-state issue order
  stageA(0, 0, 0);
  stageB(0, 0, 0);
  stageA(0, 1, 0);
  stageB(0, 1, 0);
  {
    const int k1 = (1 < nk) ? 1 : nk - 1;
    stageA(1, 0, k1);
    stageB(1, 0, k1);
  }
  asm volatile("s_waitcnt vmcnt(%0)" ::"i"(NWAIT) : "memory");
  __builtin_amdgcn_s_barrier();

  for (int u = 0; u < nk; ++u) {
    const int cur = u & 1;
    const int kp1 = (u + 1 < nk) ? u + 1 : nk - 1;
    const int kp2 = (u + 2 < nk) ? u + 2 : nk - 1;
#pragma unroll
    for (int kh = 0; kh < 2; ++kh) {
      const char* Ar = lds + (((cur << 1) | kh) * ASZ);
      const char* Br = lds + ATOT + (((cur << 1) | kh) * BSZ);
      bf16x8 bfr[4], af[MF];
#pragma unroll
      for (int ni = 0; ni < 4; ++ni) {
        const int n = wn * 64 + ni * 16 + l15;
        bfr[ni] = *(const bf16x8*)(Br + n * 64 + ((l4 ^ ((n >> 1) & 3)) << 4));
      }
#pragma unroll
      for (int mi = 0; mi < MF; ++mi) {
        const int m = wm * MPW + mi * 16 + l15;
        af[mi] = *(const bf16x8*)(Ar + m * 64 + ((l4 ^ ((m >> 1) & 3)) << 4));
      }
      if (kh == 0) {
        stageA(cur ^ 1, 1, kp1);
        stageB(cur ^ 1, 1, kp1);
      } else {
        stageA(cur, 0, kp2);
        stageB(cur, 0, kp2);
      }
      __builtin_amdgcn_s_setprio(1);
#pragma unroll
      for (int mi = 0; mi < MF; ++mi)
#pragma unroll
        for (int ni = 0; ni < 4; ++ni)
          acc[mi][ni] = mfma16(af[mi], bfr[ni], acc[mi][ni]);
      __builtin_amdgcn_s_setprio(0);
      // WAR guard: this kh's region is re-staged next superphase.
      asm volatile("s_waitcnt lgkmcnt(0)" ::: "memory");
      // visibility: next superphase's region complete for all waves.
      asm volatile("s_waitcnt vmcnt(%0)" ::"i"(NWAIT) : "memory");
      __builtin_amdgcn_s_barrier();
    }
  }
  asm volatile("s_waitcnt vmcnt(0)" ::: "memory");

  // ---- epilogue (scalar form; r13-verified) ----
#pragma unroll
  for (int mf = 0; mf < MF; ++mf) {
#pragma unroll
    for (int ni = 0; ni < 4; ++ni) {
      const int gn = bn * BN + wn * 64 + ni * 16 + l15;
      const float bia = bias[gn];
#pragma unroll
      for (int r = 0; r < 4; ++r) {
        const int gm = bm * BM + wm * MPW + mf * 16 + l4 * 4 + r;
        float v = acc[mf][ni][r] + bia;
        if (EPI == EPI_BF16) {
          ((u16*)Cout)[(size_t)gm * ldc + gn] = f2b(v);
        } else if (EPI == EPI_RELU) {
          ((u16*)Cout)[(size_t)gm * ldc + gn] = f2b(v > 0.f ? v : 0.f);
        } else if (EPI == EPI_RES) {
          ((float*)Cout)[(size_t)gm * ldc + gn] =
              v + res[(size_t)gm * ldc + gn];
        } else if (EPI == EPI_SPLIT) {  // [hi | lo] planes within row
          u16 hi = f2b(v);
          ((u16*)Cout)[(size_t)gm * ldc + gn] = hi;
          ((u16*)Cout)[(size_t)gm * ldc + N + gn] = f2b(v - b2f(hi));
        } else if (EPI == EPI_QKFRAG) {
          // gm=(b,s); gn<1024: q -> Cout frags; gn>=1024: k -> Cout2.
          const int b = gm >> 9, s = gm & 511;
          const int gs = s >> 4, sr = s & 15;
          const int n = gn & 1023;
          const int h = n >> 6, e = n & 63;
          u16* base = (u16*)((gn >> 10) ? Cout2 : Cout);
          const size_t blk = ((size_t)(b * 16 + h) * 32 + gs) * 4;
          const int idx = ((e >> 3) & 3) * 128 + sr * 8 + (e & 7);
          const u16 hi = f2b(v);
          base[(blk + (e >> 5)) * 512 + idx] = hi;
          base[(blk + 2 + (e >> 5)) * 512 + idx] = f2b(v - b2f(hi));
        } else {  // EPI_VFRAG: B-operand frag for PV
          const int b = gm >> 9, s = gm & 511;
          const int h = gn >> 6, e = gn & 63;
          const size_t blk =
              ((size_t)(b * 16 + h) * 16 + (s >> 5)) * 4 + (e >> 4);
          ((u16*)Cout)[blk * 512 + ((s >> 3) & 3) * 128 + (e & 15) * 8 +
                       (s & 7)] = f2b(v);
        }
      }
    }
  }
}

// ---------------------------------------------------------------------------
// LayerNorm row kernel. SPLIT: out row = [hi(1024) | lo(1024)] (stride 2048).
// ---------------------------------------------------------------------------
template <bool SPLIT>
__global__ __launch_bounds__(256) void lnorm(const float* __restrict__ x,
                                             const float* __restrict__ g,
                                             const float* __restrict__ bt,
                                             u16* __restrict__ out) {
  const int row = blockIdx.x, tid = threadIdx.x;
  const int wave = tid >> 6, lane = tid & 63;
  const float4 v = *(const float4*)(x + (size_t)row * 1024 + tid * 4);
  float xv[4] = {v.x, v.y, v.z, v.w};
  float s = xv[0] + xv[1] + xv[2] + xv[3];
  float s2 = xv[0] * xv[0] + xv[1] * xv[1] + xv[2] * xv[2] + xv[3] * xv[3];
  for (int off = 32; off; off >>= 1) {
    s += __shfl_down(s, off);
    s2 += __shfl_down(s2, off);
  }
  __shared__ float red[8];
  if (lane == 0) {
    red[wave] = s;
    red[4 + wave] = s2;
  }
  __syncthreads();
  const float ts = red[0] + red[1] + red[2] + red[3];
  const float ts2 = red[4] + red[5] + red[6] + red[7];
  const float mean = ts * (1.f / 1024.f);
  const float var = ts2 * (1.f / 1024.f) - mean * mean;
  const float rstd = rsqrtf(var + 1e-5f);
#pragma unroll
  for (int j = 0; j < 4; ++j) {
    const int col = tid * 4 + j;
    const float y = (xv[j] - mean) * rstd * g[col] + bt[col];
    const u16 hi = f2b(y);
    if (SPLIT) {
      out[(size_t)row * 2048 + col] = hi;
      out[(size_t)row * 2048 + 1024 + col] = f2b(y - b2f(hi));
    } else {
      out[(size_t)row * 1024 + col] = hi;
    }
  }
}

// ---------------------------------------------------------------------------
// Weight transpose f32[K][cols] -> bf16 out[n][k] (row stride ors).
// MODE 0: plain hi. MODE 2: triple [hi @0 | lo @Koff | hi @2*Koff].
// grid: (cols/64, K/64, batch)
// ---------------------------------------------------------------------------
template <int MODE>
__global__ __launch_bounds__(256) void wtrans(const float* __restrict__ in,
                                              int kstride, long ibs,
                                              u16* __restrict__ out, int ors,
                                              long obs, int Koff) {
  in += (size_t)blockIdx.z * ibs;
  out += (size_t)blockIdx.z * obs;
  const int n0 = blockIdx.x * 64, k0 = blockIdx.y * 64;
  const int tid = threadIdx.x;
  __shared__ float tt[64][65];
  const int r = tid >> 4, c4 = (tid & 15) * 4;
#pragma unroll
  for (int p = 0; p < 4; ++p) {
    const int rr = r + p * 16;
    const float4 vv =
        *(const float4*)(in + (size_t)(k0 + rr) * kstride + n0 + c4);
    tt[rr][c4] = vv.x;
    tt[rr][c4 + 1] = vv.y;
    tt[rr][c4 + 2] = vv.z;
    tt[rr][c4 + 3] = vv.w;
  }
  __syncthreads();
  const int nl = tid >> 2, kc = (tid & 3) * 16;
  u16 hi[16], lo[16];
#pragma unroll
  for (int j = 0; j < 16; ++j) {
    const float w2 = tt[kc + j][nl];
    hi[j] = f2b(w2);
    if (MODE == 2) lo[j] = f2b(w2 - b2f(hi[j]));
  }
  u16* orow = out + (size_t)(n0 + nl) * ors + k0 + kc;
  u16x8 a, b;
#pragma unroll
  for (int j = 0; j < 8; ++j) {
    a[j] = hi[j];
    b[j] = hi[8 + j];
  }
  *(u16x8*)(orow) = a;
  *(u16x8*)(orow + 8) = b;
  if (MODE == 2) {
    *(u16x8*)(orow + 2 * Koff) = a;
    *(u16x8*)(orow + 2 * Koff + 8) = b;
    u16x8 c, d;
#pragma unroll
    for (int j = 0; j < 8; ++j) {
      c[j] = lo[j];
      d[j] = lo[8 + j];
    }
    *(u16x8*)(orow + Koff) = c;
    *(u16x8*)(orow + Koff + 8) = d;
  }
}

__global__ void biascat(const float* __restrict__ bq,
                        const float* __restrict__ bk, float* __restrict__ o) {
  const int i = blockIdx.x * 256 + threadIdx.x;  // 2048 total
  o[i] = (i < 1024) ? bq[i] : bk[i - 1024];
}

__global__ void fillconst(float* __restrict__ p, float v, int n) {
  const int i = blockIdx.x * 256 + threadIdx.x;
  if (i < n) p[i] = v;
}

// ---------------------------------------------------------------------------
// Flash attention v3: paired t-groups (g, 31-g) per wave, 9 iters each.
// grid (4, B*H). Per-group body identical to verified round-3 kernel.
// ---------------------------------------------------------------------------
__global__ __launch_bounds__(256) void attn_fwd(const u16* __restrict__ qf,
                                                const u16* __restrict__ kf,
                                                const u16* __restrict__ vf,
                                                u16* __restrict__ o) {
  const int bh = blockIdx.y;
  const int b = bh >> 4, h = bh & 15;
  const int tid = threadIdx.x, wave = tid >> 6, lane = tid & 63;
  const int l15 = lane & 15, l4 = lane >> 4;
  const int g0 = (int)blockIdx.x * 4 + wave;  // 0..15
  __shared__ u16 Pl[4][1024];  // per-wave 16x64 bf16 P, 128B rows, swizzled

  const f32x4 fz = {0.f, 0.f, 0.f, 0.f};
  const u16* qfb = qf + (size_t)bh * 32 * 2048 + lane * 8;
  const u16* vfb = vf + (size_t)bh * 16 * 2048 + lane * 8;

  for (int grp = 0; grp < 2; ++grp) {
    const int gt = grp ? (31 - g0) : g0;  // pair (g, 31-g): 9 iters total
    const int tw = gt * 16;
    const u16* kfb = kf + ((size_t)(bh * 32 + gt) * 4) * 512 + lane * 8;
    const bf16x8 kh0 = *(const bf16x8*)(kfb);
    const bf16x8 kh1 = *(const bf16x8*)(kfb + 512);
    const bf16x8 kl0 = *(const bf16x8*)(kfb + 1024);
    const bf16x8 kl1 = *(const bf16x8*)(kfb + 1536);

    f32x4 oacc[4] = {fz, fz, fz, fz};
    float mrow[4] = {-1e30f, -1e30f, -1e30f, -1e30f};
    float lrow[4] = {0.f, 0.f, 0.f, 0.f};
    const int niter = (tw + 79) >> 6;

    for (int it = 0; it < niter; ++it) {
      const int s0 = it * 64;
      bf16x8 qh[4][2], ql[4][2];
#pragma unroll
      for (int scb = 0; scb < 4; ++scb) {
        const u16* qp = qfb + (size_t)((s0 >> 4) + scb) * 2048;
        qh[scb][0] = *(const bf16x8*)(qp);
        qh[scb][1] = *(const bf16x8*)(qp + 512);
        ql[scb][0] = *(const bf16x8*)(qp + 1024);
        ql[scb][1] = *(const bf16x8*)(qp + 1536);
      }
      bf16x8 vv[2][4];
#pragma unroll
      for (int h2 = 0; h2 < 2; ++h2) {
        const u16* vp = vfb + (size_t)((s0 >> 5) + h2) * 2048;
#pragma unroll
        for (int eF = 0; eF < 4; ++eF)
          vv[h2][eF] = *(const bf16x8*)(vp + eF * 512);
      }
      f32x4 sf[4];
#pragma unroll
      for (int scb = 0; scb < 4; ++scb) {
        f32x4 z = fz;
        z = mfma16(kh0, qh[scb][0], z);
        z = mfma16(kh1, qh[scb][1], z);
        z = mfma16(kh0, ql[scb][0], z);
        z = mfma16(kh1, ql[scb][1], z);
        z = mfma16(kl0, qh[scb][0], z);
        z = mfma16(kl1, qh[scb][1], z);
        sf[scb] = z;
      }
      if (s0 + 63 > tw) {
#pragma unroll
        for (int scb = 0; scb < 4; ++scb)
#pragma unroll
          for (int r = 0; r < 4; ++r) {
            const int s = s0 + scb * 16 + l15, t = tw + l4 * 4 + r;
            if (s > t) sf[scb][r] = -1e30f;
          }
      }
      float scl[4];
#pragma unroll
      for (int r = 0; r < 4; ++r) {
        float v = fmaxf(fmaxf(sf[0][r], sf[1][r]), fmaxf(sf[2][r], sf[3][r]));
        v = fmaxf(v, __shfl_xor(v, 1));
        v = fmaxf(v, __shfl_xor(v, 2));
        v = fmaxf(v, __shfl_xor(v, 4));
        v = fmaxf(v, __shfl_xor(v, 8));
        const float mn = fmaxf(mrow[r], v);
        scl[r] = __expf(mrow[r] - mn);
        mrow[r] = mn;
      }
      float ps[4] = {0.f, 0.f, 0.f, 0.f};
#pragma unroll
      for (int scb = 0; scb < 4; ++scb)
#pragma unroll
        for (int r = 0; r < 4; ++r) {
          const float p = __expf(sf[scb][r] - mrow[r]);
          sf[scb][r] = p;
          ps[r] += p;
        }
#pragma unroll
      for (int r = 0; r < 4; ++r) {
        float v = ps[r];
        v += __shfl_xor(v, 1);
        v += __shfl_xor(v, 2);
        v += __shfl_xor(v, 4);
        v += __shfl_xor(v, 8);
        lrow[r] = lrow[r] * scl[r] + v;
        oacc[0][r] *= scl[r];
        oacc[1][r] *= scl[r];
        oacc[2][r] *= scl[r];
        oacc[3][r] *= scl[r];
      }
#pragma unroll
      for (int scb = 0; scb < 4; ++scb)
#pragma unroll
        for (int r = 0; r < 4; ++r) {
          const int trow = l4 * 4 + r, scol = scb * 16 + l15;
          const int byte = trow * 128 + ((scol * 2) ^ ((trow & 7) << 4));
          *(u16*)((char*)&Pl[wave][0] + byte) = f2b(sf[scb][r]);
        }
#pragma unroll
      for (int h2 = 0; h2 < 2; ++h2) {
        const bf16x8 pf = *(const bf16x8*)((const char*)&Pl[wave][0] +
                                           l15 * 128 +
                                           (((h2 * 4 + l4) ^ (l15 & 7)) << 4));
#pragma unroll
        for (int eF = 0; eF < 4; ++eF)
          oacc[eF] = mfma16(pf, vv[h2][eF], oacc[eF]);
      }
    }
#pragma unroll
    for (int eF = 0; eF < 4; ++eF)
#pragma unroll
      for (int r = 0; r < 4; ++r) {
        const int t = tw + l4 * 4 + r;
        const float val = oacc[eF][r] / lrow[r];
        o[(size_t)(b * 512 + t) * 1024 + h * 64 + eF * 16 + l15] = f2b(val);
      }
  }
}

// ---------------------------------------------------------------------------
extern "C" void kernel_launch(void* const* d_in, const int* in_sizes, int n_in,
                              void* d_out, int out_size, void* d_ws,
                              size_t ws_size, hipStream_t stream) {
  const float* x = (const float*)d_in[0];
  const float* ga = (const float*)d_in[1];
  const float* ba = (const float*)d_in[2];
  const float* Win = (const float*)d_in[3];
  const float* bin = (const float*)d_in[4];
  const float* Wk = (const float*)d_in[5];
  const float* bk = (const float*)d_in[6];
  const float* Wq = (const float*)d_in[7];
  const float* bq = (const float*)d_in[8];
  const float* Wv = (const float*)d_in[9];
  const float* bv = (const float*)d_in[10];
  const float* Wout = (const float*)d_in[11];
  const float* bout = (const float*)d_in[12];
  const float* gf = (const float*)d_in[13];
  const float* bf_ = (const float*)d_in[14];
  const float* W1 = (const float*)d_in[15];
  const float* b1 = (const float*)d_in[16];
  const float* W2 = (const float*)d_in[17];
  const float* b2 = (const float*)d_in[18];
  float* out = (float*)d_out;

  char* ws = (char*)d_ws;
  size_t off = 0;
  auto alloc = [&](size_t bytes) {
    char* p = ws + off;
    off += (bytes + 255) & ~(size_t)255;
    return p;
  };
  u16* WinT = (u16*)alloc((size_t)1024 * 1024 * 2);  // [n][Whi]
  u16* WqkT = (u16*)alloc((size_t)2048 * 1024 * 2);  // [n][Whi]
  u16* WvT = (u16*)alloc((size_t)1024 * 1024 * 2);
  u16* WoutT = (u16*)alloc((size_t)1024 * 1024 * 2);
  u16* W1T = (u16*)alloc((size_t)4096 * 1024 * 2);
  u16* W2T = (u16*)alloc((size_t)1024 * 4096 * 2);
  float* bqk = (float*)alloc(2048 * 4);
  char* R1 = alloc((size_t)8192 * 2048 * 2);  // ln1 (split) -> vf
  char* R2 = alloc((size_t)8192 * 2048 * 2);  // hb(16MB) -> ob; ln2 2nd half
  char* QK = alloc((size_t)2 * 256 * 32 * 4 * 1024);  // qf+kf (64MB) -> ffn1
  const size_t need = off;                            // ~131 MiB

  if (need > ws_size) {  // diagnostic sentinel: ws too small -> absmax ~12345
    fillconst<<<(out_size + 255) / 256, 256, 0, stream>>>(out, 12345.0f,
                                                          out_size);
    return;
  }

  u16* ln1 = (u16*)R1;                              // 32 MiB (split)
  u16* vfb = (u16*)R1;                              // 16 MiB, after ln1 dead
  u16* hb = (u16*)R2;                               // 16 MiB (plain bf16)
  u16* ob = (u16*)R2;                               // after hb dead
  u16* ln2 = (u16*)(R2 + (size_t)8192 * 1024 * 2);  // second 16 MiB
  u16* qfb = (u16*)QK;                              // 32 MiB
  u16* kfb = (u16*)(QK + (size_t)256 * 32 * 4 * 1024);  // 32 MiB
  u16* ffn1 = (u16*)QK;                             // after attn, qf/kf dead
  float* x2 = out;                                  // d_out doubles as x2

  // ---- weight prep (bf16 transposes; hi planes only) ----
  wtrans<0><<<dim3(16, 16, 1), 256, 0, stream>>>(Win, 1024, 0, WinT, 1024, 0,
                                                 0);
  wtrans<0><<<dim3(1, 16, 16), 256, 0, stream>>>(Wq, 64, 65536, WqkT, 1024,
                                                 (long)64 * 1024, 0);
  wtrans<0><<<dim3(1, 16, 16), 256, 0, stream>>>(
      Wk, 64, 65536, WqkT + (size_t)1024 * 1024, 1024, (long)64 * 1024, 0);
  wtrans<0><<<dim3(1, 16, 16), 256, 0, stream>>>(Wv, 64, 65536, WvT, 1024,
                                                 (long)64 * 1024, 0);
  wtrans<0><<<dim3(16, 16, 1), 256, 0, stream>>>(Wout, 1024, 0, WoutT, 1024, 0,
                                                 0);
  wtrans<0><<<dim3(64, 16, 1), 256, 0, stream>>>(W1, 4096, 0, W1T, 1024, 0, 0);
  wtrans<0><<<dim3(16, 64, 1), 256, 0, stream>>>(W2, 1024, 0, W2T, 4096, 0, 0);
  biascat<<<8, 256, 0, stream>>>(bq, bk, bqk);

  // ---- pipeline (all GEMMs: verified r7 config, BM=256) ----
  lnorm<true><<<8192, 256, 0, stream>>>(x, ga, ba, ln1);
  // h = ln1 @ bf16(Win) + bin  (2-term A over split ln1; PLAIN bf16 output)
  gemm256<256, 128, EPI_BF16><<<256, 512, 0, stream>>>(
      ln1, 2048, 0, WinT, bin, nullptr, hb, nullptr, 1024, 1024, 2048, 1024,
      16);
  // [q|k] = bf16(h) @ [Wq|Wk]_hi  (1-TERM, K=1024; q/k outputs stay split)
  gemm256<256, 256, EPI_QKFRAG><<<256, 512, 0, stream>>>(
      hb, 1024, 0, WqkT, bqk, nullptr, qfb, kfb, 0, 2048, 1024, 1024, 0);
  // v = bf16(h) @ Wv + bv  (fragment layout, overwrites ln1 region: dead)
  gemm256<256, 128, EPI_VFRAG><<<256, 512, 0, stream>>>(
      hb, 1024, 0, WvT, bv, nullptr, vfb, nullptr, 0, 1024, 1024, 1024, 0);
  attn_fwd<<<dim3(4, 256), 256, 0, stream>>>(qfb, kfb, vfb, ob);
  // x2 = o @ Wout + bout + x   (x2 == d_out)
  gemm256<256, 128, EPI_RES><<<256, 512, 0, stream>>>(
      ob, 1024, 0, WoutT, bout, x, x2, nullptr, 1024, 1024, 1024, 1024, 0);
  lnorm<false><<<8192, 256, 0, stream>>>(x2, gf, bf_, ln2);
  // ffn1 = relu(ln2 @ W1 + b1)   (overwrites qf/kf region: dead)
  gemm256<256, 256, EPI_RELU><<<512, 512, 0, stream>>>(
      ln2, 1024, 0, W1T, b1, nullptr, ffn1, nullptr, 4096, 4096, 1024, 1024,
      0);
  // out = ffn1 @ W2 + b2 + x2   (res == Cout == d_out, element-wise safe)
  gemm256<256, 128, EPI_RES><<<256, 512, 0, stream>>>(
      ffn1, 4096, 0, W2T, b2, x2, out, nullptr, 1024, 1024, 4096, 4096, 0);
}

// Round 18
// 388.681 us; speedup vs baseline: 1.2189x; 1.0054x over previous
//
#include <hip/hip_runtime.h>

// ---------------------------------------------------------------------------
// Transformer block (pre-LN attn + FFN), B=16 T=512 D=1024 H=16 HD=64, f32 io.
// bf16 MFMA GEMMs. Precision ladder (calibrated r15-r18; each dropped
// ~0.026-rms score term costs ~+0.03 absmax):
//   r15 qk 2-term:  0.031 -> 0.0625      r16 Win 2-term: -> 0.0645
//   r17 h plain bf16, qk/v K=1024: -> 0.0879
//   r18 Win 1-term (h = bf16(ln1)@Win_hi, K=1024): predicted ~0.11.
// q/k outputs remain hi/lo-split in fragment layout (unscaled scores keep
// representation precision).
// r18 also MERGES q/k/v into ONE N=3072 GEMM (exact; saves a dispatch's
// fixed overhead): B = [Wq|Wk|Wv] rows, EPI_QKV routes by gn.
// GEMM v3-256 (verified r7/r13, ~960 TF structural rate): 2 superphases/
// K-tile, counted vmcnt never 0, ring-4 regions, XOR swizzle (0 conflicts),
// XCD swizzle, setprio, scalar epilogues. Schedule variants all refuted.
// Attention v3 (r13): paired t-groups (g,31-g), 9 iters/wave, grid (4,256).
// Workspace (~115 MiB, liveness-aliased), x2 lives in d_out.
// ---------------------------------------------------------------------------

#define DEV __device__ __forceinline__

typedef unsigned short u16;
typedef __attribute__((ext_vector_type(8))) __bf16 bf16x8;
typedef __attribute__((ext_vector_type(4))) float f32x4;
typedef __attribute__((ext_vector_type(8))) unsigned short u16x8;

typedef __attribute__((address_space(1))) void as1_void;
typedef __attribute__((address_space(3))) void as3_void;

DEV u16 f2b(float f) {                       // f32 -> bf16 RNE (finite inputs)
  unsigned u = __float_as_uint(f);
  u = (u + 0x7fffu + ((u >> 16) & 1u)) >> 16;
  return (u16)u;
}
DEV float b2f(u16 h) { return __uint_as_float(((unsigned)h) << 16); }

DEV f32x4 mfma16(bf16x8 a, bf16x8 b, f32x4 c) {
  return __builtin_amdgcn_mfma_f32_16x16x32_bf16(a, b, c, 0, 0, 0);
}

// async global->LDS, 16B per lane, dest = uniform base + lane*16
DEV void gload16(const void* g, void* l) {
  __builtin_amdgcn_global_load_lds((as1_void*)(unsigned long long)g,
                                   (as3_void*)(unsigned long long)l,
                                   16u, 0, 0u);
}

#define EPI_BF16 0
#define EPI_RELU 1
#define EPI_RES 2
#define EPI_QKV 3
#define EPI_VFRAG 5

// ---------------------------------------------------------------------------
// GEMM v3: C[M,N] = A[M,K]*Bt[N,K]^T + bias. BMxBN tile, BK=64.
// kdup/kdupB: block remaps for split/2-term paths (unused this round, kept).
// Superphase per iteration u (buf cur=u&1):
//   kh0: read A(cur,0)+B(cur,0); stage (u+1).kh1; MFMA; lgkm0; vmcnt; bar
//   kh1: read A(cur,1)+B(cur,1); stage (u+2).kh0; MFMA; lgkm0; vmcnt; bar
// NWAIT = 2*(LA+LB). Tail stages clamp kt (dead regions; counts uniform).
// ---------------------------------------------------------------------------
template <int BM, int BN, int EPI>
__global__ __launch_bounds__((BM == 256) ? 512 : 256, 2) void gemm256(
    const u16* __restrict__ A, int lda, int kdup, const u16* __restrict__ Bt,
    const float* __restrict__ bias, const float* __restrict__ res,
    void* __restrict__ Cout, void* __restrict__ Cout2, int ldc, int N, int K,
    int ldb, int kdupB) {
  constexpr int THREADS = (BM == 256) ? 512 : 256;
  constexpr int NWAVE = THREADS / 64;
  constexpr int NWN = (BN == 256) ? 4 : 2;   // n-waves (64 cols each)
  constexpr int NWM = NWAVE / NWN;           // m-waves
  constexpr int MPW = BM / NWM;              // per-wave m rows
  constexpr int MF = MPW / 16;               // m-frags per wave
  constexpr int LA = BM * 4 / THREADS;       // A gloads/thread/stage (=2)
  constexpr int LB = BN * 4 / THREADS;       // B gloads/thread/stage (1 or 2)
  constexpr int NWAIT = 2 * (LA + LB);       // counted vmcnt
  constexpr int ASZ = BM * 64;               // bytes per (buf,ks) A region
  constexpr int BSZ = BN * 64;
  constexpr int ATOT = 4 * ASZ;
  __shared__ __align__(1024) char lds[4 * ASZ + 4 * BSZ];

  // XCD-contiguous block swizzle (gridDim.x % 8 == 0 by construction)
  const int nwg = (int)gridDim.x;
  const int cpx = nwg >> 3;
  int w = (int)blockIdx.x;
  w = (w & 7) * cpx + (w >> 3);
  const int nbn = N / BN;
  const int bn = w % nbn, bm = w / nbn;

  const int tid = threadIdx.x;
  const int wave = tid >> 6, lane = tid & 63;
  const int l15 = lane & 15, l4 = lane >> 4;
  const int wm = wave / NWN;
  const int wn = wave % NWN;
  const int nk = K >> 6;

  // staging source: dest row-in-16-group = lane>>2, dest chunk = lane&3;
  // source holds chunk (lane&3) ^ ((row>>1)&3)  [same involution as reads]
  const int srow = lane >> 2;
  const int schunk = ((lane & 3) ^ ((srow >> 1) & 3)) << 4;
  const char* Ab = (const char*)A;
  const char* Bb = (const char*)Bt;
  const int arowA = wave * (BM / NWAVE) + srow;
  const int arowB = wave * (BN / NWAVE) + srow;

  auto stageA = [&](int buf, int kh, int kt) {
    const int ktA = (kdup && kt >= kdup) ? kt - kdup : kt;
    const char* s = Ab + (size_t)(bm * BM + arowA) * (size_t)(lda * 2) +
                    ktA * 128 + kh * 64 + schunk;
    char* d = lds + (((buf << 1) | kh) * ASZ) + wave * (LA * 1024);
    gload16(s, d);
    gload16(s + (size_t)16 * (size_t)(lda * 2), d + 1024);
  };
  auto stageB = [&](int buf, int kh, int kt) {
    const int ktB = (kdupB && kt >= kdupB) ? kt - kdupB : kt;
    const char* s = Bb + (size_t)(bn * BN + arowB) * (size_t)(ldb * 2) +
                    ktB * 128 + kh * 64 + schunk;
    char* d = lds + ATOT + (((buf << 1) | kh) * BSZ) + wave * (LB * 1024);
    gload16(s, d);
    if (LB == 2) gload16(s + (size_t)16 * (size_t)(ldb * 2), d + 1024);
  };

  const f32x4 fz = {0.f, 0.f, 0.f, 0.f};
  f32x4 acc[MF][4];
#pragma unroll
  for (int i = 0; i < MF; ++i)
#pragma unroll
    for (int j = 0; j < 4; ++j) acc[i][j] = fz;

  // prologue: tile0 full + tile1 kh0, in steady-state issue order
  stageA(0, 0, 0);
  stageB(0, 0, 0);
  stageA(0, 1, 0);
  stageB(0, 1, 0);
  {
    const int k1 = (1 < nk) ? 1 : nk - 1;
    stageA(1, 0, k1);
    stageB(1, 0, k1);
  }
  asm volatile("s_waitcnt vmcnt(%0)" ::"i"(NWAIT) : "memory");
  __builtin_amdgcn_s_barrier();

  for (int u = 0; u < nk; ++u) {
    const int cur = u & 1;
    const int kp1 = (u + 1 < nk) ? u + 1 : nk - 1;
    const int kp2 = (u + 2 < nk) ? u + 2 : nk - 1;
#pragma unroll
    for (int kh = 0; kh < 2; ++kh) {
      const char* Ar = lds + (((cur << 1) | kh) * ASZ);
      const char* Br = lds + ATOT + (((cur << 1) | kh) * BSZ);
      bf16x8 bfr[4], af[MF];
#pragma unroll
      for (int ni = 0; ni < 4; ++ni) {
        const int n = wn * 64 + ni * 16 + l15;
        bfr[ni] = *(const bf16x8*)(Br + n * 64 + ((l4 ^ ((n >> 1) & 3)) << 4));
      }
#pragma unroll
      for (int mi = 0; mi < MF; ++mi) {
        const int m = wm * MPW + mi * 16 + l15;
        af[mi] = *(const bf16x8*)(Ar + m * 64 + ((l4 ^ ((m >> 1) & 3)) << 4));
      }
      if (kh == 0) {
        stageA(cur ^ 1, 1, kp1);
        stageB(cur ^ 1, 1, kp1);
      } else {
        stageA(cur, 0, kp2);
        stageB(cur, 0, kp2);
      }
      __builtin_amdgcn_s_setprio(1);
#pragma unroll
      for (int mi = 0; mi < MF; ++mi)
#pragma unroll
        for (int ni = 0; ni < 4; ++ni)
          acc[mi][ni] = mfma16(af[mi], bfr[ni], acc[mi][ni]);
      __builtin_amdgcn_s_setprio(0);
      // WAR guard: this kh's region is re-staged next superphase.
      asm volatile("s_waitcnt lgkmcnt(0)" ::: "memory");
      // visibility: next superphase's region complete for all waves.
      asm volatile("s_waitcnt vmcnt(%0)" ::"i"(NWAIT) : "memory");
      __builtin_amdgcn_s_barrier();
    }
  }
  asm volatile("s_waitcnt vmcnt(0)" ::: "memory");

  // ---- epilogue (scalar form; r13-verified) ----
#pragma unroll
  for (int mf = 0; mf < MF; ++mf) {
#pragma unroll
    for (int ni = 0; ni < 4; ++ni) {
      const int gn = bn * BN + wn * 64 + ni * 16 + l15;
      const float bia = bias[gn];
#pragma unroll
      for (int r = 0; r < 4; ++r) {
        const int gm = bm * BM + wm * MPW + mf * 16 + l4 * 4 + r;
        float v = acc[mf][ni][r] + bia;
        if (EPI == EPI_BF16) {
          ((u16*)Cout)[(size_t)gm * ldc + gn] = f2b(v);
        } else if (EPI == EPI_RELU) {
          ((u16*)Cout)[(size_t)gm * ldc + gn] = f2b(v > 0.f ? v : 0.f);
        } else if (EPI == EPI_RES) {
          ((float*)Cout)[(size_t)gm * ldc + gn] =
              v + res[(size_t)gm * ldc + gn];
        } else if (EPI == EPI_QKV) {
          // gm=(b,s). gn<1024: q-frags (Cout); gn<2048: k-frags (Cout +
          // 16M u16); else: v-frags (Cout2). q/k stored hi/lo split.
          const int b = gm >> 9, s = gm & 511;
          if (gn < 2048) {
            const int gs = s >> 4, sr = s & 15;
            const int n = gn & 1023;
            const int h = n >> 6, e = n & 63;
            u16* base = (u16*)Cout + ((gn >> 10) ? (size_t)16777216 : 0);
            const size_t blk = ((size_t)(b * 16 + h) * 32 + gs) * 4;
            const int idx = ((e >> 3) & 3) * 128 + sr * 8 + (e & 7);
            const u16 hi = f2b(v);
            base[(blk + (e >> 5)) * 512 + idx] = hi;
            base[(blk + 2 + (e >> 5)) * 512 + idx] = f2b(v - b2f(hi));
          } else {
            const int n = gn - 2048;
            const int h = n >> 6, e = n & 63;
            const size_t blk =
                ((size_t)(b * 16 + h) * 16 + (s >> 5)) * 4 + (e >> 4);
            ((u16*)Cout2)[blk * 512 + ((s >> 3) & 3) * 128 + (e & 15) * 8 +
                          (s & 7)] = f2b(v);
          }
        }
      }
    }
  }
}

// ---------------------------------------------------------------------------
// LayerNorm row kernel (plain bf16 output, 1024-wide).
// ---------------------------------------------------------------------------
__global__ __launch_bounds__(256) void lnorm(const float* __restrict__ x,
                                             const float* __restrict__ g,
                                             const float* __restrict__ bt,
                                             u16* __restrict__ out) {
  const int row = blockIdx.x, tid = threadIdx.x;
  const int wave = tid >> 6, lane = tid & 63;
  const float4 v = *(const float4*)(x + (size_t)row * 1024 + tid * 4);
  float xv[4] = {v.x, v.y, v.z, v.w};
  float s = xv[0] + xv[1] + xv[2] + xv[3];
  float s2 = xv[0] * xv[0] + xv[1] * xv[1] + xv[2] * xv[2] + xv[3] * xv[3];
  for (int off = 32; off; off >>= 1) {
    s += __shfl_down(s, off);
    s2 += __shfl_down(s2, off);
  }
  __shared__ float red[8];
  if (lane == 0) {
    red[wave] = s;
    red[4 + wave] = s2;
  }
  __syncthreads();
  const float ts = red[0] + red[1] + red[2] + red[3];
  const float ts2 = red[4] + red[5] + red[6] + red[7];
  const float mean = ts * (1.f / 1024.f);
  const float var = ts2 * (1.f / 1024.f) - mean * mean;
  const float rstd = rsqrtf(var + 1e-5f);
#pragma unroll
  for (int j = 0; j < 4; ++j) {
    const int col = tid * 4 + j;
    const float y = (xv[j] - mean) * rstd * g[col] + bt[col];
    out[(size_t)row * 1024 + col] = f2b(y);
  }
}

// ---------------------------------------------------------------------------
// Weight transpose f32[K][cols] -> bf16 out[n][k] (row stride ors), hi only.
// grid: (cols/64, K/64, batch)
// ---------------------------------------------------------------------------
__global__ __launch_bounds__(256) void wtrans(const float* __restrict__ in,
                                              int kstride, long ibs,
                                              u16* __restrict__ out, int ors,
                                              long obs) {
  in += (size_t)blockIdx.z * ibs;
  out += (size_t)blockIdx.z * obs;
  const int n0 = blockIdx.x * 64, k0 = blockIdx.y * 64;
  const int tid = threadIdx.x;
  __shared__ float tt[64][65];
  const int r = tid >> 4, c4 = (tid & 15) * 4;
#pragma unroll
  for (int p = 0; p < 4; ++p) {
    const int rr = r + p * 16;
    const float4 vv =
        *(const float4*)(in + (size_t)(k0 + rr) * kstride + n0 + c4);
    tt[rr][c4] = vv.x;
    tt[rr][c4 + 1] = vv.y;
    tt[rr][c4 + 2] = vv.z;
    tt[rr][c4 + 3] = vv.w;
  }
  __syncthreads();
  const int nl = tid >> 2, kc = (tid & 3) * 16;
  u16x8 a, b;
#pragma unroll
  for (int j = 0; j < 8; ++j) {
    a[j] = f2b(tt[kc + j][nl]);
    b[j] = f2b(tt[kc + 8 + j][nl]);
  }
  u16* orow = out + (size_t)(n0 + nl) * ors + k0 + kc;
  *(u16x8*)(orow) = a;
  *(u16x8*)(orow + 8) = b;
}

__global__ void biascat3(const float* __restrict__ bq,
                         const float* __restrict__ bk,
                         const float* __restrict__ bv, float* __restrict__ o) {
  const int i = blockIdx.x * 256 + threadIdx.x;  // 3072 total
  o[i] = (i < 1024) ? bq[i] : (i < 2048 ? bk[i - 1024] : bv[i - 2048]);
}

__global__ void fillconst(float* __restrict__ p, float v, int n) {
  const int i = blockIdx.x * 256 + threadIdx.x;
  if (i < n) p[i] = v;
}

// ---------------------------------------------------------------------------
// Flash attention v3: paired t-groups (g, 31-g) per wave, 9 iters each.
// grid (4, B*H). Per-group body identical to verified round-3 kernel.
// ---------------------------------------------------------------------------
__global__ __launch_bounds__(256) void attn_fwd(const u16* __restrict__ qf,
                                                const u16* __restrict__ kf,
                                                const u16* __restrict__ vf,
                                                u16* __restrict__ o) {
  const int bh = blockIdx.y;
  const int b = bh >> 4, h = bh & 15;
  const int tid = threadIdx.x, wave = tid >> 6, lane = tid & 63;
  const int l15 = lane & 15, l4 = lane >> 4;
  const int g0 = (int)blockIdx.x * 4 + wave;  // 0..15
  __shared__ u16 Pl[4][1024];  // per-wave 16x64 bf16 P, 128B rows, swizzled

  const f32x4 fz = {0.f, 0.f, 0.f, 0.f};
  const u16* qfb = qf + (size_t)bh * 32 * 2048 + lane * 8;
  const u16* vfb = vf + (size_t)bh * 16 * 2048 + lane * 8;

  for (int grp = 0; grp < 2; ++grp) {
    const int gt = grp ? (31 - g0) : g0;  // pair (g, 31-g): 9 iters total
    const int tw = gt * 16;
    const u16* kfb = kf + ((size_t)(bh * 32 + gt) * 4) * 512 + lane * 8;
    const bf16x8 kh0 = *(const bf16x8*)(kfb);
    const bf16x8 kh1 = *(const bf16x8*)(kfb + 512);
    const bf16x8 kl0 = *(const bf16x8*)(kfb + 1024);
    const bf16x8 kl1 = *(const bf16x8*)(kfb + 1536);

    f32x4 oacc[4] = {fz, fz, fz, fz};
    float mrow[4] = {-1e30f, -1e30f, -1e30f, -1e30f};
    float lrow[4] = {0.f, 0.f, 0.f, 0.f};
    const int niter = (tw + 79) >> 6;

    for (int it = 0; it < niter; ++it) {
      const int s0 = it * 64;
      bf16x8 qh[4][2], ql[4][2];
#pragma unroll
      for (int scb = 0; scb < 4; ++scb) {
        const u16* qp = qfb + (size_t)((s0 >> 4) + scb) * 2048;
        qh[scb][0] = *(const bf16x8*)(qp);
        qh[scb][1] = *(const bf16x8*)(qp + 512);
        ql[scb][0] = *(const bf16x8*)(qp + 1024);
        ql[scb][1] = *(const bf16x8*)(qp + 1536);
      }
      bf16x8 vv[2][4];
#pragma unroll
      for (int h2 = 0; h2 < 2; ++h2) {
        const u16* vp = vfb + (size_t)((s0 >> 5) + h2) * 2048;
#pragma unroll
        for (int eF = 0; eF < 4; ++eF)
          vv[h2][eF] = *(const bf16x8*)(vp + eF * 512);
      }
      f32x4 sf[4];
#pragma unroll
      for (int scb = 0; scb < 4; ++scb) {
        f32x4 z = fz;
        z = mfma16(kh0, qh[scb][0], z);
        z = mfma16(kh1, qh[scb][1], z);
        z = mfma16(kh0, ql[scb][0], z);
        z = mfma16(kh1, ql[scb][1], z);
        z = mfma16(kl0, qh[scb][0], z);
        z = mfma16(kl1, qh[scb][1], z);
        sf[scb] = z;
      }
      if (s0 + 63 > tw) {
#pragma unroll
        for (int scb = 0; scb < 4; ++scb)
#pragma unroll
          for (int r = 0; r < 4; ++r) {
            const int s = s0 + scb * 16 + l15, t = tw + l4 * 4 + r;
            if (s > t) sf[scb][r] = -1e30f;
          }
      }
      float scl[4];
#pragma unroll
      for (int r = 0; r < 4; ++r) {
        float v = fmaxf(fmaxf(sf[0][r], sf[1][r]), fmaxf(sf[2][r], sf[3][r]));
        v = fmaxf(v, __shfl_xor(v, 1));
        v = fmaxf(v, __shfl_xor(v, 2));
        v = fmaxf(v, __shfl_xor(v, 4));
        v = fmaxf(v, __shfl_xor(v, 8));
        const float mn = fmaxf(mrow[r], v);
        scl[r] = __expf(mrow[r] - mn);
        mrow[r] = mn;
      }
      float ps[4] = {0.f, 0.f, 0.f, 0.f};
#pragma unroll
      for (int scb = 0; scb < 4; ++scb)
#pragma unroll
        for (int r = 0; r < 4; ++r) {
          const float p = __expf(sf[scb][r] - mrow[r]);
          sf[scb][r] = p;
          ps[r] += p;
        }
#pragma unroll
      for (int r = 0; r < 4; ++r) {
        float v = ps[r];
        v += __shfl_xor(v, 1);
        v += __shfl_xor(v, 2);
        v += __shfl_xor(v, 4);
        v += __shfl_xor(v, 8);
        lrow[r] = lrow[r] * scl[r] + v;
        oacc[0][r] *= scl[r];
        oacc[1][r] *= scl[r];
        oacc[2][r] *= scl[r];
        oacc[3][r] *= scl[r];
      }
#pragma unroll
      for (int scb = 0; scb < 4; ++scb)
#pragma unroll
        for (int r = 0; r < 4; ++r) {
          const int trow = l4 * 4 + r, scol = scb * 16 + l15;
          const int byte = trow * 128 + ((scol * 2) ^ ((trow & 7) << 4));
          *(u16*)((char*)&Pl[wave][0] + byte) = f2b(sf[scb][r]);
        }
#pragma unroll
      for (int h2 = 0; h2 < 2; ++h2) {
        const bf16x8 pf = *(const bf16x8*)((const char*)&Pl[wave][0] +
                                           l15 * 128 +
                                           (((h2 * 4 + l4) ^ (l15 & 7)) << 4));
#pragma unroll
        for (int eF = 0; eF < 4; ++eF)
          oacc[eF] = mfma16(pf, vv[h2][eF], oacc[eF]);
      }
    }
#pragma unroll
    for (int eF = 0; eF < 4; ++eF)
#pragma unroll
      for (int r = 0; r < 4; ++r) {
        const int t = tw + l4 * 4 + r;
        const float val = oacc[eF][r] / lrow[r];
        o[(size_t)(b * 512 + t) * 1024 + h * 64 + eF * 16 + l15] = f2b(val);
      }
  }
}

// ---------------------------------------------------------------------------
extern "C" void kernel_launch(void* const* d_in, const int* in_sizes, int n_in,
                              void* d_out, int out_size, void* d_ws,
                              size_t ws_size, hipStream_t stream) {
  const float* x = (const float*)d_in[0];
  const float* ga = (const float*)d_in[1];
  const float* ba = (const float*)d_in[2];
  const float* Win = (const float*)d_in[3];
  const float* bin = (const float*)d_in[4];
  const float* Wk = (const float*)d_in[5];
  const float* bk = (const float*)d_in[6];
  const float* Wq = (const float*)d_in[7];
  const float* bq = (const float*)d_in[8];
  const float* Wv = (const float*)d_in[9];
  const float* bv = (const float*)d_in[10];
  const float* Wout = (const float*)d_in[11];
  const float* bout = (const float*)d_in[12];
  const float* gf = (const float*)d_in[13];
  const float* bf_ = (const float*)d_in[14];
  const float* W1 = (const float*)d_in[15];
  const float* b1 = (const float*)d_in[16];
  const float* W2 = (const float*)d_in[17];
  const float* b2 = (const float*)d_in[18];
  float* out = (float*)d_out;

  char* ws = (char*)d_ws;
  size_t off = 0;
  auto alloc = [&](size_t bytes) {
    char* p = ws + off;
    off += (bytes + 255) & ~(size_t)255;
    return p;
  };
  u16* WinT = (u16*)alloc((size_t)1024 * 1024 * 2);   // [n][Whi]
  u16* WqkvT = (u16*)alloc((size_t)3072 * 1024 * 2);  // [Wq|Wk|Wv] rows
  u16* WoutT = (u16*)alloc((size_t)1024 * 1024 * 2);
  u16* W1T = (u16*)alloc((size_t)4096 * 1024 * 2);
  u16* W2T = (u16*)alloc((size_t)1024 * 4096 * 2);
  float* bqkv = (float*)alloc(3072 * 4);
  char* R1 = alloc((size_t)8192 * 1024 * 2);  // ln1 -> vfb
  char* R2 = alloc((size_t)8192 * 2048 * 2);  // hb -> ob; ln2 2nd half
  char* QK = alloc((size_t)2 * 256 * 32 * 4 * 1024);  // qf+kf (64MB) -> ffn1
  const size_t need = off;                            // ~115 MiB

  if (need > ws_size) {  // diagnostic sentinel: ws too small -> absmax ~12345
    fillconst<<<(out_size + 255) / 256, 256, 0, stream>>>(out, 12345.0f,
                                                          out_size);
    return;
  }

  u16* ln1 = (u16*)R1;                              // 16 MiB (plain bf16)
  u16* vfb = (u16*)R1;                              // after ln1 dead
  u16* hb = (u16*)R2;                               // 16 MiB (plain bf16)
  u16* ob = (u16*)R2;                               // after hb dead
  u16* ln2 = (u16*)(R2 + (size_t)8192 * 1024 * 2);  // second 16 MiB
  u16* qfb = (u16*)QK;                              // 32 MiB (k at +16M u16)
  u16* kfb = (u16*)(QK + (size_t)256 * 32 * 4 * 1024);  // 32 MiB
  u16* ffn1 = (u16*)QK;                             // after attn, q/k/v dead
  float* x2 = out;                                  // d_out doubles as x2

  // ---- weight prep (bf16 transposes; hi planes only) ----
  wtrans<<<dim3(16, 16, 1), 256, 0, stream>>>(Win, 1024, 0, WinT, 1024, 0);
  wtrans<<<dim3(1, 16, 16), 256, 0, stream>>>(Wq, 64, 65536, WqkvT, 1024,
                                              (long)64 * 1024);
  wtrans<<<dim3(1, 16, 16), 256, 0, stream>>>(
      Wk, 64, 65536, WqkvT + (size_t)1024 * 1024, 1024, (long)64 * 1024);
  wtrans<<<dim3(1, 16, 16), 256, 0, stream>>>(
      Wv, 64, 65536, WqkvT + (size_t)2048 * 1024, 1024, (long)64 * 1024);
  wtrans<<<dim3(16, 16, 1), 256, 0, stream>>>(Wout, 1024, 0, WoutT, 1024, 0);
  wtrans<<<dim3(64, 16, 1), 256, 0, stream>>>(W1, 4096, 0, W1T, 1024, 0);
  wtrans<<<dim3(16, 64, 1), 256, 0, stream>>>(W2, 1024, 0, W2T, 4096, 0);
  biascat3<<<12, 256, 0, stream>>>(bq, bk, bv, bqkv);

  // ---- pipeline (all GEMMs: verified r7 config, BM=256) ----
  lnorm<<<8192, 256, 0, stream>>>(x, ga, ba, ln1);
  // h = bf16(ln1) @ Win_hi + bin  (1-term, K=1024; plain bf16 output)
  gemm256<256, 128, EPI_BF16><<<256, 512, 0, stream>>>(
      ln1, 1024, 0, WinT, bin, nullptr, hb, nullptr, 1024, 1024, 1024, 1024,
      0);
  // [q|k|v] = bf16(h) @ [Wq|Wk|Wv]_hi  (merged, N=3072, K=1024; q/k split
  // fragment outputs to qfb/+16M; v fragments to vfb)
  gemm256<256, 256, EPI_QKV><<<384, 512, 0, stream>>>(
      hb, 1024, 0, WqkvT, bqkv, nullptr, qfb, vfb, 0, 3072, 1024, 1024, 0);
  attn_fwd<<<dim3(4, 256), 256, 0, stream>>>(qfb, kfb, vfb, ob);
  // x2 = o @ Wout + bout + x   (x2 == d_out)
  gemm256<256, 128, EPI_RES><<<256, 512, 0, stream>>>(
      ob, 1024, 0, WoutT, bout, x, x2, nullptr, 1024, 1024, 1024, 1024, 0);
  lnorm<<<8192, 256, 0, stream>>>(x2, gf, bf_, ln2);
  // ffn1 = relu(ln2 @ W1 + b1)   (overwrites q/k region: dead)
  gemm256<256, 256, EPI_RELU><<<512, 512, 0, stream>>>(
      ln2, 1024, 0, W1T, b1, nullptr, ffn1, nullptr, 4096, 4096, 1024, 1024,
      0);
  // out = ffn1 @ W2 + b2 + x2   (res == Cout == d_out, element-wise safe)
  gemm256<256, 128, EPI_RES><<<256, 512, 0, stream>>>(
      ffn1, 4096, 0, W2T, b2, x2, out, nullptr, 1024, 1024, 4096, 4096, 0);
}

// Round 19
// 375.613 us; speedup vs baseline: 1.2613x; 1.0348x over previous
//
#include <hip/hip_runtime.h>

// ---------------------------------------------------------------------------
// Transformer block (pre-LN attn + FFN), B=16 T=512 D=1024 H=16 HD=64, f32 io.
// bf16 MFMA GEMMs. Precision ladder (calibrated r15-r18, CLOSED):
//   r15 qk 2-term 0.0625 | r16 Win 2-term 0.0645 | r17 h bf16 0.0879 |
//   r18 Win 1-term 0.1016. All matmuls now 1-term bf16 except q/k OUTPUTS,
//   which stay hi/lo-split in fragment layout (unscaled scores).
// r19: qkv merge REVERTED (r18: grid 384 = 1.5 rounds on 256 CUs -> 75%
// util, 90.6us @ 22.6% MfmaUtil; separate qk(grid 256)+v(grid 256) = ~73us.
// Per-block model: T = ~9us fixed + nk*2.23us (BN=256) / nk*1.16 (BN=128)).
// GEMM v3-256 (verified r7/r13, ~960 TF structural rate): 2 superphases/
// K-tile, counted vmcnt never 0, ring-4 regions, XOR swizzle (0 conflicts),
// XCD swizzle, setprio, scalar epilogues. Schedule variants all refuted.
// Attention v3 (r13): paired t-groups (g,31-g), 9 iters/wave, grid (4,256).
// Workspace (~117 MiB, liveness-aliased), x2 lives in d_out.
// ---------------------------------------------------------------------------

#define DEV __device__ __forceinline__

typedef unsigned short u16;
typedef __attribute__((ext_vector_type(8))) __bf16 bf16x8;
typedef __attribute__((ext_vector_type(4))) float f32x4;
typedef __attribute__((ext_vector_type(8))) unsigned short u16x8;

typedef __attribute__((address_space(1))) void as1_void;
typedef __attribute__((address_space(3))) void as3_void;

DEV u16 f2b(float f) {                       // f32 -> bf16 RNE (finite inputs)
  unsigned u = __float_as_uint(f);
  u = (u + 0x7fffu + ((u >> 16) & 1u)) >> 16;
  return (u16)u;
}
DEV float b2f(u16 h) { return __uint_as_float(((unsigned)h) << 16); }

DEV f32x4 mfma16(bf16x8 a, bf16x8 b, f32x4 c) {
  return __builtin_amdgcn_mfma_f32_16x16x32_bf16(a, b, c, 0, 0, 0);
}

// async global->LDS, 16B per lane, dest = uniform base + lane*16
DEV void gload16(const void* g, void* l) {
  __builtin_amdgcn_global_load_lds((as1_void*)(unsigned long long)g,
                                   (as3_void*)(unsigned long long)l,
                                   16u, 0, 0u);
}

#define EPI_BF16 0
#define EPI_RELU 1
#define EPI_RES 2
#define EPI_QKFRAG 4
#define EPI_VFRAG 5

// ---------------------------------------------------------------------------
// GEMM v3: C[M,N] = A[M,K]*Bt[N,K]^T + bias. BMxBN tile, BK=64.
// kdup/kdupB: block remaps (unused this round, kept for generality).
// Superphase per iteration u (buf cur=u&1):
//   kh0: read A(cur,0)+B(cur,0); stage (u+1).kh1; MFMA; lgkm0; vmcnt; bar
//   kh1: read A(cur,1)+B(cur,1); stage (u+2).kh0; MFMA; lgkm0; vmcnt; bar
// NWAIT = 2*(LA+LB). Tail stages clamp kt (dead regions; counts uniform).
// ---------------------------------------------------------------------------
template <int BM, int BN, int EPI>
__global__ __launch_bounds__((BM == 256) ? 512 : 256, 2) void gemm256(
    const u16* __restrict__ A, int lda, int kdup, const u16* __restrict__ Bt,
    const float* __restrict__ bias, const float* __restrict__ res,
    void* __restrict__ Cout, void* __restrict__ Cout2, int ldc, int N, int K,
    int ldb, int kdupB) {
  constexpr int THREADS = (BM == 256) ? 512 : 256;
  constexpr int NWAVE = THREADS / 64;
  constexpr int NWN = (BN == 256) ? 4 : 2;   // n-waves (64 cols each)
  constexpr int NWM = NWAVE / NWN;           // m-waves
  constexpr int MPW = BM / NWM;              // per-wave m rows
  constexpr int MF = MPW / 16;               // m-frags per wave
  constexpr int LA = BM * 4 / THREADS;       // A gloads/thread/stage (=2)
  constexpr int LB = BN * 4 / THREADS;       // B gloads/thread/stage (1 or 2)
  constexpr int NWAIT = 2 * (LA + LB);       // counted vmcnt
  constexpr int ASZ = BM * 64;               // bytes per (buf,ks) A region
  constexpr int BSZ = BN * 64;
  constexpr int ATOT = 4 * ASZ;
  __shared__ __align__(1024) char lds[4 * ASZ + 4 * BSZ];

  // XCD-contiguous block swizzle (gridDim.x % 8 == 0 by construction)
  const int nwg = (int)gridDim.x;
  const int cpx = nwg >> 3;
  int w = (int)blockIdx.x;
  w = (w & 7) * cpx + (w >> 3);
  const int nbn = N / BN;
  const int bn = w % nbn, bm = w / nbn;

  const int tid = threadIdx.x;
  const int wave = tid >> 6, lane = tid & 63;
  const int l15 = lane & 15, l4 = lane >> 4;
  const int wm = wave / NWN;
  const int wn = wave % NWN;
  const int nk = K >> 6;

  // staging source: dest row-in-16-group = lane>>2, dest chunk = lane&3;
  // source holds chunk (lane&3) ^ ((row>>1)&3)  [same involution as reads]
  const int srow = lane >> 2;
  const int schunk = ((lane & 3) ^ ((srow >> 1) & 3)) << 4;
  const char* Ab = (const char*)A;
  const char* Bb = (const char*)Bt;
  const int arowA = wave * (BM / NWAVE) + srow;
  const int arowB = wave * (BN / NWAVE) + srow;

  auto stageA = [&](int buf, int kh, int kt) {
    const int ktA = (kdup && kt >= kdup) ? kt - kdup : kt;
    const char* s = Ab + (size_t)(bm * BM + arowA) * (size_t)(lda * 2) +
                    ktA * 128 + kh * 64 + schunk;
    char* d = lds + (((buf << 1) | kh) * ASZ) + wave * (LA * 1024);
    gload16(s, d);
    gload16(s + (size_t)16 * (size_t)(lda * 2), d + 1024);
  };
  auto stageB = [&](int buf, int kh, int kt) {
    const int ktB = (kdupB && kt >= kdupB) ? kt - kdupB : kt;
    const char* s = Bb + (size_t)(bn * BN + arowB) * (size_t)(ldb * 2) +
                    ktB * 128 + kh * 64 + schunk;
    char* d = lds + ATOT + (((buf << 1) | kh) * BSZ) + wave * (LB * 1024);
    gload16(s, d);
    if (LB == 2) gload16(s + (size_t)16 * (size_t)(ldb * 2), d + 1024);
  };

  const f32x4 fz = {0.f, 0.f, 0.f, 0.f};
  f32x4 acc[MF][4];
#pragma unroll
  for (int i = 0; i < MF; ++i)
#pragma unroll
    for (int j = 0; j < 4; ++j) acc[i][j] = fz;

  // prologue: tile0 full + tile1 kh0, in steady-state issue order
  stageA(0, 0, 0);
  stageB(0, 0, 0);
  stageA(0, 1, 0);
  stageB(0, 1, 0);
  {
    const int k1 = (1 < nk) ? 1 : nk - 1;
    stageA(1, 0, k1);
    stageB(1, 0, k1);
  }
  asm volatile("s_waitcnt vmcnt(%0)" ::"i"(NWAIT) : "memory");
  __builtin_amdgcn_s_barrier();

  for (int u = 0; u < nk; ++u) {
    const int cur = u & 1;
    const int kp1 = (u + 1 < nk) ? u + 1 : nk - 1;
    const int kp2 = (u + 2 < nk) ? u + 2 : nk - 1;
#pragma unroll
    for (int kh = 0; kh < 2; ++kh) {
      const char* Ar = lds + (((cur << 1) | kh) * ASZ);
      const char* Br = lds + ATOT + (((cur << 1) | kh) * BSZ);
      bf16x8 bfr[4], af[MF];
#pragma unroll
      for (int ni = 0; ni < 4; ++ni) {
        const int n = wn * 64 + ni * 16 + l15;
        bfr[ni] = *(const bf16x8*)(Br + n * 64 + ((l4 ^ ((n >> 1) & 3)) << 4));
      }
#pragma unroll
      for (int mi = 0; mi < MF; ++mi) {
        const int m = wm * MPW + mi * 16 + l15;
        af[mi] = *(const bf16x8*)(Ar + m * 64 + ((l4 ^ ((m >> 1) & 3)) << 4));
      }
      if (kh == 0) {
        stageA(cur ^ 1, 1, kp1);
        stageB(cur ^ 1, 1, kp1);
      } else {
        stageA(cur, 0, kp2);
        stageB(cur, 0, kp2);
      }
      __builtin_amdgcn_s_setprio(1);
#pragma unroll
      for (int mi = 0; mi < MF; ++mi)
#pragma unroll
        for (int ni = 0; ni < 4; ++ni)
          acc[mi][ni] = mfma16(af[mi], bfr[ni], acc[mi][ni]);
      __builtin_amdgcn_s_setprio(0);
      // WAR guard: this kh's region is re-staged next superphase.
      asm volatile("s_waitcnt lgkmcnt(0)" ::: "memory");
      // visibility: next superphase's region complete for all waves.
      asm volatile("s_waitcnt vmcnt(%0)" ::"i"(NWAIT) : "memory");
      __builtin_amdgcn_s_barrier();
    }
  }
  asm volatile("s_waitcnt vmcnt(0)" ::: "memory");

  // ---- epilogue (scalar form; r13-verified) ----
#pragma unroll
  for (int mf = 0; mf < MF; ++mf) {
#pragma unroll
    for (int ni = 0; ni < 4; ++ni) {
      const int gn = bn * BN + wn * 64 + ni * 16 + l15;
      const float bia = bias[gn];
#pragma unroll
      for (int r = 0; r < 4; ++r) {
        const int gm = bm * BM + wm * MPW + mf * 16 + l4 * 4 + r;
        float v = acc[mf][ni][r] + bia;
        if (EPI == EPI_BF16) {
          ((u16*)Cout)[(size_t)gm * ldc + gn] = f2b(v);
        } else if (EPI == EPI_RELU) {
          ((u16*)Cout)[(size_t)gm * ldc + gn] = f2b(v > 0.f ? v : 0.f);
        } else if (EPI == EPI_RES) {
          ((float*)Cout)[(size_t)gm * ldc + gn] =
              v + res[(size_t)gm * ldc + gn];
        } else if (EPI == EPI_QKFRAG) {
          // gm=(b,s); gn<1024: q -> Cout frags; gn>=1024: k -> Cout2.
          // q/k stored hi/lo split in fragment layout.
          const int b = gm >> 9, s = gm & 511;
          const int gs = s >> 4, sr = s & 15;
          const int n = gn & 1023;
          const int h = n >> 6, e = n & 63;
          u16* base = (u16*)((gn >> 10) ? Cout2 : Cout);
          const size_t blk = ((size_t)(b * 16 + h) * 32 + gs) * 4;
          const int idx = ((e >> 3) & 3) * 128 + sr * 8 + (e & 7);
          const u16 hi = f2b(v);
          base[(blk + (e >> 5)) * 512 + idx] = hi;
          base[(blk + 2 + (e >> 5)) * 512 + idx] = f2b(v - b2f(hi));
        } else {  // EPI_VFRAG: B-operand frag for PV
          const int b = gm >> 9, s = gm & 511;
          const int h = gn >> 6, e = gn & 63;
          const size_t blk =
              ((size_t)(b * 16 + h) * 16 + (s >> 5)) * 4 + (e >> 4);
          ((u16*)Cout)[blk * 512 + ((s >> 3) & 3) * 128 + (e & 15) * 8 +
                       (s & 7)] = f2b(v);
        }
      }
    }
  }
}

// ---------------------------------------------------------------------------
// LayerNorm row kernel (plain bf16 output, 1024-wide).
// ---------------------------------------------------------------------------
__global__ __launch_bounds__(256) void lnorm(const float* __restrict__ x,
                                             const float* __restrict__ g,
                                             const float* __restrict__ bt,
                                             u16* __restrict__ out) {
  const int row = blockIdx.x, tid = threadIdx.x;
  const int wave = tid >> 6, lane = tid & 63;
  const float4 v = *(const float4*)(x + (size_t)row * 1024 + tid * 4);
  float xv[4] = {v.x, v.y, v.z, v.w};
  float s = xv[0] + xv[1] + xv[2] + xv[3];
  float s2 = xv[0] * xv[0] + xv[1] * xv[1] + xv[2] * xv[2] + xv[3] * xv[3];
  for (int off = 32; off; off >>= 1) {
    s += __shfl_down(s, off);
    s2 += __shfl_down(s2, off);
  }
  __shared__ float red[8];
  if (lane == 0) {
    red[wave] = s;
    red[4 + wave] = s2;
  }
  __syncthreads();
  const float ts = red[0] + red[1] + red[2] + red[3];
  const float ts2 = red[4] + red[5] + red[6] + red[7];
  const float mean = ts * (1.f / 1024.f);
  const float var = ts2 * (1.f / 1024.f) - mean * mean;
  const float rstd = rsqrtf(var + 1e-5f);
#pragma unroll
  for (int j = 0; j < 4; ++j) {
    const int col = tid * 4 + j;
    const float y = (xv[j] - mean) * rstd * g[col] + bt[col];
    out[(size_t)row * 1024 + col] = f2b(y);
  }
}

// ---------------------------------------------------------------------------
// Weight transpose f32[K][cols] -> bf16 out[n][k] (row stride ors), hi only.
// grid: (cols/64, K/64, batch)
// ---------------------------------------------------------------------------
__global__ __launch_bounds__(256) void wtrans(const float* __restrict__ in,
                                              int kstride, long ibs,
                                              u16* __restrict__ out, int ors,
                                              long obs) {
  in += (size_t)blockIdx.z * ibs;
  out += (size_t)blockIdx.z * obs;
  const int n0 = blockIdx.x * 64, k0 = blockIdx.y * 64;
  const int tid = threadIdx.x;
  __shared__ float tt[64][65];
  const int r = tid >> 4, c4 = (tid & 15) * 4;
#pragma unroll
  for (int p = 0; p < 4; ++p) {
    const int rr = r + p * 16;
    const float4 vv =
        *(const float4*)(in + (size_t)(k0 + rr) * kstride + n0 + c4);
    tt[rr][c4] = vv.x;
    tt[rr][c4 + 1] = vv.y;
    tt[rr][c4 + 2] = vv.z;
    tt[rr][c4 + 3] = vv.w;
  }
  __syncthreads();
  const int nl = tid >> 2, kc = (tid & 3) * 16;
  u16x8 a, b;
#pragma unroll
  for (int j = 0; j < 8; ++j) {
    a[j] = f2b(tt[kc + j][nl]);
    b[j] = f2b(tt[kc + 8 + j][nl]);
  }
  u16* orow = out + (size_t)(n0 + nl) * ors + k0 + kc;
  *(u16x8*)(orow) = a;
  *(u16x8*)(orow + 8) = b;
}

__global__ void biascat(const float* __restrict__ bq,
                        const float* __restrict__ bk, float* __restrict__ o) {
  const int i = blockIdx.x * 256 + threadIdx.x;  // 2048 total
  o[i] = (i < 1024) ? bq[i] : bk[i - 1024];
}

__global__ void fillconst(float* __restrict__ p, float v, int n) {
  const int i = blockIdx.x * 256 + threadIdx.x;
  if (i < n) p[i] = v;
}

// ---------------------------------------------------------------------------
// Flash attention v3: paired t-groups (g, 31-g) per wave, 9 iters each.
// grid (4, B*H). Per-group body identical to verified round-3 kernel.
// ---------------------------------------------------------------------------
__global__ __launch_bounds__(256) void attn_fwd(const u16* __restrict__ qf,
                                                const u16* __restrict__ kf,
                                                const u16* __restrict__ vf,
                                                u16* __restrict__ o) {
  const int bh = blockIdx.y;
  const int b = bh >> 4, h = bh & 15;
  const int tid = threadIdx.x, wave = tid >> 6, lane = tid & 63;
  const int l15 = lane & 15, l4 = lane >> 4;
  const int g0 = (int)blockIdx.x * 4 + wave;  // 0..15
  __shared__ u16 Pl[4][1024];  // per-wave 16x64 bf16 P, 128B rows, swizzled

  const f32x4 fz = {0.f, 0.f, 0.f, 0.f};
  const u16* qfb = qf + (size_t)bh * 32 * 2048 + lane * 8;
  const u16* vfb = vf + (size_t)bh * 16 * 2048 + lane * 8;

  for (int grp = 0; grp < 2; ++grp) {
    const int gt = grp ? (31 - g0) : g0;  // pair (g, 31-g): 9 iters total
    const int tw = gt * 16;
    const u16* kfb = kf + ((size_t)(bh * 32 + gt) * 4) * 512 + lane * 8;
    const bf16x8 kh0 = *(const bf16x8*)(kfb);
    const bf16x8 kh1 = *(const bf16x8*)(kfb + 512);
    const bf16x8 kl0 = *(const bf16x8*)(kfb + 1024);
    const bf16x8 kl1 = *(const bf16x8*)(kfb + 1536);

    f32x4 oacc[4] = {fz, fz, fz, fz};
    float mrow[4] = {-1e30f, -1e30f, -1e30f, -1e30f};
    float lrow[4] = {0.f, 0.f, 0.f, 0.f};
    const int niter = (tw + 79) >> 6;

    for (int it = 0; it < niter; ++it) {
      const int s0 = it * 64;
      bf16x8 qh[4][2], ql[4][2];
#pragma unroll
      for (int scb = 0; scb < 4; ++scb) {
        const u16* qp = qfb + (size_t)((s0 >> 4) + scb) * 2048;
        qh[scb][0] = *(const bf16x8*)(qp);
        qh[scb][1] = *(const bf16x8*)(qp + 512);
        ql[scb][0] = *(const bf16x8*)(qp + 1024);
        ql[scb][1] = *(const bf16x8*)(qp + 1536);
      }
      bf16x8 vv[2][4];
#pragma unroll
      for (int h2 = 0; h2 < 2; ++h2) {
        const u16* vp = vfb + (size_t)((s0 >> 5) + h2) * 2048;
#pragma unroll
        for (int eF = 0; eF < 4; ++eF)
          vv[h2][eF] = *(const bf16x8*)(vp + eF * 512);
      }
      f32x4 sf[4];
#pragma unroll
      for (int scb = 0; scb < 4; ++scb) {
        f32x4 z = fz;
        z = mfma16(kh0, qh[scb][0], z);
        z = mfma16(kh1, qh[scb][1], z);
        z = mfma16(kh0, ql[scb][0], z);
        z = mfma16(kh1, ql[scb][1], z);
        z = mfma16(kl0, qh[scb][0], z);
        z = mfma16(kl1, qh[scb][1], z);
        sf[scb] = z;
      }
      if (s0 + 63 > tw) {
#pragma unroll
        for (int scb = 0; scb < 4; ++scb)
#pragma unroll
          for (int r = 0; r < 4; ++r) {
            const int s = s0 + scb * 16 + l15, t = tw + l4 * 4 + r;
            if (s > t) sf[scb][r] = -1e30f;
          }
      }
      float scl[4];
#pragma unroll
      for (int r = 0; r < 4; ++r) {
        float v = fmaxf(fmaxf(sf[0][r], sf[1][r]), fmaxf(sf[2][r], sf[3][r]));
        v = fmaxf(v, __shfl_xor(v, 1));
        v = fmaxf(v, __shfl_xor(v, 2));
        v = fmaxf(v, __shfl_xor(v, 4));
        v = fmaxf(v, __shfl_xor(v, 8));
        const float mn = fmaxf(mrow[r], v);
        scl[r] = __expf(mrow[r] - mn);
        mrow[r] = mn;
      }
      float ps[4] = {0.f, 0.f, 0.f, 0.f};
#pragma unroll
      for (int scb = 0; scb < 4; ++scb)
#pragma unroll
        for (int r = 0; r < 4; ++r) {
          const float p = __expf(sf[scb][r] - mrow[r]);
          sf[scb][r] = p;
          ps[r] += p;
        }
#pragma unroll
      for (int r = 0; r < 4; ++r) {
        float v = ps[r];
        v += __shfl_xor(v, 1);
        v += __shfl_xor(v, 2);
        v += __shfl_xor(v, 4);
        v += __shfl_xor(v, 8);
        lrow[r] = lrow[r] * scl[r] + v;
        oacc[0][r] *= scl[r];
        oacc[1][r] *= scl[r];
        oacc[2][r] *= scl[r];
        oacc[3][r] *= scl[r];
      }
#pragma unroll
      for (int scb = 0; scb < 4; ++scb)
#pragma unroll
        for (int r = 0; r < 4; ++r) {
          const int trow = l4 * 4 + r, scol = scb * 16 + l15;
          const int byte = trow * 128 + ((scol * 2) ^ ((trow & 7) << 4));
          *(u16*)((char*)&Pl[wave][0] + byte) = f2b(sf[scb][r]);
        }
#pragma unroll
      for (int h2 = 0; h2 < 2; ++h2) {
        const bf16x8 pf = *(const bf16x8*)((const char*)&Pl[wave][0] +
                                           l15 * 128 +
                                           (((h2 * 4 + l4) ^ (l15 & 7)) << 4));
#pragma unroll
        for (int eF = 0; eF < 4; ++eF)
          oacc[eF] = mfma16(pf, vv[h2][eF], oacc[eF]);
      }
    }
#pragma unroll
    for (int eF = 0; eF < 4; ++eF)
#pragma unroll
      for (int r = 0; r < 4; ++r) {
        const int t = tw + l4 * 4 + r;
        const float val = oacc[eF][r] / lrow[r];
        o[(size_t)(b * 512 + t) * 1024 + h * 64 + eF * 16 + l15] = f2b(val);
      }
  }
}

// ---------------------------------------------------------------------------
extern "C" void kernel_launch(void* const* d_in, const int* in_sizes, int n_in,
                              void* d_out, int out_size, void* d_ws,
                              size_t ws_size, hipStream_t stream) {
  const float* x = (const float*)d_in[0];
  const float* ga = (const float*)d_in[1];
  const float* ba = (const float*)d_in[2];
  const float* Win = (const float*)d_in[3];
  const float* bin = (const float*)d_in[4];
  const float* Wk = (const float*)d_in[5];
  const float* bk = (const float*)d_in[6];
  const float* Wq = (const float*)d_in[7];
  const float* bq = (const float*)d_in[8];
  const float* Wv = (const float*)d_in[9];
  const float* bv = (const float*)d_in[10];
  const float* Wout = (const float*)d_in[11];
  const float* bout = (const float*)d_in[12];
  const float* gf = (const float*)d_in[13];
  const float* bf_ = (const float*)d_in[14];
  const float* W1 = (const float*)d_in[15];
  const float* b1 = (const float*)d_in[16];
  const float* W2 = (const float*)d_in[17];
  const float* b2 = (const float*)d_in[18];
  float* out = (float*)d_out;

  char* ws = (char*)d_ws;
  size_t off = 0;
  auto alloc = [&](size_t bytes) {
    char* p = ws + off;
    off += (bytes + 255) & ~(size_t)255;
    return p;
  };
  u16* WinT = (u16*)alloc((size_t)1024 * 1024 * 2);  // [n][Whi]
  u16* WqkT = (u16*)alloc((size_t)2048 * 1024 * 2);  // [Wq|Wk] rows
  u16* WvT = (u16*)alloc((size_t)1024 * 1024 * 2);
  u16* WoutT = (u16*)alloc((size_t)1024 * 1024 * 2);
  u16* W1T = (u16*)alloc((size_t)4096 * 1024 * 2);
  u16* W2T = (u16*)alloc((size_t)1024 * 4096 * 2);
  float* bqk = (float*)alloc(2048 * 4);
  char* R1 = alloc((size_t)8192 * 1024 * 2);  // ln1 -> vfb
  char* R2 = alloc((size_t)8192 * 2048 * 2);  // hb -> ob; ln2 2nd half
  char* QK = alloc((size_t)2 * 256 * 32 * 4 * 1024);  // qf+kf (64MB) -> ffn1
  const size_t need = off;                            // ~117 MiB

  if (need > ws_size) {  // diagnostic sentinel: ws too small -> absmax ~12345
    fillconst<<<(out_size + 255) / 256, 256, 0, stream>>>(out, 12345.0f,
                                                          out_size);
    return;
  }

  u16* ln1 = (u16*)R1;                              // 16 MiB (plain bf16)
  u16* vfb = (u16*)R1;                              // after ln1 dead
  u16* hb = (u16*)R2;                               // 16 MiB (plain bf16)
  u16* ob = (u16*)R2;                               // after hb dead
  u16* ln2 = (u16*)(R2 + (size_t)8192 * 1024 * 2);  // second 16 MiB
  u16* qfb = (u16*)QK;                              // 32 MiB
  u16* kfb = (u16*)(QK + (size_t)256 * 32 * 4 * 1024);  // 32 MiB
  u16* ffn1 = (u16*)QK;                             // after attn, q/k dead
  float* x2 = out;                                  // d_out doubles as x2

  // ---- weight prep (bf16 transposes; hi planes only) ----
  wtrans<<<dim3(16, 16, 1), 256, 0, stream>>>(Win, 1024, 0, WinT, 1024, 0);
  wtrans<<<dim3(1, 16, 16), 256, 0, stream>>>(Wq, 64, 65536, WqkT, 1024,
                                              (long)64 * 1024);
  wtrans<<<dim3(1, 16, 16), 256, 0, stream>>>(
      Wk, 64, 65536, WqkT + (size_t)1024 * 1024, 1024, (long)64 * 1024);
  wtrans<<<dim3(1, 16, 16), 256, 0, stream>>>(Wv, 64, 65536, WvT, 1024,
                                              (long)64 * 1024);
  wtrans<<<dim3(16, 16, 1), 256, 0, stream>>>(Wout, 1024, 0, WoutT, 1024, 0);
  wtrans<<<dim3(64, 16, 1), 256, 0, stream>>>(W1, 4096, 0, W1T, 1024, 0);
  wtrans<<<dim3(16, 64, 1), 256, 0, stream>>>(W2, 1024, 0, W2T, 4096, 0);
  biascat<<<8, 256, 0, stream>>>(bq, bk, bqk);

  // ---- pipeline (all GEMMs: verified r7 config, BM=256) ----
  lnorm<<<8192, 256, 0, stream>>>(x, ga, ba, ln1);
  // h = bf16(ln1) @ Win_hi + bin  (1-term, K=1024; plain bf16 output)
  gemm256<256, 128, EPI_BF16><<<256, 512, 0, stream>>>(
      ln1, 1024, 0, WinT, bin, nullptr, hb, nullptr, 1024, 1024, 1024, 1024,
      0);
  // [q|k] = bf16(h) @ [Wq|Wk]_hi  (N=2048, K=1024, grid 256 = 1 full round)
  gemm256<256, 256, EPI_QKFRAG><<<256, 512, 0, stream>>>(
      hb, 1024, 0, WqkT, bqk, nullptr, qfb, kfb, 0, 2048, 1024, 1024, 0);
  // v = bf16(h) @ Wv + bv  (N=1024, BN=128, grid 256 = 1 full round)
  gemm256<256, 128, EPI_VFRAG><<<256, 512, 0, stream>>>(
      hb, 1024, 0, WvT, bv, nullptr, vfb, nullptr, 0, 1024, 1024, 1024, 0);
  attn_fwd<<<dim3(4, 256), 256, 0, stream>>>(qfb, kfb, vfb, ob);
  // x2 = o @ Wout + bout + x   (x2 == d_out)
  gemm256<256, 128, EPI_RES><<<256, 512, 0, stream>>>(
      ob, 1024, 0, WoutT, bout, x, x2, nullptr, 1024, 1024, 1024, 1024, 0);
  lnorm<<<8192, 256, 0, stream>>>(x2, gf, bf_, ln2);
  // ffn1 = relu(ln2 @ W1 + b1)   (overwrites q/k region: dead)
  gemm256<256, 256, EPI_RELU><<<512, 512, 0, stream>>>(
      ln2, 1024, 0, W1T, b1, nullptr, ffn1, nullptr, 4096, 4096, 1024, 1024,
      0);
  // out = ffn1 @ W2 + b2 + x2   (res == Cout == d_out, element-wise safe)
  gemm256<256, 128, EPI_RES><<<256, 512, 0, stream>>>(
      ffn1, 4096, 0, W2T, b2, x2, out, nullptr, 1024, 1024, 4096, 4096, 0);
}

// Round 20
// 358.647 us; speedup vs baseline: 1.3210x; 1.0473x over previous
//
#include <hip/hip_runtime.h>

// ---------------------------------------------------------------------------
// Transformer block (pre-LN attn + FFN), B=16 T=512 D=1024 H=16 HD=64, f32 io.
// bf16 MFMA GEMMs. Precision ladder (calibrated r15-r18, CLOSED at 0.1016):
//   r15 qk 2-term 0.0625 | r16 Win 2-term 0.0645 | r17 h bf16 0.0879 |
//   r18 Win 1-term 0.1016. All matmuls 1-term bf16; q/k OUTPUTS stay
//   hi/lo-split in fragment layout (unscaled scores).
// Dispatch plan (r19/r20): separate qk(grid 256)+v(grid 256) (r18 merge
// refuted: grid 384 = 1.5 rounds -> 75% util). Per-block model:
// T = ~9us fixed + nk*2.23us (BN=256) / nk*1.16us (BN=128).
// r20: 7 wtrans + biascat merged into ONE prep_all kernel (segment table,
// 3336 blocks) -> saves ~7 launch gaps (~2.3us each).
// GEMM v3-256 (verified r7/r13, ~960 TF structural rate): 2 superphases/
// K-tile, counted vmcnt never 0, ring-4 regions, XOR swizzle (0 conflicts),
// XCD swizzle, setprio, scalar epilogues. Schedule variants all refuted.
// Attention v3 (r13): paired t-groups (g,31-g), 9 iters/wave, grid (4,256).
// Workspace (~117 MiB, liveness-aliased), x2 lives in d_out.
// ---------------------------------------------------------------------------

#define DEV __device__ __forceinline__

typedef unsigned short u16;
typedef __attribute__((ext_vector_type(8))) __bf16 bf16x8;
typedef __attribute__((ext_vector_type(4))) float f32x4;
typedef __attribute__((ext_vector_type(8))) unsigned short u16x8;

typedef __attribute__((address_space(1))) void as1_void;
typedef __attribute__((address_space(3))) void as3_void;

DEV u16 f2b(float f) {                       // f32 -> bf16 RNE (finite inputs)
  unsigned u = __float_as_uint(f);
  u = (u + 0x7fffu + ((u >> 16) & 1u)) >> 16;
  return (u16)u;
}
DEV float b2f(u16 h) { return __uint_as_float(((unsigned)h) << 16); }

DEV f32x4 mfma16(bf16x8 a, bf16x8 b, f32x4 c) {
  return __builtin_amdgcn_mfma_f32_16x16x32_bf16(a, b, c, 0, 0, 0);
}

// async global->LDS, 16B per lane, dest = uniform base + lane*16
DEV void gload16(const void* g, void* l) {
  __builtin_amdgcn_global_load_lds((as1_void*)(unsigned long long)g,
                                   (as3_void*)(unsigned long long)l,
                                   16u, 0, 0u);
}

#define EPI_BF16 0
#define EPI_RELU 1
#define EPI_RES 2
#define EPI_QKFRAG 4
#define EPI_VFRAG 5

// ---------------------------------------------------------------------------
// GEMM v3: C[M,N] = A[M,K]*Bt[N,K]^T + bias. BMxBN tile, BK=64.
// Superphase per iteration u (buf cur=u&1):
//   kh0: read A(cur,0)+B(cur,0); stage (u+1).kh1; MFMA; lgkm0; vmcnt; bar
//   kh1: read A(cur,1)+B(cur,1); stage (u+2).kh0; MFMA; lgkm0; vmcnt; bar
// NWAIT = 2*(LA+LB). Tail stages clamp kt (dead regions; counts uniform).
// ---------------------------------------------------------------------------
template <int BM, int BN, int EPI>
__global__ __launch_bounds__((BM == 256) ? 512 : 256, 2) void gemm256(
    const u16* __restrict__ A, int lda, int kdup, const u16* __restrict__ Bt,
    const float* __restrict__ bias, const float* __restrict__ res,
    void* __restrict__ Cout, void* __restrict__ Cout2, int ldc, int N, int K,
    int ldb, int kdupB) {
  constexpr int THREADS = (BM == 256) ? 512 : 256;
  constexpr int NWAVE = THREADS / 64;
  constexpr int NWN = (BN == 256) ? 4 : 2;   // n-waves (64 cols each)
  constexpr int NWM = NWAVE / NWN;           // m-waves
  constexpr int MPW = BM / NWM;              // per-wave m rows
  constexpr int MF = MPW / 16;               // m-frags per wave
  constexpr int LA = BM * 4 / THREADS;       // A gloads/thread/stage (=2)
  constexpr int LB = BN * 4 / THREADS;       // B gloads/thread/stage (1 or 2)
  constexpr int NWAIT = 2 * (LA + LB);       // counted vmcnt
  constexpr int ASZ = BM * 64;               // bytes per (buf,ks) A region
  constexpr int BSZ = BN * 64;
  constexpr int ATOT = 4 * ASZ;
  __shared__ __align__(1024) char lds[4 * ASZ + 4 * BSZ];

  // XCD-contiguous block swizzle (gridDim.x % 8 == 0 by construction)
  const int nwg = (int)gridDim.x;
  const int cpx = nwg >> 3;
  int w = (int)blockIdx.x;
  w = (w & 7) * cpx + (w >> 3);
  const int nbn = N / BN;
  const int bn = w % nbn, bm = w / nbn;

  const int tid = threadIdx.x;
  const int wave = tid >> 6, lane = tid & 63;
  const int l15 = lane & 15, l4 = lane >> 4;
  const int wm = wave / NWN;
  const int wn = wave % NWN;
  const int nk = K >> 6;

  // staging source: dest row-in-16-group = lane>>2, dest chunk = lane&3;
  // source holds chunk (lane&3) ^ ((row>>1)&3)  [same involution as reads]
  const int srow = lane >> 2;
  const int schunk = ((lane & 3) ^ ((srow >> 1) & 3)) << 4;
  const char* Ab = (const char*)A;
  const char* Bb = (const char*)Bt;
  const int arowA = wave * (BM / NWAVE) + srow;
  const int arowB = wave * (BN / NWAVE) + srow;

  auto stageA = [&](int buf, int kh, int kt) {
    const int ktA = (kdup && kt >= kdup) ? kt - kdup : kt;
    const char* s = Ab + (size_t)(bm * BM + arowA) * (size_t)(lda * 2) +
                    ktA * 128 + kh * 64 + schunk;
    char* d = lds + (((buf << 1) | kh) * ASZ) + wave * (LA * 1024);
    gload16(s, d);
    gload16(s + (size_t)16 * (size_t)(lda * 2), d + 1024);
  };
  auto stageB = [&](int buf, int kh, int kt) {
    const int ktB = (kdupB && kt >= kdupB) ? kt - kdupB : kt;
    const char* s = Bb + (size_t)(bn * BN + arowB) * (size_t)(ldb * 2) +
                    ktB * 128 + kh * 64 + schunk;
    char* d = lds + ATOT + (((buf << 1) | kh) * BSZ) + wave * (LB * 1024);
    gload16(s, d);
    if (LB == 2) gload16(s + (size_t)16 * (size_t)(ldb * 2), d + 1024);
  };

  const f32x4 fz = {0.f, 0.f, 0.f, 0.f};
  f32x4 acc[MF][4];
#pragma unroll
  for (int i = 0; i < MF; ++i)
#pragma unroll
    for (int j = 0; j < 4; ++j) acc[i][j] = fz;

  // prologue: tile0 full + tile1 kh0, in steady-state issue order
  stageA(0, 0, 0);
  stageB(0, 0, 0);
  stageA(0, 1, 0);
  stageB(0, 1, 0);
  {
    const int k1 = (1 < nk) ? 1 : nk - 1;
    stageA(1, 0, k1);
    stageB(1, 0, k1);
  }
  asm volatile("s_waitcnt vmcnt(%0)" ::"i"(NWAIT) : "memory");
  __builtin_amdgcn_s_barrier();

  for (int u = 0; u < nk; ++u) {
    const int cur = u & 1;
    const int kp1 = (u + 1 < nk) ? u + 1 : nk - 1;
    const int kp2 = (u + 2 < nk) ? u + 2 : nk - 1;
#pragma unroll
    for (int kh = 0; kh < 2; ++kh) {
      const char* Ar = lds + (((cur << 1) | kh) * ASZ);
      const char* Br = lds + ATOT + (((cur << 1) | kh) * BSZ);
      bf16x8 bfr[4], af[MF];
#pragma unroll
      for (int ni = 0; ni < 4; ++ni) {
        const int n = wn * 64 + ni * 16 + l15;
        bfr[ni] = *(const bf16x8*)(Br + n * 64 + ((l4 ^ ((n >> 1) & 3)) << 4));
      }
#pragma unroll
      for (int mi = 0; mi < MF; ++mi) {
        const int m = wm * MPW + mi * 16 + l15;
        af[mi] = *(const bf16x8*)(Ar + m * 64 + ((l4 ^ ((m >> 1) & 3)) << 4));
      }
      if (kh == 0) {
        stageA(cur ^ 1, 1, kp1);
        stageB(cur ^ 1, 1, kp1);
      } else {
        stageA(cur, 0, kp2);
        stageB(cur, 0, kp2);
      }
      __builtin_amdgcn_s_setprio(1);
#pragma unroll
      for (int mi = 0; mi < MF; ++mi)
#pragma unroll
        for (int ni = 0; ni < 4; ++ni)
          acc[mi][ni] = mfma16(af[mi], bfr[ni], acc[mi][ni]);
      __builtin_amdgcn_s_setprio(0);
      // WAR guard: this kh's region is re-staged next superphase.
      asm volatile("s_waitcnt lgkmcnt(0)" ::: "memory");
      // visibility: next superphase's region complete for all waves.
      asm volatile("s_waitcnt vmcnt(%0)" ::"i"(NWAIT) : "memory");
      __builtin_amdgcn_s_barrier();
    }
  }
  asm volatile("s_waitcnt vmcnt(0)" ::: "memory");

  // ---- epilogue (scalar form; r13-verified) ----
#pragma unroll
  for (int mf = 0; mf < MF; ++mf) {
#pragma unroll
    for (int ni = 0; ni < 4; ++ni) {
      const int gn = bn * BN + wn * 64 + ni * 16 + l15;
      const float bia = bias[gn];
#pragma unroll
      for (int r = 0; r < 4; ++r) {
        const int gm = bm * BM + wm * MPW + mf * 16 + l4 * 4 + r;
        float v = acc[mf][ni][r] + bia;
        if (EPI == EPI_BF16) {
          ((u16*)Cout)[(size_t)gm * ldc + gn] = f2b(v);
        } else if (EPI == EPI_RELU) {
          ((u16*)Cout)[(size_t)gm * ldc + gn] = f2b(v > 0.f ? v : 0.f);
        } else if (EPI == EPI_RES) {
          ((float*)Cout)[(size_t)gm * ldc + gn] =
              v + res[(size_t)gm * ldc + gn];
        } else if (EPI == EPI_QKFRAG) {
          // gm=(b,s); gn<1024: q -> Cout frags; gn>=1024: k -> Cout2.
          // q/k stored hi/lo split in fragment layout.
          const int b = gm >> 9, s = gm & 511;
          const int gs = s >> 4, sr = s & 15;
          const int n = gn & 1023;
          const int h = n >> 6, e = n & 63;
          u16* base = (u16*)((gn >> 10) ? Cout2 : Cout);
          const size_t blk = ((size_t)(b * 16 + h) * 32 + gs) * 4;
          const int idx = ((e >> 3) & 3) * 128 + sr * 8 + (e & 7);
          const u16 hi = f2b(v);
          base[(blk + (e >> 5)) * 512 + idx] = hi;
          base[(blk + 2 + (e >> 5)) * 512 + idx] = f2b(v - b2f(hi));
        } else {  // EPI_VFRAG: B-operand frag for PV
          const int b = gm >> 9, s = gm & 511;
          const int h = gn >> 6, e = gn & 63;
          const size_t blk =
              ((size_t)(b * 16 + h) * 16 + (s >> 5)) * 4 + (e >> 4);
          ((u16*)Cout)[blk * 512 + ((s >> 3) & 3) * 128 + (e & 15) * 8 +
                       (s & 7)] = f2b(v);
        }
      }
    }
  }
}

// ---------------------------------------------------------------------------
// LayerNorm row kernel (plain bf16 output, 1024-wide).
// ---------------------------------------------------------------------------
__global__ __launch_bounds__(256) void lnorm(const float* __restrict__ x,
                                             const float* __restrict__ g,
                                             const float* __restrict__ bt,
                                             u16* __restrict__ out) {
  const int row = blockIdx.x, tid = threadIdx.x;
  const int wave = tid >> 6, lane = tid & 63;
  const float4 v = *(const float4*)(x + (size_t)row * 1024 + tid * 4);
  float xv[4] = {v.x, v.y, v.z, v.w};
  float s = xv[0] + xv[1] + xv[2] + xv[3];
  float s2 = xv[0] * xv[0] + xv[1] * xv[1] + xv[2] * xv[2] + xv[3] * xv[3];
  for (int off = 32; off; off >>= 1) {
    s += __shfl_down(s, off);
    s2 += __shfl_down(s2, off);
  }
  __shared__ float red[8];
  if (lane == 0) {
    red[wave] = s;
    red[4 + wave] = s2;
  }
  __syncthreads();
  const float ts = red[0] + red[1] + red[2] + red[3];
  const float ts2 = red[4] + red[5] + red[6] + red[7];
  const float mean = ts * (1.f / 1024.f);
  const float var = ts2 * (1.f / 1024.f) - mean * mean;
  const float rstd = rsqrtf(var + 1e-5f);
#pragma unroll
  for (int j = 0; j < 4; ++j) {
    const int col = tid * 4 + j;
    const float y = (xv[j] - mean) * rstd * g[col] + bt[col];
    out[(size_t)row * 1024 + col] = f2b(y);
  }
}

// ---------------------------------------------------------------------------
// Merged weight-prep kernel (r20): all 7 transposes + biascat in ONE launch.
// Transpose body identical to verified wtrans (f32[K][cols] 64x64 tile ->
// bf16 out[n][k], hi plane only). Segment table by blockIdx.x:
//   [0,256)     Win   (16 cols-tiles x 16 k-tiles), kstride 1024 -> WinT
//   [256,512)   Wq    batch 16 x (1x16),  kstride 64 -> WqkT[h*64 rows]
//   [512,768)   Wk    -> WqkT + 1024*1024
//   [768,1024)  Wv    -> WvT
//   [1024,1280) Wout  -> WoutT
//   [1280,2304) W1    (64x16), kstride 4096 -> W1T (ors 1024)
//   [2304,3328) W2    (16x64), kstride 1024 -> W2T (ors 4096)
//   [3328,3336) biascat: bqk[0..2047] = [bq|bk]
// ---------------------------------------------------------------------------
DEV void wtrans_body(const float* __restrict__ in, int kstride,
                     u16* __restrict__ out, int ors, int bx, int by, int tid,
                     float (*tt)[65]) {
  const int n0 = bx * 64, k0 = by * 64;
  const int r = tid >> 4, c4 = (tid & 15) * 4;
#pragma unroll
  for (int p = 0; p < 4; ++p) {
    const int rr = r + p * 16;
    const float4 vv =
        *(const float4*)(in + (size_t)(k0 + rr) * kstride + n0 + c4);
    tt[rr][c4] = vv.x;
    tt[rr][c4 + 1] = vv.y;
    tt[rr][c4 + 2] = vv.z;
    tt[rr][c4 + 3] = vv.w;
  }
  __syncthreads();
  const int nl = tid >> 2, kc = (tid & 3) * 16;
  u16x8 a, b;
#pragma unroll
  for (int j = 0; j < 8; ++j) {
    a[j] = f2b(tt[kc + j][nl]);
    b[j] = f2b(tt[kc + 8 + j][nl]);
  }
  u16* orow = out + (size_t)(n0 + nl) * ors + k0 + kc;
  *(u16x8*)(orow) = a;
  *(u16x8*)(orow + 8) = b;
}

__global__ __launch_bounds__(256) void prep_all(
    const float* __restrict__ Win, const float* __restrict__ Wq,
    const float* __restrict__ Wk, const float* __restrict__ Wv,
    const float* __restrict__ Wout, const float* __restrict__ W1,
    const float* __restrict__ W2, const float* __restrict__ bq,
    const float* __restrict__ bk, float* __restrict__ bqk,
    u16* __restrict__ WinT, u16* __restrict__ WqkT, u16* __restrict__ WvT,
    u16* __restrict__ WoutT, u16* __restrict__ W1T, u16* __restrict__ W2T) {
  __shared__ float tt[64][65];
  const int blk = (int)blockIdx.x, tid = threadIdx.x;
  if (blk < 256) {  // Win
    wtrans_body(Win, 1024, WinT, 1024, blk & 15, blk >> 4, tid, tt);
  } else if (blk < 512) {  // Wq (batch h = l>>4)
    const int l = blk - 256, bz = l >> 4, by = l & 15;
    wtrans_body(Wq + (size_t)bz * 65536, 64, WqkT + (size_t)bz * 64 * 1024,
                1024, 0, by, tid, tt);
  } else if (blk < 768) {  // Wk
    const int l = blk - 512, bz = l >> 4, by = l & 15;
    wtrans_body(Wk + (size_t)bz * 65536, 64,
                WqkT + (size_t)1024 * 1024 + (size_t)bz * 64 * 1024, 1024, 0,
                by, tid, tt);
  } else if (blk < 1024) {  // Wv
    const int l = blk - 768, bz = l >> 4, by = l & 15;
    wtrans_body(Wv + (size_t)bz * 65536, 64, WvT + (size_t)bz * 64 * 1024,
                1024, 0, by, tid, tt);
  } else if (blk < 1280) {  // Wout
    const int l = blk - 1024;
    wtrans_body(Wout, 1024, WoutT, 1024, l & 15, l >> 4, tid, tt);
  } else if (blk < 2304) {  // W1 (cols 4096, K 1024)
    const int l = blk - 1280;
    wtrans_body(W1, 4096, W1T, 1024, l & 63, l >> 6, tid, tt);
  } else if (blk < 3328) {  // W2 (cols 1024, K 4096)
    const int l = blk - 2304;
    wtrans_body(W2, 1024, W2T, 4096, l & 15, l >> 4, tid, tt);
  } else {  // biascat
    const int i = (blk - 3328) * 256 + tid;  // 0..2047
    bqk[i] = (i < 1024) ? bq[i] : bk[i - 1024];
  }
}

__global__ void fillconst(float* __restrict__ p, float v, int n) {
  const int i = blockIdx.x * 256 + threadIdx.x;
  if (i < n) p[i] = v;
}

// ---------------------------------------------------------------------------
// Flash attention v3: paired t-groups (g, 31-g) per wave, 9 iters each.
// grid (4, B*H). Per-group body identical to verified round-3 kernel.
// ---------------------------------------------------------------------------
__global__ __launch_bounds__(256) void attn_fwd(const u16* __restrict__ qf,
                                                const u16* __restrict__ kf,
                                                const u16* __restrict__ vf,
                                                u16* __restrict__ o) {
  const int bh = blockIdx.y;
  const int b = bh >> 4, h = bh & 15;
  const int tid = threadIdx.x, wave = tid >> 6, lane = tid & 63;
  const int l15 = lane & 15, l4 = lane >> 4;
  const int g0 = (int)blockIdx.x * 4 + wave;  // 0..15
  __shared__ u16 Pl[4][1024];  // per-wave 16x64 bf16 P, 128B rows, swizzled

  const f32x4 fz = {0.f, 0.f, 0.f, 0.f};
  const u16* qfb = qf + (size_t)bh * 32 * 2048 + lane * 8;
  const u16* vfb = vf + (size_t)bh * 16 * 2048 + lane * 8;

  for (int grp = 0; grp < 2; ++grp) {
    const int gt = grp ? (31 - g0) : g0;  // pair (g, 31-g): 9 iters total
    const int tw = gt * 16;
    const u16* kfb = kf + ((size_t)(bh * 32 + gt) * 4) * 512 + lane * 8;
    const bf16x8 kh0 = *(const bf16x8*)(kfb);
    const bf16x8 kh1 = *(const bf16x8*)(kfb + 512);
    const bf16x8 kl0 = *(const bf16x8*)(kfb + 1024);
    const bf16x8 kl1 = *(const bf16x8*)(kfb + 1536);

    f32x4 oacc[4] = {fz, fz, fz, fz};
    float mrow[4] = {-1e30f, -1e30f, -1e30f, -1e30f};
    float lrow[4] = {0.f, 0.f, 0.f, 0.f};
    const int niter = (tw + 79) >> 6;

    for (int it = 0; it < niter; ++it) {
      const int s0 = it * 64;
      bf16x8 qh[4][2], ql[4][2];
#pragma unroll
      for (int scb = 0; scb < 4; ++scb) {
        const u16* qp = qfb + (size_t)((s0 >> 4) + scb) * 2048;
        qh[scb][0] = *(const bf16x8*)(qp);
        qh[scb][1] = *(const bf16x8*)(qp + 512);
        ql[scb][0] = *(const bf16x8*)(qp + 1024);
        ql[scb][1] = *(const bf16x8*)(qp + 1536);
      }
      bf16x8 vv[2][4];
#pragma unroll
      for (int h2 = 0; h2 < 2; ++h2) {
        const u16* vp = vfb + (size_t)((s0 >> 5) + h2) * 2048;
#pragma unroll
        for (int eF = 0; eF < 4; ++eF)
          vv[h2][eF] = *(const bf16x8*)(vp + eF * 512);
      }
      f32x4 sf[4];
#pragma unroll
      for (int scb = 0; scb < 4; ++scb) {
        f32x4 z = fz;
        z = mfma16(kh0, qh[scb][0], z);
        z = mfma16(kh1, qh[scb][1], z);
        z = mfma16(kh0, ql[scb][0], z);
        z = mfma16(kh1, ql[scb][1], z);
        z = mfma16(kl0, qh[scb][0], z);
        z = mfma16(kl1, qh[scb][1], z);
        sf[scb] = z;
      }
      if (s0 + 63 > tw) {
#pragma unroll
        for (int scb = 0; scb < 4; ++scb)
#pragma unroll
          for (int r = 0; r < 4; ++r) {
            const int s = s0 + scb * 16 + l15, t = tw + l4 * 4 + r;
            if (s > t) sf[scb][r] = -1e30f;
          }
      }
      float scl[4];
#pragma unroll
      for (int r = 0; r < 4; ++r) {
        float v = fmaxf(fmaxf(sf[0][r], sf[1][r]), fmaxf(sf[2][r], sf[3][r]));
        v = fmaxf(v, __shfl_xor(v, 1));
        v = fmaxf(v, __shfl_xor(v, 2));
        v = fmaxf(v, __shfl_xor(v, 4));
        v = fmaxf(v, __shfl_xor(v, 8));
        const float mn = fmaxf(mrow[r], v);
        scl[r] = __expf(mrow[r] - mn);
        mrow[r] = mn;
      }
      float ps[4] = {0.f, 0.f, 0.f, 0.f};
#pragma unroll
      for (int scb = 0; scb < 4; ++scb)
#pragma unroll
        for (int r = 0; r < 4; ++r) {
          const float p = __expf(sf[scb][r] - mrow[r]);
          sf[scb][r] = p;
          ps[r] += p;
        }
#pragma unroll
      for (int r = 0; r < 4; ++r) {
        float v = ps[r];
        v += __shfl_xor(v, 1);
        v += __shfl_xor(v, 2);
        v += __shfl_xor(v, 4);
        v += __shfl_xor(v, 8);
        lrow[r] = lrow[r] * scl[r] + v;
        oacc[0][r] *= scl[r];
        oacc[1][r] *= scl[r];
        oacc[2][r] *= scl[r];
        oacc[3][r] *= scl[r];
      }
#pragma unroll
      for (int scb = 0; scb < 4; ++scb)
#pragma unroll
        for (int r = 0; r < 4; ++r) {
          const int trow = l4 * 4 + r, scol = scb * 16 + l15;
          const int byte = trow * 128 + ((scol * 2) ^ ((trow & 7) << 4));
          *(u16*)((char*)&Pl[wave][0] + byte) = f2b(sf[scb][r]);
        }
#pragma unroll
      for (int h2 = 0; h2 < 2; ++h2) {
        const bf16x8 pf = *(const bf16x8*)((const char*)&Pl[wave][0] +
                                           l15 * 128 +
                                           (((h2 * 4 + l4) ^ (l15 & 7)) << 4));
#pragma unroll
        for (int eF = 0; eF < 4; ++eF)
          oacc[eF] = mfma16(pf, vv[h2][eF], oacc[eF]);
      }
    }
#pragma unroll
    for (int eF = 0; eF < 4; ++eF)
#pragma unroll
      for (int r = 0; r < 4; ++r) {
        const int t = tw + l4 * 4 + r;
        const float val = oacc[eF][r] / lrow[r];
        o[(size_t)(b * 512 + t) * 1024 + h * 64 + eF * 16 + l15] = f2b(val);
      }
  }
}

// ---------------------------------------------------------------------------
extern "C" void kernel_launch(void* const* d_in, const int* in_sizes, int n_in,
                              void* d_out, int out_size, void* d_ws,
                              size_t ws_size, hipStream_t stream) {
  const float* x = (const float*)d_in[0];
  const float* ga = (const float*)d_in[1];
  const float* ba = (const float*)d_in[2];
  const float* Win = (const float*)d_in[3];
  const float* bin = (const float*)d_in[4];
  const float* Wk = (const float*)d_in[5];
  const float* bk = (const float*)d_in[6];
  const float* Wq = (const float*)d_in[7];
  const float* bq = (const float*)d_in[8];
  const float* Wv = (const float*)d_in[9];
  const float* bv = (const float*)d_in[10];
  const float* Wout = (const float*)d_in[11];
  const float* bout = (const float*)d_in[12];
  const float* gf = (const float*)d_in[13];
  const float* bf_ = (const float*)d_in[14];
  const float* W1 = (const float*)d_in[15];
  const float* b1 = (const float*)d_in[16];
  const float* W2 = (const float*)d_in[17];
  const float* b2 = (const float*)d_in[18];
  float* out = (float*)d_out;

  char* ws = (char*)d_ws;
  size_t off = 0;
  auto alloc = [&](size_t bytes) {
    char* p = ws + off;
    off += (bytes + 255) & ~(size_t)255;
    return p;
  };
  u16* WinT = (u16*)alloc((size_t)1024 * 1024 * 2);  // [n][Whi]
  u16* WqkT = (u16*)alloc((size_t)2048 * 1024 * 2);  // [Wq|Wk] rows
  u16* WvT = (u16*)alloc((size_t)1024 * 1024 * 2);
  u16* WoutT = (u16*)alloc((size_t)1024 * 1024 * 2);
  u16* W1T = (u16*)alloc((size_t)4096 * 1024 * 2);
  u16* W2T = (u16*)alloc((size_t)1024 * 4096 * 2);
  float* bqk = (float*)alloc(2048 * 4);
  char* R1 = alloc((size_t)8192 * 1024 * 2);  // ln1 -> vfb
  char* R2 = alloc((size_t)8192 * 2048 * 2);  // hb -> ob; ln2 2nd half
  char* QK = alloc((size_t)2 * 256 * 32 * 4 * 1024);  // qf+kf (64MB) -> ffn1
  const size_t need = off;                            // ~117 MiB

  if (need > ws_size) {  // diagnostic sentinel: ws too small -> absmax ~12345
    fillconst<<<(out_size + 255) / 256, 256, 0, stream>>>(out, 12345.0f,
                                                          out_size);
    return;
  }

  u16* ln1 = (u16*)R1;                              // 16 MiB (plain bf16)
  u16* vfb = (u16*)R1;                              // after ln1 dead
  u16* hb = (u16*)R2;                               // 16 MiB (plain bf16)
  u16* ob = (u16*)R2;                               // after hb dead
  u16* ln2 = (u16*)(R2 + (size_t)8192 * 1024 * 2);  // second 16 MiB
  u16* qfb = (u16*)QK;                              // 32 MiB
  u16* kfb = (u16*)(QK + (size_t)256 * 32 * 4 * 1024);  // 32 MiB
  u16* ffn1 = (u16*)QK;                             // after attn, q/k dead
  float* x2 = out;                                  // d_out doubles as x2

  // ---- weight prep: ONE merged launch (7 transposes + biascat) ----
  prep_all<<<3336, 256, 0, stream>>>(Win, Wq, Wk, Wv, Wout, W1, W2, bq, bk,
                                     bqk, WinT, WqkT, WvT, WoutT, W1T, W2T);

  // ---- pipeline (all GEMMs: verified r7 config, BM=256) ----
  lnorm<<<8192, 256, 0, stream>>>(x, ga, ba, ln1);
  // h = bf16(ln1) @ Win_hi + bin  (1-term, K=1024; plain bf16 output)
  gemm256<256, 128, EPI_BF16><<<256, 512, 0, stream>>>(
      ln1, 1024, 0, WinT, bin, nullptr, hb, nullptr, 1024, 1024, 1024, 1024,
      0);
  // [q|k] = bf16(h) @ [Wq|Wk]_hi  (N=2048, K=1024, grid 256 = 1 full round)
  gemm256<256, 256, EPI_QKFRAG><<<256, 512, 0, stream>>>(
      hb, 1024, 0, WqkT, bqk, nullptr, qfb, kfb, 0, 2048, 1024, 1024, 0);
  // v = bf16(h) @ Wv + bv  (N=1024, BN=128, grid 256 = 1 full round)
  gemm256<256, 128, EPI_VFRAG><<<256, 512, 0, stream>>>(
      hb, 1024, 0, WvT, bv, nullptr, vfb, nullptr, 0, 1024, 1024, 1024, 0);
  attn_fwd<<<dim3(4, 256), 256, 0, stream>>>(qfb, kfb, vfb, ob);
  // x2 = o @ Wout + bout + x   (x2 == d_out)
  gemm256<256, 128, EPI_RES><<<256, 512, 0, stream>>>(
      ob, 1024, 0, WoutT, bout, x, x2, nullptr, 1024, 1024, 1024, 1024, 0);
  lnorm<<<8192, 256, 0, stream>>>(x2, gf, bf_, ln2);
  // ffn1 = relu(ln2 @ W1 + b1)   (overwrites q/k region: dead)
  gemm256<256, 256, EPI_RELU><<<512, 512, 0, stream>>>(
      ln2, 1024, 0, W1T, b1, nullptr, ffn1, nullptr, 4096, 4096, 1024, 1024,
      0);
  // out = ffn1 @ W2 + b2 + x2   (res == Cout == d_out, element-wise safe)
  gemm256<256, 128, EPI_RES><<<256, 512, 0, stream>>>(
      ffn1, 4096, 0, W2T, b2, x2, out, nullptr, 1024, 1024, 4096, 4096, 0);
}

// Round 21
// 349.682 us; speedup vs baseline: 1.3548x; 1.0256x over previous
//
#include <hip/hip_runtime.h>

// ---------------------------------------------------------------------------
// Transformer block (pre-LN attn + FFN), B=16 T=512 D=1024 H=16 HD=64, f32 io.
// bf16 MFMA GEMMs. Precision ladder (calibrated r15-r18, CLOSED at 0.1016):
//   r15 qk 2-term 0.0625 | r16 Win 2-term 0.0645 | r17 h bf16 0.0879 |
//   r18 Win 1-term 0.1016. All matmuls 1-term bf16; q/k OUTPUTS stay
//   hi/lo-split in fragment layout (unscaled scores).
// r21 fusions (dependency-safe, math bit-identical):
//   - qkv_fused: qk(256x256) + v(256x128) phases in ONE dispatch (both read
//     hb, both grid 256 = 1 full round; shares prologue/epilogue/launch gap).
//   - lnorm1 merged into prep_all (depends only on input x).
// Dispatch count 10 -> 8. Per-block model: T = ~9us fixed + nk*2.23us
// (BN=256) / nk*1.16us (BN=128); all GEMMs at ~960 TF structural rate.
// GEMM v3-256 (verified r7/r13): 2 superphases/K-tile, counted vmcnt never
// 0, ring-4 regions, XOR swizzle (0 conflicts), XCD swizzle, setprio,
// scalar epilogues. Schedule variants all refuted (r5/r8/r11/r12).
// Attention v3 (r13): paired t-groups (g,31-g), 9 iters/wave, grid (4,256).
// Workspace (~117 MiB, liveness-aliased), x2 lives in d_out.
// ---------------------------------------------------------------------------

#define DEV __device__ __forceinline__

typedef unsigned short u16;
typedef __attribute__((ext_vector_type(8))) __bf16 bf16x8;
typedef __attribute__((ext_vector_type(4))) float f32x4;
typedef __attribute__((ext_vector_type(8))) unsigned short u16x8;

typedef __attribute__((address_space(1))) void as1_void;
typedef __attribute__((address_space(3))) void as3_void;

DEV u16 f2b(float f) {                       // f32 -> bf16 RNE (finite inputs)
  unsigned u = __float_as_uint(f);
  u = (u + 0x7fffu + ((u >> 16) & 1u)) >> 16;
  return (u16)u;
}
DEV float b2f(u16 h) { return __uint_as_float(((unsigned)h) << 16); }

DEV f32x4 mfma16(bf16x8 a, bf16x8 b, f32x4 c) {
  return __builtin_amdgcn_mfma_f32_16x16x32_bf16(a, b, c, 0, 0, 0);
}

// async global->LDS, 16B per lane, dest = uniform base + lane*16
DEV void gload16(const void* g, void* l) {
  __builtin_amdgcn_global_load_lds((as1_void*)(unsigned long long)g,
                                   (as3_void*)(unsigned long long)l,
                                   16u, 0, 0u);
}

#define EPI_BF16 0
#define EPI_RELU 1
#define EPI_RES 2
#define EPI_QKFRAG 4
#define EPI_VFRAG 5

// ---------------------------------------------------------------------------
// GEMM v3 core (device function; r21 refactor of the verified r7/r13 body).
// C[M,N] = A[M,K]*Bt[N,K]^T + bias. BMxBN tile, BK=64, 512 thr (BM=256).
// Superphase per iteration u (buf cur=u&1):
//   kh0: read A(cur,0)+B(cur,0); stage (u+1).kh1; MFMA; lgkm0; vmcnt; bar
//   kh1: read A(cur,1)+B(cur,1); stage (u+2).kh0; MFMA; lgkm0; vmcnt; bar
// NWAIT = 2*(LA+LB). Tail stages clamp kt (dead regions; counts uniform).
// ---------------------------------------------------------------------------
template <int BM, int BN, int EPI>
DEV void gemm_core(const u16* __restrict__ A, int lda, int kdup,
                   const u16* __restrict__ Bt, const float* __restrict__ bias,
                   const float* __restrict__ res, void* __restrict__ Cout,
                   void* __restrict__ Cout2, int ldc, int N, int K, int ldb,
                   int kdupB, char* lds, int w) {
  constexpr int THREADS = (BM == 256) ? 512 : 256;
  constexpr int NWAVE = THREADS / 64;
  constexpr int NWN = (BN == 256) ? 4 : 2;   // n-waves (64 cols each)
  constexpr int NWM = NWAVE / NWN;           // m-waves
  constexpr int MPW = BM / NWM;              // per-wave m rows
  constexpr int MF = MPW / 16;               // m-frags per wave
  constexpr int LA = BM * 4 / THREADS;       // A gloads/thread/stage (=2)
  constexpr int LB = BN * 4 / THREADS;       // B gloads/thread/stage (1 or 2)
  constexpr int NWAIT = 2 * (LA + LB);       // counted vmcnt
  constexpr int ASZ = BM * 64;               // bytes per (buf,ks) A region
  constexpr int BSZ = BN * 64;
  constexpr int ATOT = 4 * ASZ;

  const int nbn = N / BN;
  const int bn = w % nbn, bm = w / nbn;

  const int tid = threadIdx.x;
  const int wave = tid >> 6, lane = tid & 63;
  const int l15 = lane & 15, l4 = lane >> 4;
  const int wm = wave / NWN;
  const int wn = wave % NWN;
  const int nk = K >> 6;

  // staging source: dest row-in-16-group = lane>>2, dest chunk = lane&3;
  // source holds chunk (lane&3) ^ ((row>>1)&3)  [same involution as reads]
  const int srow = lane >> 2;
  const int schunk = ((lane & 3) ^ ((srow >> 1) & 3)) << 4;
  const char* Ab = (const char*)A;
  const char* Bb = (const char*)Bt;
  const int arowA = wave * (BM / NWAVE) + srow;
  const int arowB = wave * (BN / NWAVE) + srow;

  auto stageA = [&](int buf, int kh, int kt) {
    const int ktA = (kdup && kt >= kdup) ? kt - kdup : kt;
    const char* s = Ab + (size_t)(bm * BM + arowA) * (size_t)(lda * 2) +
                    ktA * 128 + kh * 64 + schunk;
    char* d = lds + (((buf << 1) | kh) * ASZ) + wave * (LA * 1024);
    gload16(s, d);
    gload16(s + (size_t)16 * (size_t)(lda * 2), d + 1024);
  };
  auto stageB = [&](int buf, int kh, int kt) {
    const int ktB = (kdupB && kt >= kdupB) ? kt - kdupB : kt;
    const char* s = Bb + (size_t)(bn * BN + arowB) * (size_t)(ldb * 2) +
                    ktB * 128 + kh * 64 + schunk;
    char* d = lds + ATOT + (((buf << 1) | kh) * BSZ) + wave * (LB * 1024);
    gload16(s, d);
    if (LB == 2) gload16(s + (size_t)16 * (size_t)(ldb * 2), d + 1024);
  };

  const f32x4 fz = {0.f, 0.f, 0.f, 0.f};
  f32x4 acc[MF][4];
#pragma unroll
  for (int i = 0; i < MF; ++i)
#pragma unroll
    for (int j = 0; j < 4; ++j) acc[i][j] = fz;

  // prologue: tile0 full + tile1 kh0, in steady-state issue order
  stageA(0, 0, 0);
  stageB(0, 0, 0);
  stageA(0, 1, 0);
  stageB(0, 1, 0);
  {
    const int k1 = (1 < nk) ? 1 : nk - 1;
    stageA(1, 0, k1);
    stageB(1, 0, k1);
  }
  asm volatile("s_waitcnt vmcnt(%0)" ::"i"(NWAIT) : "memory");
  __builtin_amdgcn_s_barrier();

  for (int u = 0; u < nk; ++u) {
    const int cur = u & 1;
    const int kp1 = (u + 1 < nk) ? u + 1 : nk - 1;
    const int kp2 = (u + 2 < nk) ? u + 2 : nk - 1;
#pragma unroll
    for (int kh = 0; kh < 2; ++kh) {
      const char* Ar = lds + (((cur << 1) | kh) * ASZ);
      const char* Br = lds + ATOT + (((cur << 1) | kh) * BSZ);
      bf16x8 bfr[4], af[MF];
#pragma unroll
      for (int ni = 0; ni < 4; ++ni) {
        const int n = wn * 64 + ni * 16 + l15;
        bfr[ni] = *(const bf16x8*)(Br + n * 64 + ((l4 ^ ((n >> 1) & 3)) << 4));
      }
#pragma unroll
      for (int mi = 0; mi < MF; ++mi) {
        const int m = wm * MPW + mi * 16 + l15;
        af[mi] = *(const bf16x8*)(Ar + m * 64 + ((l4 ^ ((m >> 1) & 3)) << 4));
      }
      if (kh == 0) {
        stageA(cur ^ 1, 1, kp1);
        stageB(cur ^ 1, 1, kp1);
      } else {
        stageA(cur, 0, kp2);
        stageB(cur, 0, kp2);
      }
      __builtin_amdgcn_s_setprio(1);
#pragma unroll
      for (int mi = 0; mi < MF; ++mi)
#pragma unroll
        for (int ni = 0; ni < 4; ++ni)
          acc[mi][ni] = mfma16(af[mi], bfr[ni], acc[mi][ni]);
      __builtin_amdgcn_s_setprio(0);
      // WAR guard: this kh's region is re-staged next superphase.
      asm volatile("s_waitcnt lgkmcnt(0)" ::: "memory");
      // visibility: next superphase's region complete for all waves.
      asm volatile("s_waitcnt vmcnt(%0)" ::"i"(NWAIT) : "memory");
      __builtin_amdgcn_s_barrier();
    }
  }
  asm volatile("s_waitcnt vmcnt(0)" ::: "memory");

  // ---- epilogue (scalar form; r13-verified) ----
#pragma unroll
  for (int mf = 0; mf < MF; ++mf) {
#pragma unroll
    for (int ni = 0; ni < 4; ++ni) {
      const int gn = bn * BN + wn * 64 + ni * 16 + l15;
      const float bia = bias[gn];
#pragma unroll
      for (int r = 0; r < 4; ++r) {
        const int gm = bm * BM + wm * MPW + mf * 16 + l4 * 4 + r;
        float v = acc[mf][ni][r] + bia;
        if (EPI == EPI_BF16) {
          ((u16*)Cout)[(size_t)gm * ldc + gn] = f2b(v);
        } else if (EPI == EPI_RELU) {
          ((u16*)Cout)[(size_t)gm * ldc + gn] = f2b(v > 0.f ? v : 0.f);
        } else if (EPI == EPI_RES) {
          ((float*)Cout)[(size_t)gm * ldc + gn] =
              v + res[(size_t)gm * ldc + gn];
        } else if (EPI == EPI_QKFRAG) {
          // gm=(b,s); gn<1024: q -> Cout frags; gn>=1024: k -> Cout2.
          // q/k stored hi/lo split in fragment layout.
          const int b = gm >> 9, s = gm & 511;
          const int gs = s >> 4, sr = s & 15;
          const int n = gn & 1023;
          const int h = n >> 6, e = n & 63;
          u16* base = (u16*)((gn >> 10) ? Cout2 : Cout);
          const size_t blk = ((size_t)(b * 16 + h) * 32 + gs) * 4;
          const int idx = ((e >> 3) & 3) * 128 + sr * 8 + (e & 7);
          const u16 hi = f2b(v);
          base[(blk + (e >> 5)) * 512 + idx] = hi;
          base[(blk + 2 + (e >> 5)) * 512 + idx] = f2b(v - b2f(hi));
        } else {  // EPI_VFRAG: B-operand frag for PV
          const int b = gm >> 9, s = gm & 511;
          const int h = gn >> 6, e = gn & 63;
          const size_t blk =
              ((size_t)(b * 16 + h) * 16 + (s >> 5)) * 4 + (e >> 4);
          ((u16*)Cout)[blk * 512 + ((s >> 3) & 3) * 128 + (e & 15) * 8 +
                       (s & 7)] = f2b(v);
        }
      }
    }
  }
}

// ---- thin wrappers ----
template <int BM, int BN, int EPI>
__global__ __launch_bounds__((BM == 256) ? 512 : 256, 2) void gemm256(
    const u16* __restrict__ A, int lda, int kdup, const u16* __restrict__ Bt,
    const float* __restrict__ bias, const float* __restrict__ res,
    void* __restrict__ Cout, void* __restrict__ Cout2, int ldc, int N, int K,
    int ldb, int kdupB) {
  constexpr int ASZ = BM * 64;
  constexpr int BSZ = BN * 64;
  __shared__ __align__(1024) char lds[4 * ASZ + 4 * BSZ];
  const int nwg = (int)gridDim.x;
  const int cpx = nwg >> 3;
  int w = (int)blockIdx.x;
  w = (w & 7) * cpx + (w >> 3);
  gemm_core<BM, BN, EPI>(A, lda, kdup, Bt, bias, res, Cout, Cout2, ldc, N, K,
                         ldb, kdupB, lds, w);
}

// Fused qk + v (r21): both read hb; qk = 256x256 tiles (nbn=8), v = 256x128
// tiles (nbn=8) -> identical block->tile mapping at grid 256. Phase 2's
// staging is safe: after phase 1's final K-loop barrier no wave reads LDS.
__global__ __launch_bounds__(512, 2) void qkv_fused(
    const u16* __restrict__ hb, const u16* __restrict__ WqkT,
    const u16* __restrict__ WvT, const float* __restrict__ bqk,
    const float* __restrict__ bv, u16* __restrict__ qfb,
    u16* __restrict__ kfb, u16* __restrict__ vfb) {
  __shared__ __align__(1024) char lds[131072];  // max(qk 128KB, v 96KB)
  const int nwg = (int)gridDim.x;
  const int cpx = nwg >> 3;
  int w = (int)blockIdx.x;
  w = (w & 7) * cpx + (w >> 3);
  gemm_core<256, 256, EPI_QKFRAG>(hb, 1024, 0, WqkT, bqk, nullptr, qfb, kfb,
                                  0, 2048, 1024, 1024, 0, lds, w);
  __syncthreads();
  gemm_core<256, 128, EPI_VFRAG>(hb, 1024, 0, WvT, bv, nullptr, vfb, nullptr,
                                 0, 1024, 1024, 1024, 0, lds, w);
}

// ---------------------------------------------------------------------------
// LayerNorm row body (plain bf16 output, 1024-wide) + standalone kernel.
// ---------------------------------------------------------------------------
DEV void lnorm_body(const float* __restrict__ x, const float* __restrict__ g,
                    const float* __restrict__ bt, u16* __restrict__ out,
                    int row, int tid, float* red) {
  const int wave = tid >> 6, lane = tid & 63;
  const float4 v = *(const float4*)(x + (size_t)row * 1024 + tid * 4);
  float xv[4] = {v.x, v.y, v.z, v.w};
  float s = xv[0] + xv[1] + xv[2] + xv[3];
  float s2 = xv[0] * xv[0] + xv[1] * xv[1] + xv[2] * xv[2] + xv[3] * xv[3];
  for (int off = 32; off; off >>= 1) {
    s += __shfl_down(s, off);
    s2 += __shfl_down(s2, off);
  }
  if (lane == 0) {
    red[wave] = s;
    red[4 + wave] = s2;
  }
  __syncthreads();
  const float ts = red[0] + red[1] + red[2] + red[3];
  const float ts2 = red[4] + red[5] + red[6] + red[7];
  const float mean = ts * (1.f / 1024.f);
  const float var = ts2 * (1.f / 1024.f) - mean * mean;
  const float rstd = rsqrtf(var + 1e-5f);
#pragma unroll
  for (int j = 0; j < 4; ++j) {
    const int col = tid * 4 + j;
    const float y = (xv[j] - mean) * rstd * g[col] + bt[col];
    out[(size_t)row * 1024 + col] = f2b(y);
  }
}

__global__ __launch_bounds__(256) void lnorm(const float* __restrict__ x,
                                             const float* __restrict__ g,
                                             const float* __restrict__ bt,
                                             u16* __restrict__ out) {
  __shared__ float red[8];
  lnorm_body(x, g, bt, out, blockIdx.x, threadIdx.x, red);
}

// ---------------------------------------------------------------------------
// Merged prep kernel (r20/r21): 7 transposes + biascat + lnorm1.
// Segment table by blockIdx.x:
//   [0,256) Win | [256,512) Wq | [512,768) Wk | [768,1024) Wv |
//   [1024,1280) Wout | [1280,2304) W1 | [2304,3328) W2 |
//   [3328,3336) biascat | [3336,11528) lnorm1 rows (depends only on x).
// ---------------------------------------------------------------------------
DEV void wtrans_body(const float* __restrict__ in, int kstride,
                     u16* __restrict__ out, int ors, int bx, int by, int tid,
                     float (*tt)[65]) {
  const int n0 = bx * 64, k0 = by * 64;
  const int r = tid >> 4, c4 = (tid & 15) * 4;
#pragma unroll
  for (int p = 0; p < 4; ++p) {
    const int rr = r + p * 16;
    const float4 vv =
        *(const float4*)(in + (size_t)(k0 + rr) * kstride + n0 + c4);
    tt[rr][c4] = vv.x;
    tt[rr][c4 + 1] = vv.y;
    tt[rr][c4 + 2] = vv.z;
    tt[rr][c4 + 3] = vv.w;
  }
  __syncthreads();
  const int nl = tid >> 2, kc = (tid & 3) * 16;
  u16x8 a, b;
#pragma unroll
  for (int j = 0; j < 8; ++j) {
    a[j] = f2b(tt[kc + j][nl]);
    b[j] = f2b(tt[kc + 8 + j][nl]);
  }
  u16* orow = out + (size_t)(n0 + nl) * ors + k0 + kc;
  *(u16x8*)(orow) = a;
  *(u16x8*)(orow + 8) = b;
}

__global__ __launch_bounds__(256) void prep_all(
    const float* __restrict__ Win, const float* __restrict__ Wq,
    const float* __restrict__ Wk, const float* __restrict__ Wv,
    const float* __restrict__ Wout, const float* __restrict__ W1,
    const float* __restrict__ W2, const float* __restrict__ bq,
    const float* __restrict__ bk, float* __restrict__ bqk,
    u16* __restrict__ WinT, u16* __restrict__ WqkT, u16* __restrict__ WvT,
    u16* __restrict__ WoutT, u16* __restrict__ W1T, u16* __restrict__ W2T,
    const float* __restrict__ x, const float* __restrict__ ga,
    const float* __restrict__ ba, u16* __restrict__ ln1) {
  __shared__ float tt[64][65];
  __shared__ float red[8];
  const int blk = (int)blockIdx.x, tid = threadIdx.x;
  if (blk < 256) {  // Win
    wtrans_body(Win, 1024, WinT, 1024, blk & 15, blk >> 4, tid, tt);
  } else if (blk < 512) {  // Wq (batch h = l>>4)
    const int l = blk - 256, bz = l >> 4, by = l & 15;
    wtrans_body(Wq + (size_t)bz * 65536, 64, WqkT + (size_t)bz * 64 * 1024,
                1024, 0, by, tid, tt);
  } else if (blk < 768) {  // Wk
    const int l = blk - 512, bz = l >> 4, by = l & 15;
    wtrans_body(Wk + (size_t)bz * 65536, 64,
                WqkT + (size_t)1024 * 1024 + (size_t)bz * 64 * 1024, 1024, 0,
                by, tid, tt);
  } else if (blk < 1024) {  // Wv
    const int l = blk - 768, bz = l >> 4, by = l & 15;
    wtrans_body(Wv + (size_t)bz * 65536, 64, WvT + (size_t)bz * 64 * 1024,
                1024, 0, by, tid, tt);
  } else if (blk < 1280) {  // Wout
    const int l = blk - 1024;
    wtrans_body(Wout, 1024, WoutT, 1024, l & 15, l >> 4, tid, tt);
  } else if (blk < 2304) {  // W1 (cols 4096, K 1024)
    const int l = blk - 1280;
    wtrans_body(W1, 4096, W1T, 1024, l & 63, l >> 6, tid, tt);
  } else if (blk < 3328) {  // W2 (cols 1024, K 4096)
    const int l = blk - 2304;
    wtrans_body(W2, 1024, W2T, 4096, l & 15, l >> 4, tid, tt);
  } else if (blk < 3336) {  // biascat
    const int i = (blk - 3328) * 256 + tid;  // 0..2047
    bqk[i] = (i < 1024) ? bq[i] : bk[i - 1024];
  } else {  // lnorm1 rows
    lnorm_body(x, ga, ba, ln1, blk - 3336, tid, red);
  }
}

__global__ void fillconst(float* __restrict__ p, float v, int n) {
  const int i = blockIdx.x * 256 + threadIdx.x;
  if (i < n) p[i] = v;
}

// ---------------------------------------------------------------------------
// Flash attention v3: paired t-groups (g, 31-g) per wave, 9 iters each.
// grid (4, B*H). Per-group body identical to verified round-3 kernel.
// ---------------------------------------------------------------------------
__global__ __launch_bounds__(256) void attn_fwd(const u16* __restrict__ qf,
                                                const u16* __restrict__ kf,
                                                const u16* __restrict__ vf,
                                                u16* __restrict__ o) {
  const int bh = blockIdx.y;
  const int b = bh >> 4, h = bh & 15;
  const int tid = threadIdx.x, wave = tid >> 6, lane = tid & 63;
  const int l15 = lane & 15, l4 = lane >> 4;
  const int g0 = (int)blockIdx.x * 4 + wave;  // 0..15
  __shared__ u16 Pl[4][1024];  // per-wave 16x64 bf16 P, 128B rows, swizzled

  const f32x4 fz = {0.f, 0.f, 0.f, 0.f};
  const u16* qfb = qf + (size_t)bh * 32 * 2048 + lane * 8;
  const u16* vfb = vf + (size_t)bh * 16 * 2048 + lane * 8;

  for (int grp = 0; grp < 2; ++grp) {
    const int gt = grp ? (31 - g0) : g0;  // pair (g, 31-g): 9 iters total
    const int tw = gt * 16;
    const u16* kfb = kf + ((size_t)(bh * 32 + gt) * 4) * 512 + lane * 8;
    const bf16x8 kh0 = *(const bf16x8*)(kfb);
    const bf16x8 kh1 = *(const bf16x8*)(kfb + 512);
    const bf16x8 kl0 = *(const bf16x8*)(kfb + 1024);
    const bf16x8 kl1 = *(const bf16x8*)(kfb + 1536);

    f32x4 oacc[4] = {fz, fz, fz, fz};
    float mrow[4] = {-1e30f, -1e30f, -1e30f, -1e30f};
    float lrow[4] = {0.f, 0.f, 0.f, 0.f};
    const int niter = (tw + 79) >> 6;

    for (int it = 0; it < niter; ++it) {
      const int s0 = it * 64;
      bf16x8 qh[4][2], ql[4][2];
#pragma unroll
      for (int scb = 0; scb < 4; ++scb) {
        const u16* qp = qfb + (size_t)((s0 >> 4) + scb) * 2048;
        qh[scb][0] = *(const bf16x8*)(qp);
        qh[scb][1] = *(const bf16x8*)(qp + 512);
        ql[scb][0] = *(const bf16x8*)(qp + 1024);
        ql[scb][1] = *(const bf16x8*)(qp + 1536);
      }
      bf16x8 vv[2][4];
#pragma unroll
      for (int h2 = 0; h2 < 2; ++h2) {
        const u16* vp = vfb + (size_t)((s0 >> 5) + h2) * 2048;
#pragma unroll
        for (int eF = 0; eF < 4; ++eF)
          vv[h2][eF] = *(const bf16x8*)(vp + eF * 512);
      }
      f32x4 sf[4];
#pragma unroll
      for (int scb = 0; scb < 4; ++scb) {
        f32x4 z = fz;
        z = mfma16(kh0, qh[scb][0], z);
        z = mfma16(kh1, qh[scb][1], z);
        z = mfma16(kh0, ql[scb][0], z);
        z = mfma16(kh1, ql[scb][1], z);
        z = mfma16(kl0, qh[scb][0], z);
        z = mfma16(kl1, qh[scb][1], z);
        sf[scb] = z;
      }
      if (s0 + 63 > tw) {
#pragma unroll
        for (int scb = 0; scb < 4; ++scb)
#pragma unroll
          for (int r = 0; r < 4; ++r) {
            const int s = s0 + scb * 16 + l15, t = tw + l4 * 4 + r;
            if (s > t) sf[scb][r] = -1e30f;
          }
      }
      float scl[4];
#pragma unroll
      for (int r = 0; r < 4; ++r) {
        float v = fmaxf(fmaxf(sf[0][r], sf[1][r]), fmaxf(sf[2][r], sf[3][r]));
        v = fmaxf(v, __shfl_xor(v, 1));
        v = fmaxf(v, __shfl_xor(v, 2));
        v = fmaxf(v, __shfl_xor(v, 4));
        v = fmaxf(v, __shfl_xor(v, 8));
        const float mn = fmaxf(mrow[r], v);
        scl[r] = __expf(mrow[r] - mn);
        mrow[r] = mn;
      }
      float ps[4] = {0.f, 0.f, 0.f, 0.f};
#pragma unroll
      for (int scb = 0; scb < 4; ++scb)
#pragma unroll
        for (int r = 0; r < 4; ++r) {
          const float p = __expf(sf[scb][r] - mrow[r]);
          sf[scb][r] = p;
          ps[r] += p;
        }
#pragma unroll
      for (int r = 0; r < 4; ++r) {
        float v = ps[r];
        v += __shfl_xor(v, 1);
        v += __shfl_xor(v, 2);
        v += __shfl_xor(v, 4);
        v += __shfl_xor(v, 8);
        lrow[r] = lrow[r] * scl[r] + v;
        oacc[0][r] *= scl[r];
        oacc[1][r] *= scl[r];
        oacc[2][r] *= scl[r];
        oacc[3][r] *= scl[r];
      }
#pragma unroll
      for (int scb = 0; scb < 4; ++scb)
#pragma unroll
        for (int r = 0; r < 4; ++r) {
          const int trow = l4 * 4 + r, scol = scb * 16 + l15;
          const int byte = trow * 128 + ((scol * 2) ^ ((trow & 7) << 4));
          *(u16*)((char*)&Pl[wave][0] + byte) = f2b(sf[scb][r]);
        }
#pragma unroll
      for (int h2 = 0; h2 < 2; ++h2) {
        const bf16x8 pf = *(const bf16x8*)((const char*)&Pl[wave][0] +
                                           l15 * 128 +
                                           (((h2 * 4 + l4) ^ (l15 & 7)) << 4));
#pragma unroll
        for (int eF = 0; eF < 4; ++eF)
          oacc[eF] = mfma16(pf, vv[h2][eF], oacc[eF]);
      }
    }
#pragma unroll
    for (int eF = 0; eF < 4; ++eF)
#pragma unroll
      for (int r = 0; r < 4; ++r) {
        const int t = tw + l4 * 4 + r;
        const float val = oacc[eF][r] / lrow[r];
        o[(size_t)(b * 512 + t) * 1024 + h * 64 + eF * 16 + l15] = f2b(val);
      }
  }
}

// ---------------------------------------------------------------------------
extern "C" void kernel_launch(void* const* d_in, const int* in_sizes, int n_in,
                              void* d_out, int out_size, void* d_ws,
                              size_t ws_size, hipStream_t stream) {
  const float* x = (const float*)d_in[0];
  const float* ga = (const float*)d_in[1];
  const float* ba = (const float*)d_in[2];
  const float* Win = (const float*)d_in[3];
  const float* bin = (const float*)d_in[4];
  const float* Wk = (const float*)d_in[5];
  const float* bk = (const float*)d_in[6];
  const float* Wq = (const float*)d_in[7];
  const float* bq = (const float*)d_in[8];
  const float* Wv = (const float*)d_in[9];
  const float* bv = (const float*)d_in[10];
  const float* Wout = (const float*)d_in[11];
  const float* bout = (const float*)d_in[12];
  const float* gf = (const float*)d_in[13];
  const float* bf_ = (const float*)d_in[14];
  const float* W1 = (const float*)d_in[15];
  const float* b1 = (const float*)d_in[16];
  const float* W2 = (const float*)d_in[17];
  const float* b2 = (const float*)d_in[18];
  float* out = (float*)d_out;

  char* ws = (char*)d_ws;
  size_t off = 0;
  auto alloc = [&](size_t bytes) {
    char* p = ws + off;
    off += (bytes + 255) & ~(size_t)255;
    return p;
  };
  u16* WinT = (u16*)alloc((size_t)1024 * 1024 * 2);  // [n][Whi]
  u16* WqkT = (u16*)alloc((size_t)2048 * 1024 * 2);  // [Wq|Wk] rows
  u16* WvT = (u16*)alloc((size_t)1024 * 1024 * 2);
  u16* WoutT = (u16*)alloc((size_t)1024 * 1024 * 2);
  u16* W1T = (u16*)alloc((size_t)4096 * 1024 * 2);
  u16* W2T = (u16*)alloc((size_t)1024 * 4096 * 2);
  float* bqk = (float*)alloc(2048 * 4);
  char* R1 = alloc((size_t)8192 * 1024 * 2);  // ln1 -> vfb
  char* R2 = alloc((size_t)8192 * 2048 * 2);  // hb -> ob; ln2 2nd half
  char* QK = alloc((size_t)2 * 256 * 32 * 4 * 1024);  // qf+kf (64MB) -> ffn1
  const size_t need = off;                            // ~117 MiB

  if (need > ws_size) {  // diagnostic sentinel: ws too small -> absmax ~12345
    fillconst<<<(out_size + 255) / 256, 256, 0, stream>>>(out, 12345.0f,
                                                          out_size);
    return;
  }

  u16* ln1 = (u16*)R1;                              // 16 MiB (plain bf16)
  u16* vfb = (u16*)R1;                              // after ln1 dead
  u16* hb = (u16*)R2;                               // 16 MiB (plain bf16)
  u16* ob = (u16*)R2;                               // after hb dead
  u16* ln2 = (u16*)(R2 + (size_t)8192 * 1024 * 2);  // second 16 MiB
  u16* qfb = (u16*)QK;                              // 32 MiB
  u16* kfb = (u16*)(QK + (size_t)256 * 32 * 4 * 1024);  // 32 MiB
  u16* ffn1 = (u16*)QK;                             // after attn, q/k dead
  float* x2 = out;                                  // d_out doubles as x2

  // ---- prep: transposes + biascat + lnorm1 in ONE launch ----
  prep_all<<<11528, 256, 0, stream>>>(Win, Wq, Wk, Wv, Wout, W1, W2, bq, bk,
                                      bqk, WinT, WqkT, WvT, WoutT, W1T, W2T,
                                      x, ga, ba, ln1);

  // ---- pipeline ----
  // h = bf16(ln1) @ Win_hi + bin  (1-term, K=1024; plain bf16 output)
  gemm256<256, 128, EPI_BF16><<<256, 512, 0, stream>>>(
      ln1, 1024, 0, WinT, bin, nullptr, hb, nullptr, 1024, 1024, 1024, 1024,
      0);
  // fused: [q|k] = bf16(h)@[Wq|Wk]_hi ; v = bf16(h)@Wv_hi  (ONE dispatch)
  qkv_fused<<<256, 512, 0, stream>>>(hb, WqkT, WvT, bqk, bv, qfb, kfb, vfb);
  attn_fwd<<<dim3(4, 256), 256, 0, stream>>>(qfb, kfb, vfb, ob);
  // x2 = o @ Wout + bout + x   (x2 == d_out)
  gemm256<256, 128, EPI_RES><<<256, 512, 0, stream>>>(
      ob, 1024, 0, WoutT, bout, x, x2, nullptr, 1024, 1024, 1024, 1024, 0);
  lnorm<<<8192, 256, 0, stream>>>(x2, gf, bf_, ln2);
  // ffn1 = relu(ln2 @ W1 + b1)   (overwrites q/k region: dead)
  gemm256<256, 256, EPI_RELU><<<512, 512, 0, stream>>>(
      ln2, 1024, 0, W1T, b1, nullptr, ffn1, nullptr, 4096, 4096, 1024, 1024,
      0);
  // out = ffn1 @ W2 + b2 + x2   (res == Cout == d_out, element-wise safe)
  gemm256<256, 128, EPI_RES><<<256, 512, 0, stream>>>(
      ffn1, 4096, 0, W2T, b2, x2, out, nullptr, 1024, 1024, 4096, 4096, 0);
}